// Round 5
// baseline (1631.655 us; speedup 1.0000x reference)
//
#include <hip/hip_runtime.h>
#include <hip/hip_bf16.h>

typedef __hip_bfloat16 bf16;

// RetNet block: L=2, B=4, S=2048, D=256, H=8, HD=32, FFN*D=1024
#define LYR 2
#define BB 4
#define SS 2048
#define DD 256
#define HH 8
#define HDD 32
#define FFD 1024
#define MM (BB*SS)   // 8192 tokens

// ---------------- xPos tables (sin/cos/scale, S x 16) ----------------
__global__ void tables_k(float* __restrict__ sn, float* __restrict__ cs, float* __restrict__ sc) {
  int i = blockIdx.x * 256 + threadIdx.x;
  if (i >= SS * 16) return;
  int s = i >> 4, j = i & 15;
  float sv = (2.0f * (float)j + 0.4f * (float)HDD) / (1.4f * (float)HDD);
  sc[i] = powf(sv, (float)s * (1.0f / 512.0f));
  float inv_freq = powf(10000.0f, -(float)j * (1.0f / 16.0f));
  float ang = (float)s * inv_freq;
  sn[i] = sinf(ang);
  cs[i] = cosf(ang);
}

// ---------------- LayerNorm over D=256 (one block per row), f32 in, OT out ----------------
template<typename OT>
__global__ __launch_bounds__(256) void ln_k(const float* __restrict__ in, const float* __restrict__ w,
    const float* __restrict__ b, OT* __restrict__ out)
{
  int row = blockIdx.x, t = threadIdx.x;
  float v = in[(size_t)row * DD + t];
  __shared__ float red[4];
  float s = v;
  #pragma unroll
  for (int m = 32; m >= 1; m >>= 1) s += __shfl_xor(s, m);
  if ((t & 63) == 0) red[t >> 6] = s;
  __syncthreads();
  float mu = (red[0] + red[1] + red[2] + red[3]) * (1.0f / 256.0f);
  float d = v - mu;
  float s2 = d * d;
  #pragma unroll
  for (int m = 32; m >= 1; m >>= 1) s2 += __shfl_xor(s2, m);
  __syncthreads();
  if ((t & 63) == 0) red[t >> 6] = s2;
  __syncthreads();
  float var = (red[0] + red[1] + red[2] + red[3]) * (1.0f / 256.0f);
  float o = d * rsqrtf(var + 1e-5f) * w[t] + b[t];
  if constexpr (sizeof(OT) == 2) out[(size_t)row * DD + t] = __float2bfloat16(o);
  else                           out[(size_t)row * DD + t] = o;
}

// ---------------- f32 tiled GEMM: C(M x N) = A(M x K) @ W(K x N), fused epilogues ----------------
// ALL outputs row-major (M x N). xPos epilogues rotate pairs in place (no layout change).
enum { E_PLAIN = 0, E_RES = 1, E_BGELU = 2, E_BRES = 3, E_XQ = 4, E_XK = 5 };

template<int K, int EPI>
__global__ __launch_bounds__(256) void gemm_k(const float* __restrict__ A, const float* __restrict__ Wm,
    const float* __restrict__ bias, const float* __restrict__ res, float* __restrict__ out, int N,
    const float* __restrict__ tsn, const float* __restrict__ tcs, const float* __restrict__ tsc)
{
  __shared__ __align__(16) float As[16][68];  // [k][m], padded
  __shared__ __align__(16) float Bs[16][68];  // [k][n], padded
  const int bm = blockIdx.x * 64;
  const int bn = blockIdx.y * 64;
  const int tid = threadIdx.x;
  const int tx = tid & 15, ty = tid >> 4;
  const int arow = tid >> 2, akc = (tid & 3) << 2;
  const int brow = tid >> 4, bcc = (tid & 15) << 2;
  float acc[4][4] = {};
  for (int k0 = 0; k0 < K; k0 += 16) {
    float4 a4 = *(const float4*)&A[(size_t)(bm + arow) * K + k0 + akc];
    As[akc + 0][arow] = a4.x;
    As[akc + 1][arow] = a4.y;
    As[akc + 2][arow] = a4.z;
    As[akc + 3][arow] = a4.w;
    *(float4*)&Bs[brow][bcc] = *(const float4*)&Wm[(size_t)(k0 + brow) * N + bn + bcc];
    __syncthreads();
    #pragma unroll
    for (int kk = 0; kk < 16; ++kk) {
      float4 ra = *(const float4*)&As[kk][ty << 2];
      float4 rb = *(const float4*)&Bs[kk][tx << 2];
      float fa[4] = {ra.x, ra.y, ra.z, ra.w};
      float fb[4] = {rb.x, rb.y, rb.z, rb.w};
      #pragma unroll
      for (int i = 0; i < 4; ++i)
        #pragma unroll
        for (int j = 0; j < 4; ++j)
          acc[i][j] = fmaf(fa[i], fb[j], acc[i][j]);
    }
    __syncthreads();
  }
  #pragma unroll
  for (int i = 0; i < 4; ++i) {
    const int rrow = bm + (ty << 2) + i;
    if constexpr (EPI == E_XQ || EPI == E_XK) {
      // xPos rotary in place; output row-major (B*S, D)
      const int s = rrow & (SS - 1);
      #pragma unroll
      for (int j = 0; j < 4; j += 2) {
        int c = bn + (tx << 2) + j;           // even
        int jj = (c & 31) >> 1;               // pair index within head
        float scv = tsc[s * 16 + jj];
        if constexpr (EPI == E_XK) scv = 1.0f / scv;
        float ce = tcs[s * 16 + jj] * scv;
        float se = tsn[s * 16 + jj] * scv;
        float xe = acc[i][j], xo = acc[i][j + 1];
        out[(size_t)rrow * N + c]     = xe * ce - xo * se;
        out[(size_t)rrow * N + c + 1] = xo * ce + xe * se;
      }
    } else {
      #pragma unroll
      for (int j = 0; j < 4; ++j) {
        int c = bn + (tx << 2) + j;
        float vv = acc[i][j];
        if constexpr (EPI == E_BGELU) {
          vv += bias[c];
          vv = 0.5f * vv * (1.0f + erff(vv * 0.70710678118654752f));
        } else if constexpr (EPI == E_BRES) {
          vv += bias[c] + res[(size_t)rrow * N + c];
        } else if constexpr (EPI == E_RES) {
          vv += res[(size_t)rrow * N + c];
        }
        out[(size_t)rrow * N + c] = vv;
      }
    }
  }
}

// ---------------- Retention: y = (q k^T * g^(n-m), causal) @ v ----------------
// q,k,v,y ALL row-major (B*S, D); head h occupies columns [h*32, h*32+32).
// grid (S/64, B*H), block 256 = 64 rows x 4 lane-groups (8 dims each). Full causal loop.
__global__ __launch_bounds__(256) void attn_k(const float* __restrict__ q, const float* __restrict__ k,
    const float* __restrict__ v, float* __restrict__ y)
{
  __shared__ float Ks[64][32];
  __shared__ float Vs[64][32];
  const int bh = blockIdx.y;
  const int b = bh >> 3, h = bh & (HH - 1);
  const int n0 = blockIdx.x * 64;
  const int tid = threadIdx.x;
  const int r = tid >> 2;
  const int cg = tid & 3;
  const int n = n0 + r;
  const int d0 = cg << 3;
  const size_t base = (size_t)b * SS * DD + (size_t)h * HDD;  // + row*DD + dim
  float qr[8];
  #pragma unroll
  for (int j = 0; j < 8; ++j) qr[j] = q[base + (size_t)n * DD + d0 + j];
  float acc[8] = {0.f,0.f,0.f,0.f,0.f,0.f,0.f,0.f};
  // per-head decay: g_h = 1 - exp(log(1/32) + h*(log(1/512)-log(1/32))/7)
  float onemg = expf(-3.4657359028f - 0.3960841187f * (float)h);
  float l2g = log2f(1.0f - onemg);       // negative
  const int lr = tid >> 2, lc = (tid & 3) << 3;
  for (int m0 = 0; m0 <= n0; m0 += 64) {
    __syncthreads();
    *(float4*)&Ks[lr][lc]     = *(const float4*)&k[base + (size_t)(m0 + lr) * DD + lc];
    *(float4*)&Ks[lr][lc + 4] = *(const float4*)&k[base + (size_t)(m0 + lr) * DD + lc + 4];
    *(float4*)&Vs[lr][lc]     = *(const float4*)&v[base + (size_t)(m0 + lr) * DD + lc];
    *(float4*)&Vs[lr][lc + 4] = *(const float4*)&v[base + (size_t)(m0 + lr) * DD + lc + 4];
    __syncthreads();
    for (int mi = 0; mi < 64; ++mi) {
      int ddn = n - (m0 + mi);
      float s = 0.0f;
      #pragma unroll
      for (int j = 0; j < 8; ++j) s += qr[j] * Ks[mi][d0 + j];
      s += __shfl_xor(s, 1);
      s += __shfl_xor(s, 2);
      float dm = (ddn < 0) ? 0.0f : exp2f((float)ddn * l2g);
      s *= dm;
      #pragma unroll
      for (int j = 0; j < 8; ++j) acc[j] += s * Vs[mi][d0 + j];
    }
  }
  #pragma unroll
  for (int j = 0; j < 8; ++j)
    y[base + (size_t)n * DD + d0 + j] = acc[j];
}

// ---------------- per-head GroupNorm + gn affine + SiLU(g) gate ----------------
// y,g row-major (B*S, D); head = t/32. u aliases g (same-index RMW, safe).
__global__ __launch_bounds__(256) void gn_silu_k(const float* __restrict__ y, const float* __restrict__ g,
    const float* __restrict__ gw, const float* __restrict__ gb, float* __restrict__ u)
{
  int bs = blockIdx.x;
  int t = threadIdx.x;
  float val = y[(size_t)bs * DD + t];
  float sum = val;
  #pragma unroll
  for (int m = 16; m >= 1; m >>= 1) sum += __shfl_xor(sum, m);
  float mu = sum * (1.0f / 32.0f);
  float df = val - mu;
  float s2 = df * df;
  #pragma unroll
  for (int m = 16; m >= 1; m >>= 1) s2 += __shfl_xor(s2, m);
  float var = s2 * (1.0f / 32.0f);
  float yn = df * rsqrtf(var + 1e-5f) * gw[t] + gb[t];
  float gg = g[(size_t)bs * DD + t];
  float sig = 1.0f / (1.0f + expf(-gg));
  u[(size_t)bs * DD + t] = gg * sig * yn;
}

extern "C" void kernel_launch(void* const* d_in, const int* in_sizes, int n_in,
                              void* d_out, int out_size, void* d_ws, size_t ws_size,
                              hipStream_t stream)
{
  // Inputs f32 (round-3 NaN experiment proved bf16-read is wrong; npz size matches f32).
  // OUTPUT IS f32: reference returns float32; out_npz ~8MB for 2M elems. (Rounds 1-4 wrote
  // bf16 into the f32 buffer -> packed-word garbage -> bit-identical 6.65625 across pipelines.)
  const float* X    = (const float*)d_in[0];
  const float* Wq   = (const float*)d_in[1];
  const float* Wk   = (const float*)d_in[2];
  const float* Wv   = (const float*)d_in[3];
  const float* Wg   = (const float*)d_in[4];
  const float* Wo   = (const float*)d_in[5];
  const float* gnw  = (const float*)d_in[6];
  const float* gnb  = (const float*)d_in[7];
  const float* ln1w = (const float*)d_in[8];
  const float* ln1b = (const float*)d_in[9];
  const float* ln2w = (const float*)d_in[10];
  const float* ln2b = (const float*)d_in[11];
  const float* w1   = (const float*)d_in[12];
  const float* b1   = (const float*)d_in[13];
  const float* w2   = (const float*)d_in[14];
  const float* b2   = (const float*)d_in[15];
  const float* lnfw = (const float*)d_in[16];
  const float* lnfb = (const float*)d_in[17];

  // Workspace: 7 f32 activation slots (8 MiB each) + tables = ~56.4 MiB
  char* p = (char*)d_ws;
  const size_t AF = (size_t)MM * DD * sizeof(float);   // 8 MiB
  float* xn   = (float*)p; p += AF;
  float* qb   = (float*)p; p += AF;   // h1 (32 MiB f32) aliases qb..ybuf after attention
  float* kb   = (float*)p; p += AF;
  float* vb   = (float*)p; p += AF;
  float* ybuf = (float*)p; p += AF;
  float* gbuf = (float*)p; p += AF;   // gated value in place; also FFN output (E_BRES out)
  float* yres = (float*)p; p += AF;   // attn-block residual; also next-layer x (final LN out)
  float* tsn  = (float*)p; p += SS * 16 * sizeof(float);
  float* tcs  = (float*)p; p += SS * 16 * sizeof(float);
  float* tsc  = (float*)p; p += SS * 16 * sizeof(float);
  float* h1   = qb;                   // MM*FFD f32 = 32 MiB, spans qb..ybuf (dead by then)

  tables_k<<<dim3((SS * 16 + 255) / 256), dim3(256), 0, stream>>>(tsn, tcs, tsc);

  dim3 gA(MM / 64, DD / 64);
  const float* xin = X;
  for (int l = 0; l < LYR; ++l) {
    ln_k<float><<<dim3(MM), 256, 0, stream>>>(xin, ln1w + l * DD, ln1b + l * DD, xn);
    gemm_k<DD, E_XQ   ><<<gA, 256, 0, stream>>>(xn, Wq + (size_t)l * DD * DD, nullptr, nullptr, qb,   DD, tsn, tcs, tsc);
    gemm_k<DD, E_XK   ><<<gA, 256, 0, stream>>>(xn, Wk + (size_t)l * DD * DD, nullptr, nullptr, kb,   DD, tsn, tcs, tsc);
    gemm_k<DD, E_PLAIN><<<gA, 256, 0, stream>>>(xn, Wv + (size_t)l * DD * DD, nullptr, nullptr, vb,   DD, tsn, tcs, tsc);
    gemm_k<DD, E_PLAIN><<<gA, 256, 0, stream>>>(xn, Wg + (size_t)l * DD * DD, nullptr, nullptr, gbuf, DD, tsn, tcs, tsc);
    attn_k<<<dim3(SS / 64, BB * HH), 256, 0, stream>>>(qb, kb, vb, ybuf);
    gn_silu_k<<<dim3(MM), 256, 0, stream>>>(ybuf, gbuf, gnw + l * DD, gnb + l * DD, gbuf);
    gemm_k<DD, E_RES><<<gA, 256, 0, stream>>>(gbuf, Wo + (size_t)l * DD * DD, nullptr, xin, yres, DD, tsn, tcs, tsc);
    ln_k<float><<<dim3(MM), 256, 0, stream>>>(yres, ln2w + l * DD, ln2b + l * DD, xn);
    gemm_k<DD,  E_BGELU><<<dim3(MM / 64, FFD / 64), 256, 0, stream>>>(xn, w1 + (size_t)l * DD * FFD, b1 + l * FFD, nullptr, h1, FFD, tsn, tcs, tsc);
    gemm_k<FFD, E_BRES ><<<gA, 256, 0, stream>>>(h1, w2 + (size_t)l * FFD * DD, b2 + l * DD, yres, gbuf, DD, tsn, tcs, tsc);
    if (l == LYR - 1) {
      ln_k<float><<<dim3(MM), 256, 0, stream>>>(gbuf, lnfw, lnfb, (float*)d_out);
    } else {
      ln_k<float><<<dim3(MM), 256, 0, stream>>>(gbuf, lnfw, lnfb, yres);
      xin = yres;
    }
  }
}

// Round 6
// 631.814 us; speedup vs baseline: 2.5825x; 2.5825x over previous
//
#include <hip/hip_runtime.h>
#include <hip/hip_bf16.h>

typedef __hip_bfloat16 bf16;
typedef unsigned short ushort_t;
typedef __attribute__((ext_vector_type(8))) short short8v;
typedef __attribute__((ext_vector_type(4))) float f32x4;
typedef __attribute__((ext_vector_type(4))) unsigned int uint4v;

// RetNet block: L=2, B=4, S=2048, D=256, H=8, HD=32, FFN*D=1024
#define LYR 2
#define BB 4
#define SS 2048
#define DD 256
#define HH 8
#define HDD 32
#define FFD 1024
#define MM (BB*SS)   // 8192 tokens

__device__ __forceinline__ unsigned short f2bu(float f) {
  union { float f; unsigned int u; } c; c.f = f;
  unsigned int r = (c.u + 0x7fffu + ((c.u >> 16) & 1u)) >> 16;
  return (unsigned short)r;
}

// ---------------- xPos tables (sin/cos/scale, S x 16) ----------------
__global__ void tables_k(float* __restrict__ sn, float* __restrict__ cs, float* __restrict__ sc) {
  int i = blockIdx.x * 256 + threadIdx.x;
  if (i >= SS * 16) return;
  int s = i >> 4, j = i & 15;
  float sv = (2.0f * (float)j + 0.4f * (float)HDD) / (1.4f * (float)HDD);
  sc[i] = powf(sv, (float)s * (1.0f / 512.0f));
  float inv_freq = powf(10000.0f, -(float)j * (1.0f / 16.0f));
  float ang = (float)s * inv_freq;
  sn[i] = sinf(ang);
  cs[i] = cosf(ang);
}

// ---------------- LayerNorm over D=256 (one block per row), f32 in, OT out ----------------
template<typename OT>
__global__ __launch_bounds__(256) void ln_k(const float* __restrict__ in, const float* __restrict__ w,
    const float* __restrict__ b, OT* __restrict__ out)
{
  int row = blockIdx.x, t = threadIdx.x;
  float v = in[(size_t)row * DD + t];
  __shared__ float red[4];
  float s = v;
  #pragma unroll
  for (int m = 32; m >= 1; m >>= 1) s += __shfl_xor(s, m);
  if ((t & 63) == 0) red[t >> 6] = s;
  __syncthreads();
  float mu = (red[0] + red[1] + red[2] + red[3]) * (1.0f / 256.0f);
  float d = v - mu;
  float s2 = d * d;
  #pragma unroll
  for (int m = 32; m >= 1; m >>= 1) s2 += __shfl_xor(s2, m);
  __syncthreads();
  if ((t & 63) == 0) red[t >> 6] = s2;
  __syncthreads();
  float var = (red[0] + red[1] + red[2] + red[3]) * (1.0f / 256.0f);
  float o = d * rsqrtf(var + 1e-5f) * w[t] + b[t];
  if constexpr (sizeof(OT) == 2) out[(size_t)row * DD + t] = __float2bfloat16(o);
  else                           out[(size_t)row * DD + t] = o;
}

// ---------------- f32 tiled GEMM: C(M x N) = A(M x K) @ W(K x N), fused epilogues ----------------
enum { E_PLAIN = 0, E_RES = 1, E_BGELU = 2, E_BRES = 3, E_XQ = 4, E_XK = 5 };

template<typename T>
__device__ __forceinline__ void stg(T* __restrict__ p, size_t i, float v) {
  if constexpr (sizeof(T) == 2) p[i] = __float2bfloat16(v);
  else                          p[i] = v;
}

template<int K, int EPI, typename OT>
__global__ __launch_bounds__(256) void gemm_k(const float* __restrict__ A, const float* __restrict__ Wm,
    const float* __restrict__ bias, const float* __restrict__ res, OT* __restrict__ out, int N,
    const float* __restrict__ tsn, const float* __restrict__ tcs, const float* __restrict__ tsc)
{
  __shared__ __align__(16) float As[16][68];  // [k][m], padded
  __shared__ __align__(16) float Bs[16][68];  // [k][n], padded
  const int bm = blockIdx.x * 64;
  const int bn = blockIdx.y * 64;
  const int tid = threadIdx.x;
  const int tx = tid & 15, ty = tid >> 4;
  const int arow = tid >> 2, akc = (tid & 3) << 2;
  const int brow = tid >> 4, bcc = (tid & 15) << 2;
  float acc[4][4] = {};
  for (int k0 = 0; k0 < K; k0 += 16) {
    float4 a4 = *(const float4*)&A[(size_t)(bm + arow) * K + k0 + akc];
    As[akc + 0][arow] = a4.x;
    As[akc + 1][arow] = a4.y;
    As[akc + 2][arow] = a4.z;
    As[akc + 3][arow] = a4.w;
    *(float4*)&Bs[brow][bcc] = *(const float4*)&Wm[(size_t)(k0 + brow) * N + bn + bcc];
    __syncthreads();
    #pragma unroll
    for (int kk = 0; kk < 16; ++kk) {
      float4 ra = *(const float4*)&As[kk][ty << 2];
      float4 rb = *(const float4*)&Bs[kk][tx << 2];
      float fa[4] = {ra.x, ra.y, ra.z, ra.w};
      float fb[4] = {rb.x, rb.y, rb.z, rb.w};
      #pragma unroll
      for (int i = 0; i < 4; ++i)
        #pragma unroll
        for (int j = 0; j < 4; ++j)
          acc[i][j] = fmaf(fa[i], fb[j], acc[i][j]);
    }
    __syncthreads();
  }
  #pragma unroll
  for (int i = 0; i < 4; ++i) {
    const int rrow = bm + (ty << 2) + i;
    if constexpr (EPI == E_XQ || EPI == E_XK) {
      const int s = rrow & (SS - 1);
      #pragma unroll
      for (int j = 0; j < 4; j += 2) {
        int c = bn + (tx << 2) + j;           // even
        int jj = (c & 31) >> 1;               // pair index within head
        float scv = tsc[s * 16 + jj];
        if constexpr (EPI == E_XK) scv = 1.0f / scv;
        float ce = tcs[s * 16 + jj] * scv;
        float se = tsn[s * 16 + jj] * scv;
        float xe = acc[i][j], xo = acc[i][j + 1];
        stg(out, (size_t)rrow * N + c,     xe * ce - xo * se);
        stg(out, (size_t)rrow * N + c + 1, xo * ce + xe * se);
      }
    } else {
      #pragma unroll
      for (int j = 0; j < 4; ++j) {
        int c = bn + (tx << 2) + j;
        float vv = acc[i][j];
        if constexpr (EPI == E_BGELU) {
          vv += bias[c];
          vv = 0.5f * vv * (1.0f + erff(vv * 0.70710678118654752f));
        } else if constexpr (EPI == E_BRES) {
          vv += bias[c] + res[(size_t)rrow * N + c];
        } else if constexpr (EPI == E_RES) {
          vv += res[(size_t)rrow * N + c];
        }
        stg(out, (size_t)rrow * N + c, vv);
      }
    }
  }
}

// ---------------- Retention via MFMA: y = (q k^T * g^(n-m), causal) @ v ----------------
// q,k,v bf16 row-major (B*S, D); head h = cols [h*32, h*32+32). y f32 same layout.
// grid (B*H, S/64), block 256 = 4 waves; wave w owns n-rows [n0+16w, n0+16w+16).
// Swapped QK^T: D[m][n] = mfma(A=K, B=Q^T). Swapped PV: Y^T[d][n] = mfma(A=V^T, B=P^T).
__global__ __launch_bounds__(256) void attn_k(const bf16* __restrict__ qg, const bf16* __restrict__ kg,
    const bf16* __restrict__ vg, float* __restrict__ y)
{
  __shared__ __align__(16) ushort_t Ks[64 * 32];   // [m][k], 16B-block swizzle: blk ^= (m>>1)&3
  __shared__ __align__(16) ushort_t Vt[32 * 66];   // [d][m], row pad 66, quad swizzle: blk ^= d&7
  __shared__ __align__(16) unsigned int Pl[4 * 512]; // per-wave P[16n][64m] bf16, quad swizzle: blk ^= n&7

  const int bh = blockIdx.x;
  const int b = bh >> 3, h = bh & (HH - 1);
  const int n0 = blockIdx.y * 64;
  const int tid = threadIdx.x;
  const int w = tid >> 6, lane = tid & 63;
  const int lg = lane >> 4, ln = lane & 15;

  const size_t base = (size_t)b * SS * DD + h * HDD;
  const ushort_t* qp = (const ushort_t*)qg + base;
  const ushort_t* kp = (const ushort_t*)kg + base;
  const ushort_t* vp = (const ushort_t*)vg + base;

  const int n = n0 + w * 16 + ln;                  // this lane's query row (B-frag col)
  const short8v qf = *(const short8v*)(qp + (size_t)n * DD + lg * 8);

  // per-head decay: g_h = 1 - exp(log(1/32) + h*(log(1/512)-log(1/32))/7)
  const float onemg = expf(-3.4657359028f - 0.3960841187f * (float)h);
  const float l2g = log2f(1.0f - onemg);           // negative
  float em[4][4];                                  // exp2(-l2g * (mt*16 + lg*4 + r))
  #pragma unroll
  for (int mt = 0; mt < 4; ++mt)
    #pragma unroll
    for (int r = 0; r < 4; ++r)
      em[mt][r] = exp2f(-l2g * (float)(mt * 16 + lg * 4 + r));

  f32x4 acc0 = {0.f, 0.f, 0.f, 0.f};
  f32x4 acc1 = {0.f, 0.f, 0.f, 0.f};

  const int Wwin = (int)(20.0f / (-l2g)) + 1;      // decay < 2^-20 beyond this
  int m_lo = 0;
  if (n0 > Wwin) m_lo = ((n0 - Wwin) >> 6) << 6;

  const int srow = tid >> 2;                       // staging: row 0..63
  const int sc = tid & 3;                          // staging: 8-col group

  const unsigned int* vt32 = (const unsigned int*)Vt;

  for (int m0 = m_lo; m0 <= n0; m0 += 64) {
    __syncthreads();
    // ---- stage K tile [64m][32k] (swizzled b128) and V^T tile [32d][64m] (padded+swizzled) ----
    {
      short8v kv = *(const short8v*)(kp + (size_t)(m0 + srow) * DD + sc * 8);
      *(short8v*)&Ks[srow * 32 + ((sc ^ ((srow >> 1) & 3)) << 3)] = kv;
      short8v vv = *(const short8v*)(vp + (size_t)(m0 + srow) * DD + sc * 8);
      #pragma unroll
      for (int j = 0; j < 8; ++j)   // d = sc*8+j, m = srow
        Vt[(sc * 8 + j) * 66 + ((((srow >> 3) ^ j)) << 3) + (srow & 7)] = (ushort_t)vv[j];
    }
    __syncthreads();

    const float fn = exp2f(l2g * (float)(n - m0));
    // ---- QK^T (swapped): P^T tiles, decay, pack to per-wave P_lds ----
    #pragma unroll
    for (int mt = 0; mt < 4; ++mt) {
      const int krow = mt * 16 + ln;
      short8v kf = *(const short8v*)&Ks[krow * 32 + ((lg ^ ((krow >> 1) & 3)) << 3)];
      f32x4 z = {0.f, 0.f, 0.f, 0.f};
      f32x4 pa = __builtin_amdgcn_mfma_f32_16x16x32_bf16(kf, qf, z, 0, 0, 0);
      unsigned int pk0, pk1;
      {
        int m = m0 + mt * 16 + lg * 4;
        float v0 = (n < m)     ? 0.f : pa[0] * fn * em[mt][0];
        float v1 = (n < m + 1) ? 0.f : pa[1] * fn * em[mt][1];
        float v2 = (n < m + 2) ? 0.f : pa[2] * fn * em[mt][2];
        float v3 = (n < m + 3) ? 0.f : pa[3] * fn * em[mt][3];
        pk0 = ((unsigned int)f2bu(v1) << 16) | f2bu(v0);
        pk1 = ((unsigned int)f2bu(v3) << 16) | f2bu(v2);
      }
      const int blk = (mt * 2 + (lg >> 1)) ^ (ln & 7);
      Pl[w * 512 + ln * 32 + blk * 4 + (lg & 1) * 2 + 0] = pk0;
      Pl[w * 512 + ln * 32 + blk * 4 + (lg & 1) * 2 + 1] = pk1;
    }
    // ---- PV (swapped): acc[d][n] += V^T · P^T ----
    #pragma unroll
    for (int hh = 0; hh < 2; ++hh) {
      const int pblk = (lg + 4 * hh) ^ (ln & 7);
      uint4v pw = *(const uint4v*)&Pl[w * 512 + ln * 32 + pblk * 4];
      short8v pf = __builtin_bit_cast(short8v, pw);
      #pragma unroll
      for (int dt = 0; dt < 2; ++dt) {
        const int d = dt * 16 + ln;
        const int vb = (lg + 4 * hh) ^ (ln & 7);
        uint4v vw;
        vw.x = vt32[d * 33 + vb * 4 + 0];
        vw.y = vt32[d * 33 + vb * 4 + 1];
        vw.z = vt32[d * 33 + vb * 4 + 2];
        vw.w = vt32[d * 33 + vb * 4 + 3];
        short8v vf = __builtin_bit_cast(short8v, vw);
        if (dt == 0) acc0 = __builtin_amdgcn_mfma_f32_16x16x32_bf16(vf, pf, acc0, 0, 0, 0);
        else         acc1 = __builtin_amdgcn_mfma_f32_16x16x32_bf16(vf, pf, acc1, 0, 0, 0);
      }
    }
  }

  // ---- epilogue: acc[dt][r] = Y^T[d = dt*16+lg*4+r][n] ----
  float* yp = y + (size_t)b * SS * DD + h * HDD;
  #pragma unroll
  for (int r = 0; r < 4; ++r) {
    yp[(size_t)n * DD + lg * 4 + r]      = acc0[r];
    yp[(size_t)n * DD + 16 + lg * 4 + r] = acc1[r];
  }
}

// ---------------- per-head GroupNorm + gn affine + SiLU(g) gate ----------------
__global__ __launch_bounds__(256) void gn_silu_k(const float* __restrict__ y, const float* __restrict__ g,
    const float* __restrict__ gw, const float* __restrict__ gb, float* __restrict__ u)
{
  int bs = blockIdx.x;
  int t = threadIdx.x;
  float val = y[(size_t)bs * DD + t];
  float sum = val;
  #pragma unroll
  for (int m = 16; m >= 1; m >>= 1) sum += __shfl_xor(sum, m);
  float mu = sum * (1.0f / 32.0f);
  float df = val - mu;
  float s2 = df * df;
  #pragma unroll
  for (int m = 16; m >= 1; m >>= 1) s2 += __shfl_xor(s2, m);
  float var = s2 * (1.0f / 32.0f);
  float yn = df * rsqrtf(var + 1e-5f) * gw[t] + gb[t];
  float gg = g[(size_t)bs * DD + t];
  float sig = 1.0f / (1.0f + expf(-gg));
  u[(size_t)bs * DD + t] = gg * sig * yn;
}

extern "C" void kernel_launch(void* const* d_in, const int* in_sizes, int n_in,
                              void* d_out, int out_size, void* d_ws, size_t ws_size,
                              hipStream_t stream)
{
  const float* X    = (const float*)d_in[0];
  const float* Wq   = (const float*)d_in[1];
  const float* Wk   = (const float*)d_in[2];
  const float* Wv   = (const float*)d_in[3];
  const float* Wg   = (const float*)d_in[4];
  const float* Wo   = (const float*)d_in[5];
  const float* gnw  = (const float*)d_in[6];
  const float* gnb  = (const float*)d_in[7];
  const float* ln1w = (const float*)d_in[8];
  const float* ln1b = (const float*)d_in[9];
  const float* ln2w = (const float*)d_in[10];
  const float* ln2b = (const float*)d_in[11];
  const float* w1   = (const float*)d_in[12];
  const float* b1   = (const float*)d_in[13];
  const float* w2   = (const float*)d_in[14];
  const float* b2   = (const float*)d_in[15];
  const float* lnfw = (const float*)d_in[16];
  const float* lnfb = (const float*)d_in[17];

  // Workspace: xn(8) qb(4) kb(4) vb(4) ybuf(8) gbuf(8) pad(4) yres(8) + tables = ~48.4 MiB
  char* p = (char*)d_ws;
  const size_t AF  = (size_t)MM * DD * sizeof(float);  // 8 MiB
  const size_t ABF = (size_t)MM * DD * sizeof(bf16);   // 4 MiB
  float* xn   = (float*)p; p += AF;
  bf16*  qb   = (bf16*)p;  p += ABF;
  bf16*  kb   = (bf16*)p;  p += ABF;
  bf16*  vb   = (bf16*)p;  p += ABF;
  float* ybuf = (float*)p; p += AF;
  float* gbuf = (float*)p; p += AF;
  p += ABF;  // pad so h1 (32 MiB f32) fits over qb..pad
  float* yres = (float*)p; p += AF;
  float* tsn  = (float*)p; p += SS * 16 * sizeof(float);
  float* tcs  = (float*)p; p += SS * 16 * sizeof(float);
  float* tsc  = (float*)p; p += SS * 16 * sizeof(float);
  float* h1   = (float*)qb;  // MM*FFD f32 = 32 MiB, spans qb..pad (dead by then)

  tables_k<<<dim3((SS * 16 + 255) / 256), dim3(256), 0, stream>>>(tsn, tcs, tsc);

  dim3 gA(MM / 64, DD / 64);
  const float* xin = X;
  for (int l = 0; l < LYR; ++l) {
    ln_k<float><<<dim3(MM), 256, 0, stream>>>(xin, ln1w + l * DD, ln1b + l * DD, xn);
    gemm_k<DD, E_XQ,    bf16 ><<<gA, 256, 0, stream>>>(xn, Wq + (size_t)l * DD * DD, nullptr, nullptr, qb,   DD, tsn, tcs, tsc);
    gemm_k<DD, E_XK,    bf16 ><<<gA, 256, 0, stream>>>(xn, Wk + (size_t)l * DD * DD, nullptr, nullptr, kb,   DD, tsn, tcs, tsc);
    gemm_k<DD, E_PLAIN, bf16 ><<<gA, 256, 0, stream>>>(xn, Wv + (size_t)l * DD * DD, nullptr, nullptr, vb,   DD, tsn, tcs, tsc);
    gemm_k<DD, E_PLAIN, float><<<gA, 256, 0, stream>>>(xn, Wg + (size_t)l * DD * DD, nullptr, nullptr, gbuf, DD, tsn, tcs, tsc);
    attn_k<<<dim3(BB * HH, SS / 64), 256, 0, stream>>>(qb, kb, vb, ybuf);
    gn_silu_k<<<dim3(MM), 256, 0, stream>>>(ybuf, gbuf, gnw + l * DD, gnb + l * DD, gbuf);
    gemm_k<DD, E_RES, float><<<gA, 256, 0, stream>>>(gbuf, Wo + (size_t)l * DD * DD, nullptr, xin, yres, DD, tsn, tcs, tsc);
    ln_k<float><<<dim3(MM), 256, 0, stream>>>(yres, ln2w + l * DD, ln2b + l * DD, xn);
    gemm_k<DD,  E_BGELU, float><<<dim3(MM / 64, FFD / 64), 256, 0, stream>>>(xn, w1 + (size_t)l * DD * FFD, b1 + l * FFD, nullptr, h1, FFD, tsn, tcs, tsc);
    gemm_k<FFD, E_BRES,  float><<<gA, 256, 0, stream>>>(h1, w2 + (size_t)l * FFD * DD, b2 + l * DD, yres, yres, DD, tsn, tcs, tsc);
    if (l == LYR - 1) {
      ln_k<float><<<dim3(MM), 256, 0, stream>>>(yres, lnfw, lnfb, (float*)d_out);
    } else {
      ln_k<float><<<dim3(MM), 256, 0, stream>>>(yres, lnfw, lnfb, yres);
      xin = yres;
    }
  }
}

// Round 7
// 340.041 us; speedup vs baseline: 4.7984x; 1.8581x over previous
//
#include <hip/hip_runtime.h>
#include <hip/hip_bf16.h>

typedef __hip_bfloat16 bf16;
typedef unsigned short ushort_t;
typedef __attribute__((ext_vector_type(8))) short short8v;
typedef __attribute__((ext_vector_type(4))) float f32x4;
typedef __attribute__((ext_vector_type(4))) unsigned int uint4v;

// RetNet block: L=2, B=4, S=2048, D=256, H=8, HD=32, FFN*D=1024
#define LYR 2
#define BB 4
#define SS 2048
#define DD 256
#define HH 8
#define HDD 32
#define FFD 1024
#define MM (BB*SS)   // 8192 tokens

__device__ __forceinline__ unsigned short f2bu(float f) {
  union { float f; unsigned int u; } c; c.f = f;
  unsigned int r = (c.u + 0x7fffu + ((c.u >> 16) & 1u)) >> 16;
  return (unsigned short)r;
}

__device__ __forceinline__ void gload_lds16(const void* g, void* l) {
  __builtin_amdgcn_global_load_lds((const __attribute__((address_space(1))) void*)g,
                                   (__attribute__((address_space(3))) void*)l, 16, 0, 0);
}

// ---------------- xPos tables (sin/cos/scale, S x 16) ----------------
__global__ void tables_k(float* __restrict__ sn, float* __restrict__ cs, float* __restrict__ sc) {
  int i = blockIdx.x * 256 + threadIdx.x;
  if (i >= SS * 16) return;
  int s = i >> 4, j = i & 15;
  float sv = (2.0f * (float)j + 0.4f * (float)HDD) / (1.4f * (float)HDD);
  sc[i] = powf(sv, (float)s * (1.0f / 512.0f));
  float inv_freq = powf(10000.0f, -(float)j * (1.0f / 16.0f));
  float ang = (float)s * inv_freq;
  sn[i] = sinf(ang);
  cs[i] = cosf(ang);
}

// ---------------- weight transpose+convert: Wt[n][k] = bf16(W[k][n]) ----------------
struct WDesc { const float* src; bf16* dst; int K; int N; };
struct WDescA { WDesc d[14]; };
__global__ __launch_bounds__(256) void wconv_k(WDescA da) {
  WDesc dd = da.d[blockIdx.z];
  int n0 = blockIdx.x * 32, k0 = blockIdx.y * 32;
  if (n0 >= dd.N || k0 >= dd.K) return;
  __shared__ float t[32][33];
  int tx = threadIdx.x, ty = threadIdx.y;   // 32 x 8
  #pragma unroll
  for (int i = 0; i < 32; i += 8) t[ty + i][tx] = dd.src[(size_t)(k0 + ty + i) * dd.N + n0 + tx];
  __syncthreads();
  #pragma unroll
  for (int i = 0; i < 32; i += 8) dd.dst[(size_t)(n0 + ty + i) * dd.K + k0 + tx] = __float2bfloat16(t[tx][ty + i]);
}

// ---------------- LayerNorm over D=256 (one block per row), f32 in, OT out ----------------
template<typename OT>
__global__ __launch_bounds__(256) void ln_k(const float* __restrict__ in, const float* __restrict__ w,
    const float* __restrict__ b, OT* __restrict__ out)
{
  int row = blockIdx.x, t = threadIdx.x;
  float v = in[(size_t)row * DD + t];
  __shared__ float red[4];
  float s = v;
  #pragma unroll
  for (int m = 32; m >= 1; m >>= 1) s += __shfl_xor(s, m);
  if ((t & 63) == 0) red[t >> 6] = s;
  __syncthreads();
  float mu = (red[0] + red[1] + red[2] + red[3]) * (1.0f / 256.0f);
  float d = v - mu;
  float s2 = d * d;
  #pragma unroll
  for (int m = 32; m >= 1; m >>= 1) s2 += __shfl_xor(s2, m);
  __syncthreads();
  if ((t & 63) == 0) red[t >> 6] = s2;
  __syncthreads();
  float var = (red[0] + red[1] + red[2] + red[3]) * (1.0f / 256.0f);
  float o = d * rsqrtf(var + 1e-5f) * w[t] + b[t];
  if constexpr (sizeof(OT) == 2) out[(size_t)row * DD + t] = __float2bfloat16(o);
  else                           out[(size_t)row * DD + t] = o;
}

// ---------------- bf16 MFMA GEMM: C(MxN) = A(MxK) @ Wt(N,K)^T, fused epilogues ----------------
// 128x128 tile, BK=64, 4 waves (2x2), 64x64 per wave, 16x16x32 MFMA.
// LDS staged via global_load_lds w16, XOR-swizzle blk^=(row&7) on pre-swizzled source.
enum { E_QKVG = 0, E_RES = 1, E_BGELU = 2, E_BRES = 3 };

template<int K, int EPI>
__global__ __launch_bounds__(256) void mgemm_k(const bf16* __restrict__ Ag, const bf16* __restrict__ Wt,
    const float* __restrict__ bias, const float* res,
    void* o0, void* o1, void* o2, void* o3, int N,
    const float* __restrict__ tsn, const float* __restrict__ tcs, const float* __restrict__ tsc)
{
  __shared__ __align__(16) ushort_t Al[128 * 64];
  __shared__ __align__(16) ushort_t Bl[128 * 64];
  const int bm = blockIdx.x * 128;
  const int bn = blockIdx.y * 128;
  const int tid = threadIdx.x;
  const int lane = tid & 63, w = tid >> 6;
  const int lg = lane >> 4, ln = lane & 15;
  const int wr = w >> 1, wc = w & 1;
  const ushort_t* Au = (const ushort_t*)Ag;
  const ushort_t* Bu = (const ushort_t*)Wt;
  f32x4 acc[4][4] = {};

  for (int k0 = 0; k0 < K; k0 += 64) {
    __syncthreads();
    #pragma unroll
    for (int i = 0; i < 4; ++i) {
      int slot = i * 256 + tid;
      int row = slot >> 3, blk = slot & 7;
      int sblk = blk ^ (row & 7);
      gload_lds16(Au + (size_t)(bm + row) * K + k0 + sblk * 8, Al + slot * 8);
      gload_lds16(Bu + (size_t)(bn + row) * K + k0 + sblk * 8, Bl + slot * 8);
    }
    __syncthreads();
    #pragma unroll
    for (int kh = 0; kh < 2; ++kh) {
      short8v af[4], bfr[4];
      #pragma unroll
      for (int mt = 0; mt < 4; ++mt) {
        int row = wr * 64 + mt * 16 + ln;
        int blk = (kh * 4 + lg) ^ (row & 7);
        af[mt] = *(const short8v*)&Al[row * 64 + blk * 8];
      }
      #pragma unroll
      for (int nt = 0; nt < 4; ++nt) {
        int row = wc * 64 + nt * 16 + ln;
        int blk = (kh * 4 + lg) ^ (row & 7);
        bfr[nt] = *(const short8v*)&Bl[row * 64 + blk * 8];
      }
      #pragma unroll
      for (int mt = 0; mt < 4; ++mt)
        #pragma unroll
        for (int nt = 0; nt < 4; ++nt)
          acc[mt][nt] = __builtin_amdgcn_mfma_f32_16x16x32_bf16(af[mt], bfr[nt], acc[mt][nt], 0, 0, 0);
    }
  }

  if constexpr (EPI == E_QKVG) {
    #pragma unroll
    for (int mt = 0; mt < 4; ++mt)
      #pragma unroll
      for (int nt = 0; nt < 4; ++nt) {
        const int colbase = bn + wc * 64 + nt * 16;
        const int sec = colbase >> 8;          // 0=Q 1=K 2=V 3=G
        const int c = (colbase & 255) + ln;
        const int jj = (c & 31) >> 1;
        #pragma unroll
        for (int r = 0; r < 4; ++r) {
          const int grow = bm + wr * 64 + mt * 16 + lg * 4 + r;
          const int s = grow & (SS - 1);
          float v = acc[mt][nt][r];
          if (sec <= 1) {
            float pv = __shfl_xor(v, 1);
            float scv = tsc[s * 16 + jj];
            if (sec == 1) scv = 1.0f / scv;
            float ce = tcs[s * 16 + jj] * scv, se = tsn[s * 16 + jj] * scv;
            float o = (ln & 1) ? (v * ce + pv * se) : (v * ce - pv * se);
            bf16* dst = (sec == 0) ? (bf16*)o0 : (bf16*)o1;
            dst[(size_t)grow * DD + c] = __float2bfloat16(o);
          } else if (sec == 2) {
            ((bf16*)o2)[(size_t)grow * DD + c] = __float2bfloat16(v);
          } else {
            ((float*)o3)[(size_t)grow * DD + c] = v;
          }
        }
      }
  } else {
    #pragma unroll
    for (int mt = 0; mt < 4; ++mt)
      #pragma unroll
      for (int nt = 0; nt < 4; ++nt) {
        const int gcol = bn + wc * 64 + nt * 16 + ln;
        #pragma unroll
        for (int r = 0; r < 4; ++r) {
          const int grow = bm + wr * 64 + mt * 16 + lg * 4 + r;
          float v = acc[mt][nt][r];
          if constexpr (EPI == E_BGELU) {
            v += bias[gcol];
            v = 0.5f * v * (1.0f + erff(v * 0.70710678118654752f));
            ((bf16*)o0)[(size_t)grow * N + gcol] = __float2bfloat16(v);
          } else if constexpr (EPI == E_RES) {
            v += res[(size_t)grow * N + gcol];
            ((float*)o0)[(size_t)grow * N + gcol] = v;
          } else { // E_BRES
            v += bias[gcol] + res[(size_t)grow * N + gcol];
            ((float*)o0)[(size_t)grow * N + gcol] = v;
          }
        }
      }
  }
}

// ---------------- Retention via MFMA: y = (q k^T * g^(n-m), causal) @ v ----------------
__global__ __launch_bounds__(256) void attn_k(const bf16* __restrict__ qg, const bf16* __restrict__ kg,
    const bf16* __restrict__ vg, float* __restrict__ y)
{
  __shared__ __align__(16) ushort_t Ks[64 * 32];
  __shared__ __align__(16) ushort_t Vt[32 * 66];
  __shared__ __align__(16) unsigned int Pl[4 * 512];

  const int bh = blockIdx.x;
  const int b = bh >> 3, h = bh & (HH - 1);
  const int n0 = blockIdx.y * 64;
  const int tid = threadIdx.x;
  const int w = tid >> 6, lane = tid & 63;
  const int lg = lane >> 4, ln = lane & 15;

  const size_t base = (size_t)b * SS * DD + h * HDD;
  const ushort_t* qp = (const ushort_t*)qg + base;
  const ushort_t* kp = (const ushort_t*)kg + base;
  const ushort_t* vp = (const ushort_t*)vg + base;

  const int n = n0 + w * 16 + ln;
  const short8v qf = *(const short8v*)(qp + (size_t)n * DD + lg * 8);

  const float onemg = expf(-3.4657359028f - 0.3960841187f * (float)h);
  const float l2g = log2f(1.0f - onemg);
  float em[4][4];
  #pragma unroll
  for (int mt = 0; mt < 4; ++mt)
    #pragma unroll
    for (int r = 0; r < 4; ++r)
      em[mt][r] = exp2f(-l2g * (float)(mt * 16 + lg * 4 + r));

  f32x4 acc0 = {0.f, 0.f, 0.f, 0.f};
  f32x4 acc1 = {0.f, 0.f, 0.f, 0.f};

  const int Wwin = (int)(20.0f / (-l2g)) + 1;
  int m_lo = 0;
  if (n0 > Wwin) m_lo = ((n0 - Wwin) >> 6) << 6;

  const int srow = tid >> 2;
  const int sc = tid & 3;
  const unsigned int* vt32 = (const unsigned int*)Vt;

  for (int m0 = m_lo; m0 <= n0; m0 += 64) {
    __syncthreads();
    {
      short8v kv = *(const short8v*)(kp + (size_t)(m0 + srow) * DD + sc * 8);
      *(short8v*)&Ks[srow * 32 + ((sc ^ ((srow >> 1) & 3)) << 3)] = kv;
      short8v vv = *(const short8v*)(vp + (size_t)(m0 + srow) * DD + sc * 8);
      #pragma unroll
      for (int j = 0; j < 8; ++j)
        Vt[(sc * 8 + j) * 66 + ((((srow >> 3) ^ j)) << 3) + (srow & 7)] = (ushort_t)vv[j];
    }
    __syncthreads();

    const float fn = exp2f(l2g * (float)(n - m0));
    #pragma unroll
    for (int mt = 0; mt < 4; ++mt) {
      const int krow = mt * 16 + ln;
      short8v kf = *(const short8v*)&Ks[krow * 32 + ((lg ^ ((krow >> 1) & 3)) << 3)];
      f32x4 z = {0.f, 0.f, 0.f, 0.f};
      f32x4 pa = __builtin_amdgcn_mfma_f32_16x16x32_bf16(kf, qf, z, 0, 0, 0);
      unsigned int pk0, pk1;
      {
        int m = m0 + mt * 16 + lg * 4;
        float v0 = (n < m)     ? 0.f : pa[0] * fn * em[mt][0];
        float v1 = (n < m + 1) ? 0.f : pa[1] * fn * em[mt][1];
        float v2 = (n < m + 2) ? 0.f : pa[2] * fn * em[mt][2];
        float v3 = (n < m + 3) ? 0.f : pa[3] * fn * em[mt][3];
        pk0 = ((unsigned int)f2bu(v1) << 16) | f2bu(v0);
        pk1 = ((unsigned int)f2bu(v3) << 16) | f2bu(v2);
      }
      const int blk = (mt * 2 + (lg >> 1)) ^ (ln & 7);
      Pl[w * 512 + ln * 32 + blk * 4 + (lg & 1) * 2 + 0] = pk0;
      Pl[w * 512 + ln * 32 + blk * 4 + (lg & 1) * 2 + 1] = pk1;
    }
    #pragma unroll
    for (int hh = 0; hh < 2; ++hh) {
      const int pblk = (lg + 4 * hh) ^ (ln & 7);
      uint4v pw = *(const uint4v*)&Pl[w * 512 + ln * 32 + pblk * 4];
      short8v pf = __builtin_bit_cast(short8v, pw);
      #pragma unroll
      for (int dt = 0; dt < 2; ++dt) {
        const int d = dt * 16 + ln;
        const int vb = (lg + 4 * hh) ^ (ln & 7);
        uint4v vw;
        vw.x = vt32[d * 33 + vb * 4 + 0];
        vw.y = vt32[d * 33 + vb * 4 + 1];
        vw.z = vt32[d * 33 + vb * 4 + 2];
        vw.w = vt32[d * 33 + vb * 4 + 3];
        short8v vf = __builtin_bit_cast(short8v, vw);
        if (dt == 0) acc0 = __builtin_amdgcn_mfma_f32_16x16x32_bf16(vf, pf, acc0, 0, 0, 0);
        else         acc1 = __builtin_amdgcn_mfma_f32_16x16x32_bf16(vf, pf, acc1, 0, 0, 0);
      }
    }
  }

  float* yp = y + (size_t)b * SS * DD + h * HDD;
  #pragma unroll
  for (int r = 0; r < 4; ++r) {
    yp[(size_t)n * DD + lg * 4 + r]      = acc0[r];
    yp[(size_t)n * DD + 16 + lg * 4 + r] = acc1[r];
  }
}

// ---------------- per-head GroupNorm + gn affine + SiLU(g) gate -> bf16 ----------------
__global__ __launch_bounds__(256) void gn_silu_k(const float* __restrict__ y, const float* __restrict__ g,
    const float* __restrict__ gw, const float* __restrict__ gb, bf16* __restrict__ u)
{
  int bs = blockIdx.x;
  int t = threadIdx.x;
  float val = y[(size_t)bs * DD + t];
  float sum = val;
  #pragma unroll
  for (int m = 16; m >= 1; m >>= 1) sum += __shfl_xor(sum, m);
  float mu = sum * (1.0f / 32.0f);
  float df = val - mu;
  float s2 = df * df;
  #pragma unroll
  for (int m = 16; m >= 1; m >>= 1) s2 += __shfl_xor(s2, m);
  float var = s2 * (1.0f / 32.0f);
  float yn = df * rsqrtf(var + 1e-5f) * gw[t] + gb[t];
  float gg = g[(size_t)bs * DD + t];
  float sig = 1.0f / (1.0f + expf(-gg));
  u[(size_t)bs * DD + t] = __float2bfloat16(gg * sig * yn);
}

extern "C" void kernel_launch(void* const* d_in, const int* in_sizes, int n_in,
                              void* d_out, int out_size, void* d_ws, size_t ws_size,
                              hipStream_t stream)
{
  const float* X    = (const float*)d_in[0];
  const float* Wq   = (const float*)d_in[1];
  const float* Wk   = (const float*)d_in[2];
  const float* Wv   = (const float*)d_in[3];
  const float* Wg   = (const float*)d_in[4];
  const float* Wo   = (const float*)d_in[5];
  const float* gnw  = (const float*)d_in[6];
  const float* gnb  = (const float*)d_in[7];
  const float* ln1w = (const float*)d_in[8];
  const float* ln1b = (const float*)d_in[9];
  const float* ln2w = (const float*)d_in[10];
  const float* ln2b = (const float*)d_in[11];
  const float* w1   = (const float*)d_in[12];
  const float* b1   = (const float*)d_in[13];
  const float* w2   = (const float*)d_in[14];
  const float* b2   = (const float*)d_in[15];
  const float* lnfw = (const float*)d_in[16];
  const float* lnfb = (const float*)d_in[17];

  // Workspace (~47.6 MiB)
  char* p = (char*)d_ws;
  const size_t AF  = (size_t)MM * DD * sizeof(float);  // 8 MiB
  const size_t ABF = (size_t)MM * DD * sizeof(bf16);   // 4 MiB
  bf16*  xn   = (bf16*)p;  p += ABF;
  bf16*  qb   = (bf16*)p;  p += ABF;   // h1 (16 MiB bf16) aliases qb..ub
  bf16*  kb   = (bf16*)p;  p += ABF;
  bf16*  vb   = (bf16*)p;  p += ABF;
  bf16*  ub   = (bf16*)p;  p += ABF;
  float* gbuf = (float*)p; p += AF;
  float* ybuf = (float*)p; p += AF;
  float* yres = (float*)p; p += AF;
  bf16*  wqkvgt = (bf16*)p; p += (size_t)2 * 1024 * 256 * sizeof(bf16);
  bf16*  wot    = (bf16*)p; p += (size_t)2 * 256 * 256 * sizeof(bf16);
  bf16*  w1t    = (bf16*)p; p += (size_t)2 * 1024 * 256 * sizeof(bf16);
  bf16*  w2t    = (bf16*)p; p += (size_t)2 * 256 * 1024 * sizeof(bf16);
  float* tsn  = (float*)p; p += SS * 16 * sizeof(float);
  float* tcs  = (float*)p; p += SS * 16 * sizeof(float);
  float* tsc  = (float*)p; p += SS * 16 * sizeof(float);
  bf16*  h1   = qb;                    // MM*FFD bf16 = 16 MiB

  tables_k<<<dim3((SS * 16 + 255) / 256), dim3(256), 0, stream>>>(tsn, tcs, tsc);

  {
    WDescA da;
    for (int l = 0; l < 2; ++l) {
      da.d[l * 7 + 0] = { Wq + (size_t)l * 65536, wqkvgt + (size_t)l * 262144 + 0 * 65536, 256, 256 };
      da.d[l * 7 + 1] = { Wk + (size_t)l * 65536, wqkvgt + (size_t)l * 262144 + 1 * 65536, 256, 256 };
      da.d[l * 7 + 2] = { Wv + (size_t)l * 65536, wqkvgt + (size_t)l * 262144 + 2 * 65536, 256, 256 };
      da.d[l * 7 + 3] = { Wg + (size_t)l * 65536, wqkvgt + (size_t)l * 262144 + 3 * 65536, 256, 256 };
      da.d[l * 7 + 4] = { Wo + (size_t)l * 65536, wot + (size_t)l * 65536, 256, 256 };
      da.d[l * 7 + 5] = { w1 + (size_t)l * 262144, w1t + (size_t)l * 262144, 256, 1024 };
      da.d[l * 7 + 6] = { w2 + (size_t)l * 262144, w2t + (size_t)l * 262144, 1024, 256 };
    }
    wconv_k<<<dim3(32, 32, 14), dim3(32, 8), 0, stream>>>(da);
  }

  const float* xin = X;
  for (int l = 0; l < LYR; ++l) {
    ln_k<bf16><<<dim3(MM), 256, 0, stream>>>(xin, ln1w + l * DD, ln1b + l * DD, xn);
    mgemm_k<DD, E_QKVG><<<dim3(MM / 128, 1024 / 128), 256, 0, stream>>>(
        xn, wqkvgt + (size_t)l * 262144, nullptr, nullptr, qb, kb, vb, gbuf, 1024, tsn, tcs, tsc);
    attn_k<<<dim3(BB * HH, SS / 64), 256, 0, stream>>>(qb, kb, vb, ybuf);
    gn_silu_k<<<dim3(MM), 256, 0, stream>>>(ybuf, gbuf, gnw + l * DD, gnb + l * DD, ub);
    mgemm_k<DD, E_RES><<<dim3(MM / 128, 256 / 128), 256, 0, stream>>>(
        ub, wot + (size_t)l * 65536, nullptr, xin, yres, nullptr, nullptr, nullptr, 256, tsn, tcs, tsc);
    ln_k<bf16><<<dim3(MM), 256, 0, stream>>>(yres, ln2w + l * DD, ln2b + l * DD, xn);
    mgemm_k<DD, E_BGELU><<<dim3(MM / 128, FFD / 128), 256, 0, stream>>>(
        xn, w1t + (size_t)l * 262144, b1 + l * FFD, nullptr, h1, nullptr, nullptr, nullptr, FFD, tsn, tcs, tsc);
    mgemm_k<FFD, E_BRES><<<dim3(MM / 128, 256 / 128), 256, 0, stream>>>(
        h1, w2t + (size_t)l * 262144, b2 + l * DD, yres, yres, nullptr, nullptr, nullptr, 256, tsn, tcs, tsc);
    if (l == LYR - 1) {
      ln_k<float><<<dim3(MM), 256, 0, stream>>>(yres, lnfw, lnfb, (float*)d_out);
    } else {
      ln_k<float><<<dim3(MM), 256, 0, stream>>>(yres, lnfw, lnfb, yres);
      xin = yres;
    }
  }
}

// Round 8
// 283.457 us; speedup vs baseline: 5.7563x; 1.1996x over previous
//
#include <hip/hip_runtime.h>
#include <hip/hip_bf16.h>

typedef __hip_bfloat16 bf16;
typedef unsigned short ushort_t;
typedef __attribute__((ext_vector_type(8))) short short8v;
typedef __attribute__((ext_vector_type(4))) float f32x4;
typedef __attribute__((ext_vector_type(4))) unsigned int uint4v;

// RetNet block: L=2, B=4, S=2048, D=256, H=8, HD=32, FFN*D=1024
#define LYR 2
#define BB 4
#define SS 2048
#define DD 256
#define HH 8
#define HDD 32
#define FFD 1024
#define MM (BB*SS)   // 8192 tokens

__device__ __forceinline__ unsigned short f2bu(float f) {
  union { float f; unsigned int u; } c; c.f = f;
  unsigned int r = (c.u + 0x7fffu + ((c.u >> 16) & 1u)) >> 16;
  return (unsigned short)r;
}

__device__ __forceinline__ void gload_lds16(const void* g, void* l) {
  __builtin_amdgcn_global_load_lds((const __attribute__((address_space(1))) void*)g,
                                   (__attribute__((address_space(3))) void*)l, 16, 0, 0);
}

// ---------------- xPos tables (sin/cos/scale, S x 16) ----------------
__global__ void tables_k(float* __restrict__ sn, float* __restrict__ cs, float* __restrict__ sc) {
  int i = blockIdx.x * 256 + threadIdx.x;
  if (i >= SS * 16) return;
  int s = i >> 4, j = i & 15;
  float sv = (2.0f * (float)j + 0.4f * (float)HDD) / (1.4f * (float)HDD);
  sc[i] = powf(sv, (float)s * (1.0f / 512.0f));
  float inv_freq = powf(10000.0f, -(float)j * (1.0f / 16.0f));
  float ang = (float)s * inv_freq;
  sn[i] = sinf(ang);
  cs[i] = cosf(ang);
}

// ---------------- weight transpose+convert: Wt[n][k] = bf16(W[k][n]) ----------------
struct WDesc { const float* src; bf16* dst; int K; int N; };
struct WDescA { WDesc d[14]; };
__global__ __launch_bounds__(256) void wconv_k(WDescA da) {
  WDesc dd = da.d[blockIdx.z];
  int n0 = blockIdx.x * 32, k0 = blockIdx.y * 32;
  if (n0 >= dd.N || k0 >= dd.K) return;
  __shared__ float t[32][33];
  int tx = threadIdx.x, ty = threadIdx.y;   // 32 x 8
  #pragma unroll
  for (int i = 0; i < 32; i += 8) t[ty + i][tx] = dd.src[(size_t)(k0 + ty + i) * dd.N + n0 + tx];
  __syncthreads();
  #pragma unroll
  for (int i = 0; i < 32; i += 8) dd.dst[(size_t)(n0 + ty + i) * dd.K + k0 + tx] = __float2bfloat16(t[tx][ty + i]);
}

// ---------------- LayerNorm over D=256 (one block per row), f32 in, OT out ----------------
template<typename OT>
__global__ __launch_bounds__(256) void ln_k(const float* __restrict__ in, const float* __restrict__ w,
    const float* __restrict__ b, OT* __restrict__ out)
{
  int row = blockIdx.x, t = threadIdx.x;
  float v = in[(size_t)row * DD + t];
  __shared__ float red[4];
  float s = v;
  #pragma unroll
  for (int m = 32; m >= 1; m >>= 1) s += __shfl_xor(s, m);
  if ((t & 63) == 0) red[t >> 6] = s;
  __syncthreads();
  float mu = (red[0] + red[1] + red[2] + red[3]) * (1.0f / 256.0f);
  float d = v - mu;
  float s2 = d * d;
  #pragma unroll
  for (int m = 32; m >= 1; m >>= 1) s2 += __shfl_xor(s2, m);
  __syncthreads();
  if ((t & 63) == 0) red[t >> 6] = s2;
  __syncthreads();
  float var = (red[0] + red[1] + red[2] + red[3]) * (1.0f / 256.0f);
  float o = d * rsqrtf(var + 1e-5f) * w[t] + b[t];
  if constexpr (sizeof(OT) == 2) out[(size_t)row * DD + t] = __float2bfloat16(o);
  else                           out[(size_t)row * DD + t] = o;
}

// ---------------- bf16 MFMA GEMM: C(M x N) = A(M x K) @ Wt(N,K)^T ----------------
// BM x 128 tile, BK=64, 4 waves (2x2). E_QKVG writes Q,K row-major (xPos), V transposed, G f32.
enum { E_QKVG = 0, E_RES = 1, E_BGELU = 2, E_BRES = 3 };

template<int BM, int K, int EPI>
__global__ __launch_bounds__(256) void mgemm_k(const bf16* __restrict__ Ag, const bf16* __restrict__ Wt,
    const float* __restrict__ bias, const float* res,
    void* o0, void* o1, void* o2, void* o3, int N,
    const float* __restrict__ tsn, const float* __restrict__ tcs, const float* __restrict__ tsc)
{
  constexpr int MT = BM / 32;        // 16-tiles per wave (M)
  constexpr int WMH = BM / 2;        // wave M extent
  __shared__ __align__(16) ushort_t Al[BM * 64];
  __shared__ __align__(16) ushort_t Bl[128 * 64];
  const int bm = blockIdx.x * BM;
  const int bn = blockIdx.y * 128;
  const int tid = threadIdx.x;
  const int lane = tid & 63, w = tid >> 6;
  const int lg = lane >> 4, ln = lane & 15;
  const int wr = w >> 1, wc = w & 1;
  const ushort_t* Au = (const ushort_t*)Ag;
  const ushort_t* Bu = (const ushort_t*)Wt;
  f32x4 acc[MT][4] = {};

  for (int k0 = 0; k0 < K; k0 += 64) {
    __syncthreads();
    #pragma unroll
    for (int i = 0; i < BM / 32; ++i) {
      int slot = i * 256 + tid;
      int row = slot >> 3, blk = slot & 7;
      gload_lds16(Au + (size_t)(bm + row) * K + k0 + (blk ^ (row & 7)) * 8, Al + slot * 8);
    }
    #pragma unroll
    for (int i = 0; i < 4; ++i) {
      int slot = i * 256 + tid;
      int row = slot >> 3, blk = slot & 7;
      gload_lds16(Bu + (size_t)(bn + row) * K + k0 + (blk ^ (row & 7)) * 8, Bl + slot * 8);
    }
    __syncthreads();
    #pragma unroll
    for (int kh = 0; kh < 2; ++kh) {
      short8v af[MT], bfr[4];
      #pragma unroll
      for (int mt = 0; mt < MT; ++mt) {
        int row = wr * WMH + mt * 16 + ln;
        af[mt] = *(const short8v*)&Al[row * 64 + (((kh * 4 + lg) ^ (row & 7))) * 8];
      }
      #pragma unroll
      for (int nt = 0; nt < 4; ++nt) {
        int row = wc * 64 + nt * 16 + ln;
        bfr[nt] = *(const short8v*)&Bl[row * 64 + (((kh * 4 + lg) ^ (row & 7))) * 8];
      }
      #pragma unroll
      for (int mt = 0; mt < MT; ++mt)
        #pragma unroll
        for (int nt = 0; nt < 4; ++nt)
          acc[mt][nt] = __builtin_amdgcn_mfma_f32_16x16x32_bf16(af[mt], bfr[nt], acc[mt][nt], 0, 0, 0);
    }
  }

  if constexpr (EPI == E_QKVG) {
    #pragma unroll
    for (int mt = 0; mt < MT; ++mt)
      #pragma unroll
      for (int nt = 0; nt < 4; ++nt) {
        const int colbase = bn + wc * 64 + nt * 16;
        const int sec = colbase >> 8;          // 0=Q 1=K 2=V 3=G
        const int c = (colbase & 255) + ln;
        const int grow0 = bm + wr * WMH + mt * 16 + lg * 4;
        if (sec <= 1) {
          const int jj = (c & 31) >> 1;
          #pragma unroll
          for (int r = 0; r < 4; ++r) {
            const int grow = grow0 + r;
            const int s = grow & (SS - 1);
            float v = acc[mt][nt][r];
            float pv = __shfl_xor(v, 1);
            float scv = tsc[s * 16 + jj];
            if (sec == 1) scv = 1.0f / scv;
            float ce = tcs[s * 16 + jj] * scv, se = tsn[s * 16 + jj] * scv;
            float o = (ln & 1) ? (v * ce + pv * se) : (v * ce - pv * se);
            bf16* dst = (sec == 0) ? (bf16*)o0 : (bf16*)o1;
            dst[(size_t)grow * DD + c] = __float2bfloat16(o);
          }
        } else if (sec == 2) {
          // V transposed: vT[(b*8+h)*32 + d][s], pack 4 consecutive s
          const int b = grow0 >> 11, s0 = grow0 & (SS - 1);
          const int h = c >> 5, d = c & 31;
          ushort4 pk;
          pk.x = f2bu(acc[mt][nt][0]); pk.y = f2bu(acc[mt][nt][1]);
          pk.z = f2bu(acc[mt][nt][2]); pk.w = f2bu(acc[mt][nt][3]);
          *(ushort4*)((ushort_t*)o2 + ((size_t)(b * 8 + h) * 32 + d) * SS + s0) = pk;
        } else {
          #pragma unroll
          for (int r = 0; r < 4; ++r)
            ((float*)o3)[(size_t)(grow0 + r) * DD + c] = acc[mt][nt][r];
        }
      }
  } else {
    #pragma unroll
    for (int mt = 0; mt < MT; ++mt)
      #pragma unroll
      for (int nt = 0; nt < 4; ++nt) {
        const int gcol = bn + wc * 64 + nt * 16 + ln;
        #pragma unroll
        for (int r = 0; r < 4; ++r) {
          const int grow = bm + wr * WMH + mt * 16 + lg * 4 + r;
          float v = acc[mt][nt][r];
          if constexpr (EPI == E_BGELU) {
            v += bias[gcol];
            v = 0.5f * v * (1.0f + erff(v * 0.70710678118654752f));
            ((bf16*)o0)[(size_t)grow * N + gcol] = __float2bfloat16(v);
          } else if constexpr (EPI == E_RES) {
            v += res[(size_t)grow * N + gcol];
            ((float*)o0)[(size_t)grow * N + gcol] = v;
          } else { // E_BRES
            v += bias[gcol] + res[(size_t)grow * N + gcol];
            ((float*)o0)[(size_t)grow * N + gcol] = v;
          }
        }
      }
  }
}

// ---------------- Retention + fused GroupNorm/SiLU-gate ----------------
// q,k row-major bf16; vT [b][h][32d][S] bf16. Output: ub bf16 (gated, normed).
// grid (B*H, S/128), block 256 = 4 waves; wave w owns rows [n0+32w, n0+32w+32) (2 Q-frags).
__global__ __launch_bounds__(256) void attn_k(const bf16* __restrict__ qg, const bf16* __restrict__ kg,
    const bf16* __restrict__ vtg, const float* __restrict__ gbuf,
    const float* __restrict__ gnw, const float* __restrict__ gnb, bf16* __restrict__ ub)
{
  __shared__ __align__(16) ushort_t Kl[2][64 * 32];      // [m][k], blk^ = row&3
  __shared__ __align__(16) ushort_t Vl[2][32 * 64];      // [d][m], blk^ = d&7
  __shared__ __align__(16) unsigned int Pl[8][512];      // per (wave,qf)

  const int bh = blockIdx.x;
  const int b = bh >> 3, h = bh & (HH - 1);
  const int n0 = blockIdx.y * 128;
  const int tid = threadIdx.x;
  const int w = tid >> 6, lane = tid & 63;
  const int lg = lane >> 4, ln = lane & 15;

  const size_t base = (size_t)b * SS * DD + h * HDD;
  const ushort_t* qp = (const ushort_t*)qg + base;
  const ushort_t* kp = (const ushort_t*)kg + base;
  const ushort_t* vtp = (const ushort_t*)vtg + (size_t)(b * 8 + h) * 32 * SS;

  const int nA = n0 + w * 32 + ln;                 // qf0 row
  const int nB = nA + 16;                          // qf1 row
  const short8v qfA = *(const short8v*)(qp + (size_t)nA * DD + lg * 8);
  const short8v qfB = *(const short8v*)(qp + (size_t)nB * DD + lg * 8);

  const float onemg = expf(-3.4657359028f - 0.3960841187f * (float)h);
  const float l2g = log2f(1.0f - onemg);           // negative
  float emr[4];
  #pragma unroll
  for (int r = 0; r < 4; ++r) emr[r] = exp2f(-l2g * (float)(lg * 4 + r));
  const float e16 = exp2f(-l2g * 16.0f);

  f32x4 accA0 = {0,0,0,0}, accA1 = {0,0,0,0}, accB0 = {0,0,0,0}, accB1 = {0,0,0,0};

  const int Wwin = (int)(20.0f / (-l2g)) + 1;
  int m_lo = 0;
  if (n0 > Wwin) m_lo = ((n0 - Wwin) >> 6) << 6;
  const int m_hi = n0 + 64;                        // last tile base (covers rows to n0+127)
  const int wave_hi = n0 + w * 32 + 31;
  const int wave_lo = n0 + w * 32;

  const int Krow = tid >> 2, Kc8 = tid & 3;
  const int Vrow = tid >> 3, Vc8 = tid & 7;

  #define STAGE(buf, m0s) { \
    gload_lds16(kp + (size_t)((m0s) + Krow) * DD + ((Kc8 ^ (Krow & 3)) * 8), &Kl[buf][tid * 8]); \
    gload_lds16(vtp + (size_t)Vrow * SS + (m0s) + ((Vc8 ^ (Vrow & 7)) * 8), &Vl[buf][tid * 8]); }

  STAGE(0, m_lo)
  asm volatile("s_waitcnt vmcnt(0)");
  __syncthreads();

  int cur = 0;
  for (int m0 = m_lo; m0 <= m_hi; m0 += 64) {
    if (m0 + 64 <= m_hi) STAGE(cur ^ 1, m0 + 64)
    const bool active = (m0 <= wave_hi) && (m0 + 63 >= wave_lo - Wwin);
    if (active) {
      const float fnA = exp2f(l2g * (float)(nA - m0));
      const float fnB = exp2f(l2g * (float)(nB - m0));
      float emt = 1.0f;
      #pragma unroll
      for (int mt = 0; mt < 4; ++mt) {
        const int krow = mt * 16 + ln;
        short8v kf = *(const short8v*)&Kl[cur][krow * 32 + ((lg ^ (krow & 3)) << 3)];
        f32x4 z = {0,0,0,0};
        f32x4 paA = __builtin_amdgcn_mfma_f32_16x16x32_bf16(kf, qfA, z, 0, 0, 0);
        f32x4 paB = __builtin_amdgcn_mfma_f32_16x16x32_bf16(kf, qfB, z, 0, 0, 0);
        const int m = m0 + mt * 16 + lg * 4;
        const int blk = (mt * 2 + (lg >> 1)) ^ (ln & 7);
        {
          float v0 = (nA < m)     ? 0.f : paA[0] * fnA * (emr[0] * emt);
          float v1 = (nA < m + 1) ? 0.f : paA[1] * fnA * (emr[1] * emt);
          float v2 = (nA < m + 2) ? 0.f : paA[2] * fnA * (emr[2] * emt);
          float v3 = (nA < m + 3) ? 0.f : paA[3] * fnA * (emr[3] * emt);
          Pl[w * 2 + 0][ln * 32 + blk * 4 + (lg & 1) * 2 + 0] = ((unsigned int)f2bu(v1) << 16) | f2bu(v0);
          Pl[w * 2 + 0][ln * 32 + blk * 4 + (lg & 1) * 2 + 1] = ((unsigned int)f2bu(v3) << 16) | f2bu(v2);
        }
        {
          float v0 = (nB < m)     ? 0.f : paB[0] * fnB * (emr[0] * emt);
          float v1 = (nB < m + 1) ? 0.f : paB[1] * fnB * (emr[1] * emt);
          float v2 = (nB < m + 2) ? 0.f : paB[2] * fnB * (emr[2] * emt);
          float v3 = (nB < m + 3) ? 0.f : paB[3] * fnB * (emr[3] * emt);
          Pl[w * 2 + 1][ln * 32 + blk * 4 + (lg & 1) * 2 + 0] = ((unsigned int)f2bu(v1) << 16) | f2bu(v0);
          Pl[w * 2 + 1][ln * 32 + blk * 4 + (lg & 1) * 2 + 1] = ((unsigned int)f2bu(v3) << 16) | f2bu(v2);
        }
        emt *= e16;
      }
      #pragma unroll
      for (int hh = 0; hh < 2; ++hh) {
        const int pblk = (lg + 4 * hh) ^ (ln & 7);
        uint4v pwA = *(const uint4v*)&Pl[w * 2 + 0][ln * 32 + pblk * 4];
        uint4v pwB = *(const uint4v*)&Pl[w * 2 + 1][ln * 32 + pblk * 4];
        short8v pfA = __builtin_bit_cast(short8v, pwA);
        short8v pfB = __builtin_bit_cast(short8v, pwB);
        #pragma unroll
        for (int dt = 0; dt < 2; ++dt) {
          const int d = dt * 16 + ln;
          short8v vf = *(const short8v*)&Vl[cur][d * 64 + (((hh * 4 + lg) ^ (d & 7)) << 3)];
          if (dt == 0) {
            accA0 = __builtin_amdgcn_mfma_f32_16x16x32_bf16(vf, pfA, accA0, 0, 0, 0);
            accB0 = __builtin_amdgcn_mfma_f32_16x16x32_bf16(vf, pfB, accB0, 0, 0, 0);
          } else {
            accA1 = __builtin_amdgcn_mfma_f32_16x16x32_bf16(vf, pfA, accA1, 0, 0, 0);
            accB1 = __builtin_amdgcn_mfma_f32_16x16x32_bf16(vf, pfB, accB1, 0, 0, 0);
          }
        }
      }
    }
    asm volatile("s_waitcnt vmcnt(0)");
    __syncthreads();
    cur ^= 1;
  }
  #undef STAGE

  // ---- fused GroupNorm (per head, 32 d across 4 lane-groups) + SiLU gate ----
  float gwv[8], gbv[8];
  #pragma unroll
  for (int dt = 0; dt < 2; ++dt) {
    f32x4 a = *(const f32x4*)&gnw[h * 32 + dt * 16 + lg * 4];
    f32x4 c = *(const f32x4*)&gnb[h * 32 + dt * 16 + lg * 4];
    #pragma unroll
    for (int r = 0; r < 4; ++r) { gwv[dt * 4 + r] = a[r]; gbv[dt * 4 + r] = c[r]; }
  }
  #pragma unroll
  for (int qf = 0; qf < 2; ++qf) {
    const int n = (qf == 0) ? nA : nB;
    f32x4 y0 = (qf == 0) ? accA0 : accB0;
    f32x4 y1 = (qf == 0) ? accA1 : accB1;
    float s = 0.f;
    #pragma unroll
    for (int r = 0; r < 4; ++r) s += y0[r] + y1[r];
    s += __shfl_xor(s, 16); s += __shfl_xor(s, 32);
    const float mu = s * (1.0f / 32.0f);
    float s2 = 0.f;
    #pragma unroll
    for (int r = 0; r < 4; ++r) { float d0 = y0[r] - mu, d1 = y1[r] - mu; s2 += d0 * d0 + d1 * d1; }
    s2 += __shfl_xor(s2, 16); s2 += __shfl_xor(s2, 32);
    const float rs = rsqrtf(s2 * (1.0f / 32.0f) + 1e-5f);
    const size_t rowoff = ((size_t)b * SS + n) * DD + h * 32;
    #pragma unroll
    for (int dt = 0; dt < 2; ++dt) {
      f32x4 yv = dt ? y1 : y0;
      f32x4 gv = *(const f32x4*)&gbuf[rowoff + dt * 16 + lg * 4];
      uint2 pk;
      float o0, o1;
      {
        float yn0 = (yv[0] - mu) * rs * gwv[dt * 4 + 0] + gbv[dt * 4 + 0];
        float yn1 = (yv[1] - mu) * rs * gwv[dt * 4 + 1] + gbv[dt * 4 + 1];
        o0 = gv[0] / (1.0f + expf(-gv[0])) * yn0;
        o1 = gv[1] / (1.0f + expf(-gv[1])) * yn1;
        pk.x = ((unsigned int)f2bu(o1) << 16) | f2bu(o0);
        float yn2 = (yv[2] - mu) * rs * gwv[dt * 4 + 2] + gbv[dt * 4 + 2];
        float yn3 = (yv[3] - mu) * rs * gwv[dt * 4 + 3] + gbv[dt * 4 + 3];
        o0 = gv[2] / (1.0f + expf(-gv[2])) * yn2;
        o1 = gv[3] / (1.0f + expf(-gv[3])) * yn3;
        pk.y = ((unsigned int)f2bu(o1) << 16) | f2bu(o0);
      }
      *(uint2*)((ushort_t*)ub + rowoff + dt * 16 + lg * 4) = pk;
    }
  }
}

extern "C" void kernel_launch(void* const* d_in, const int* in_sizes, int n_in,
                              void* d_out, int out_size, void* d_ws, size_t ws_size,
                              hipStream_t stream)
{
  const float* X    = (const float*)d_in[0];
  const float* Wq   = (const float*)d_in[1];
  const float* Wk   = (const float*)d_in[2];
  const float* Wv   = (const float*)d_in[3];
  const float* Wg   = (const float*)d_in[4];
  const float* Wo   = (const float*)d_in[5];
  const float* gnw  = (const float*)d_in[6];
  const float* gnb  = (const float*)d_in[7];
  const float* ln1w = (const float*)d_in[8];
  const float* ln1b = (const float*)d_in[9];
  const float* ln2w = (const float*)d_in[10];
  const float* ln2b = (const float*)d_in[11];
  const float* w1   = (const float*)d_in[12];
  const float* b1   = (const float*)d_in[13];
  const float* w2   = (const float*)d_in[14];
  const float* b2   = (const float*)d_in[15];
  const float* lnfw = (const float*)d_in[16];
  const float* lnfb = (const float*)d_in[17];

  // Workspace (~40 MiB)
  char* p = (char*)d_ws;
  const size_t AF  = (size_t)MM * DD * sizeof(float);  // 8 MiB
  const size_t ABF = (size_t)MM * DD * sizeof(bf16);   // 4 MiB
  bf16*  xn   = (bf16*)p;  p += ABF;
  bf16*  qb   = (bf16*)p;  p += ABF;   // h1 (16 MiB bf16) aliases qb..ub
  bf16*  kb   = (bf16*)p;  p += ABF;
  bf16*  vT   = (bf16*)p;  p += ABF;   // [B][H][32][S]
  bf16*  ub   = (bf16*)p;  p += ABF;
  float* gbuf = (float*)p; p += AF;
  float* yres = (float*)p; p += AF;
  bf16*  wqkvgt = (bf16*)p; p += (size_t)2 * 1024 * 256 * sizeof(bf16);
  bf16*  wot    = (bf16*)p; p += (size_t)2 * 256 * 256 * sizeof(bf16);
  bf16*  w1t    = (bf16*)p; p += (size_t)2 * 1024 * 256 * sizeof(bf16);
  bf16*  w2t    = (bf16*)p; p += (size_t)2 * 256 * 1024 * sizeof(bf16);
  float* tsn  = (float*)p; p += SS * 16 * sizeof(float);
  float* tcs  = (float*)p; p += SS * 16 * sizeof(float);
  float* tsc  = (float*)p; p += SS * 16 * sizeof(float);
  bf16*  h1   = qb;                    // MM*FFD bf16 = 16 MiB

  tables_k<<<dim3((SS * 16 + 255) / 256), dim3(256), 0, stream>>>(tsn, tcs, tsc);

  {
    WDescA da;
    for (int l = 0; l < 2; ++l) {
      da.d[l * 7 + 0] = { Wq + (size_t)l * 65536, wqkvgt + (size_t)l * 262144 + 0 * 65536, 256, 256 };
      da.d[l * 7 + 1] = { Wk + (size_t)l * 65536, wqkvgt + (size_t)l * 262144 + 1 * 65536, 256, 256 };
      da.d[l * 7 + 2] = { Wv + (size_t)l * 65536, wqkvgt + (size_t)l * 262144 + 2 * 65536, 256, 256 };
      da.d[l * 7 + 3] = { Wg + (size_t)l * 65536, wqkvgt + (size_t)l * 262144 + 3 * 65536, 256, 256 };
      da.d[l * 7 + 4] = { Wo + (size_t)l * 65536, wot + (size_t)l * 65536, 256, 256 };
      da.d[l * 7 + 5] = { w1 + (size_t)l * 262144, w1t + (size_t)l * 262144, 256, 1024 };
      da.d[l * 7 + 6] = { w2 + (size_t)l * 262144, w2t + (size_t)l * 262144, 1024, 256 };
    }
    wconv_k<<<dim3(32, 32, 14), dim3(32, 8), 0, stream>>>(da);
  }

  const float* xin = X;
  for (int l = 0; l < LYR; ++l) {
    ln_k<bf16><<<dim3(MM), 256, 0, stream>>>(xin, ln1w + l * DD, ln1b + l * DD, xn);
    mgemm_k<128, DD, E_QKVG><<<dim3(MM / 128, 1024 / 128), 256, 0, stream>>>(
        xn, wqkvgt + (size_t)l * 262144, nullptr, nullptr, qb, kb, vT, gbuf, 1024, tsn, tcs, tsc);
    attn_k<<<dim3(BB * HH, SS / 128), 256, 0, stream>>>(qb, kb, vT, gbuf, gnw + l * DD, gnb + l * DD, ub);
    mgemm_k<64, DD, E_RES><<<dim3(MM / 64, 256 / 128), 256, 0, stream>>>(
        ub, wot + (size_t)l * 65536, nullptr, xin, yres, nullptr, nullptr, nullptr, 256, tsn, tcs, tsc);
    ln_k<bf16><<<dim3(MM), 256, 0, stream>>>(yres, ln2w + l * DD, ln2b + l * DD, xn);
    mgemm_k<128, DD, E_BGELU><<<dim3(MM / 128, FFD / 128), 256, 0, stream>>>(
        xn, w1t + (size_t)l * 262144, b1 + l * FFD, nullptr, h1, nullptr, nullptr, nullptr, FFD, tsn, tcs, tsc);
    mgemm_k<64, FFD, E_BRES><<<dim3(MM / 64, 256 / 128), 256, 0, stream>>>(
        h1, w2t + (size_t)l * 262144, b2 + l * DD, yres, yres, nullptr, nullptr, nullptr, 256, tsn, tcs, tsc);
    if (l == LYR - 1) {
      ln_k<float><<<dim3(MM), 256, 0, stream>>>(yres, lnfw, lnfb, (float*)d_out);
    } else {
      ln_k<float><<<dim3(MM), 256, 0, stream>>>(yres, lnfw, lnfb, yres);
      xin = yres;
    }
  }
}

// Round 9
// 252.249 us; speedup vs baseline: 6.4684x; 1.1237x over previous
//
#include <hip/hip_runtime.h>
#include <hip/hip_bf16.h>

typedef __hip_bfloat16 bf16;
typedef unsigned short ushort_t;
typedef __attribute__((ext_vector_type(8))) short short8v;
typedef __attribute__((ext_vector_type(4))) float f32x4;
typedef __attribute__((ext_vector_type(4))) unsigned int uint4v;

// RetNet block: L=2, B=4, S=2048, D=256, H=8, HD=32, FFN*D=1024
#define LYR 2
#define BB 4
#define SS 2048
#define DD 256
#define HH 8
#define HDD 32
#define FFD 1024
#define MM (BB*SS)   // 8192 tokens

__device__ __forceinline__ unsigned int cvtpk(float lo, float hi) {
  unsigned int r;
  asm("v_cvt_pk_bf16_f32 %0, %1, %2" : "=v"(r) : "v"(lo), "v"(hi));
  return r;
}

__device__ __forceinline__ void gload_lds16(const void* g, void* l) {
  __builtin_amdgcn_global_load_lds((const __attribute__((address_space(1))) void*)g,
                                   (__attribute__((address_space(3))) void*)l, 16, 0, 0);
}

// ---------------- xPos tables (sin/cos/scale, S x 16) ----------------
__global__ void tables_k(float* __restrict__ sn, float* __restrict__ cs, float* __restrict__ sc) {
  int i = blockIdx.x * 256 + threadIdx.x;
  if (i >= SS * 16) return;
  int s = i >> 4, j = i & 15;
  float sv = (2.0f * (float)j + 0.4f * (float)HDD) / (1.4f * (float)HDD);
  sc[i] = powf(sv, (float)s * (1.0f / 512.0f));
  float inv_freq = powf(10000.0f, -(float)j * (1.0f / 16.0f));
  float ang = (float)s * inv_freq;
  sn[i] = sinf(ang);
  cs[i] = cosf(ang);
}

// ---------------- weight transpose+convert: Wt[n][k] = bf16(W[k][n]) ----------------
struct WDesc { const float* src; bf16* dst; int K; int N; };
struct WDescA { WDesc d[14]; };
__global__ __launch_bounds__(256) void wconv_k(WDescA da) {
  WDesc dd = da.d[blockIdx.z];
  int n0 = blockIdx.x * 32, k0 = blockIdx.y * 32;
  if (n0 >= dd.N || k0 >= dd.K) return;
  __shared__ float t[32][33];
  int tx = threadIdx.x, ty = threadIdx.y;   // 32 x 8
  #pragma unroll
  for (int i = 0; i < 32; i += 8) t[ty + i][tx] = dd.src[(size_t)(k0 + ty + i) * dd.N + n0 + tx];
  __syncthreads();
  #pragma unroll
  for (int i = 0; i < 32; i += 8) dd.dst[(size_t)(n0 + ty + i) * dd.K + k0 + tx] = __float2bfloat16(t[tx][ty + i]);
}

// ---------------- LayerNorm over D=256 (one block per row), f32 in, OT out ----------------
template<typename OT>
__global__ __launch_bounds__(256) void ln_k(const float* __restrict__ in, const float* __restrict__ w,
    const float* __restrict__ b, OT* __restrict__ out)
{
  int row = blockIdx.x, t = threadIdx.x;
  float v = in[(size_t)row * DD + t];
  __shared__ float red[4];
  float s = v;
  #pragma unroll
  for (int m = 32; m >= 1; m >>= 1) s += __shfl_xor(s, m);
  if ((t & 63) == 0) red[t >> 6] = s;
  __syncthreads();
  float mu = (red[0] + red[1] + red[2] + red[3]) * (1.0f / 256.0f);
  float d = v - mu;
  float s2 = d * d;
  #pragma unroll
  for (int m = 32; m >= 1; m >>= 1) s2 += __shfl_xor(s2, m);
  __syncthreads();
  if ((t & 63) == 0) red[t >> 6] = s2;
  __syncthreads();
  float var = (red[0] + red[1] + red[2] + red[3]) * (1.0f / 256.0f);
  float o = d * rsqrtf(var + 1e-5f) * w[t] + b[t];
  if constexpr (sizeof(OT) == 2) out[(size_t)row * DD + t] = __float2bfloat16(o);
  else                           out[(size_t)row * DD + t] = o;
}

// ---------------- bf16 MFMA GEMM, double-buffered pipeline ----------------
enum { E_QKVG = 0, E_RES = 1, E_BGELU = 2, E_BRES = 3 };

template<int BM, int BN, int K, int EPI>
__global__ __launch_bounds__(256) void mgemm_k(const bf16* __restrict__ Ag, const bf16* __restrict__ Wt,
    const float* __restrict__ bias, const float* res,
    void* o0, void* o1, void* o2, void* o3, int N,
    const float* __restrict__ tsn, const float* __restrict__ tcs, const float* __restrict__ tsc)
{
  constexpr int MT = BM / 32, NT = BN / 32;
  constexpr int WMH = BM / 2, WNH = BN / 2;
  __shared__ __align__(16) ushort_t Al[2][BM * 64];
  __shared__ __align__(16) ushort_t Bl[2][BN * 64];
  const int bm = blockIdx.x * BM;
  const int bn = blockIdx.y * BN;
  const int tid = threadIdx.x;
  const int lane = tid & 63, w = tid >> 6;
  const int lg = lane >> 4, ln = lane & 15;
  const int wr = w >> 1, wc = w & 1;
  const ushort_t* Au = (const ushort_t*)Ag;
  const ushort_t* Bu = (const ushort_t*)Wt;
  f32x4 acc[MT][NT] = {};

  #define STAGEG(buf, k0s) { \
    _Pragma("unroll") \
    for (int i = 0; i < BM / 32; ++i) { \
      int slot = i * 256 + tid; int row = slot >> 3, blk = slot & 7; \
      gload_lds16(Au + (size_t)(bm + row) * K + (k0s) + ((blk ^ (row & 7))) * 8, &Al[buf][slot * 8]); \
    } \
    _Pragma("unroll") \
    for (int i = 0; i < BN / 32; ++i) { \
      int slot = i * 256 + tid; int row = slot >> 3, blk = slot & 7; \
      gload_lds16(Bu + (size_t)(bn + row) * K + (k0s) + ((blk ^ (row & 7))) * 8, &Bl[buf][slot * 8]); \
    } }

  STAGEG(0, 0)
  asm volatile("s_waitcnt vmcnt(0)" ::: "memory");
  __builtin_amdgcn_s_barrier();

  int cur = 0;
  for (int k0 = 0; k0 < K; k0 += 64) {
    if (k0 + 64 < K) STAGEG(cur ^ 1, k0 + 64)
    #pragma unroll
    for (int kh = 0; kh < 2; ++kh) {
      short8v af[MT], bfr[NT];
      #pragma unroll
      for (int mt = 0; mt < MT; ++mt) {
        int row = wr * WMH + mt * 16 + ln;
        af[mt] = *(const short8v*)&Al[cur][row * 64 + (((kh * 4 + lg) ^ (row & 7))) * 8];
      }
      #pragma unroll
      for (int nt = 0; nt < NT; ++nt) {
        int row = wc * WNH + nt * 16 + ln;
        bfr[nt] = *(const short8v*)&Bl[cur][row * 64 + (((kh * 4 + lg) ^ (row & 7))) * 8];
      }
      #pragma unroll
      for (int mt = 0; mt < MT; ++mt)
        #pragma unroll
        for (int nt = 0; nt < NT; ++nt)
          acc[mt][nt] = __builtin_amdgcn_mfma_f32_16x16x32_bf16(af[mt], bfr[nt], acc[mt][nt], 0, 0, 0);
    }
    asm volatile("s_waitcnt vmcnt(0)" ::: "memory");
    __builtin_amdgcn_s_barrier();
    cur ^= 1;
  }
  #undef STAGEG

  if constexpr (EPI == E_QKVG) {
    #pragma unroll
    for (int mt = 0; mt < MT; ++mt)
      #pragma unroll
      for (int nt = 0; nt < NT; ++nt) {
        const int colbase = bn + wc * WNH + nt * 16;
        const int sec = colbase >> 8;          // 0=Q 1=K 2=V 3=G
        const int c = (colbase & 255) + ln;
        const int grow0 = bm + wr * WMH + mt * 16 + lg * 4;
        if (sec <= 1) {
          const int jj = (c & 31) >> 1;
          #pragma unroll
          for (int r = 0; r < 4; ++r) {
            const int grow = grow0 + r;
            const int s = grow & (SS - 1);
            float v = acc[mt][nt][r];
            float pv = __shfl_xor(v, 1);
            float scv = tsc[s * 16 + jj];
            if (sec == 1) scv = 1.0f / scv;
            float ce = tcs[s * 16 + jj] * scv, se = tsn[s * 16 + jj] * scv;
            float o = (ln & 1) ? (v * ce + pv * se) : (v * ce - pv * se);
            bf16* dst = (sec == 0) ? (bf16*)o0 : (bf16*)o1;
            dst[(size_t)grow * DD + c] = __float2bfloat16(o);
          }
        } else if (sec == 2) {
          // V transposed: vT[(b*8+h)*32 + d][s], pack 4 consecutive s
          const int b = grow0 >> 11, s0 = grow0 & (SS - 1);
          const int h = c >> 5, d = c & 31;
          uint2 pk;
          pk.x = cvtpk(acc[mt][nt][0], acc[mt][nt][1]);
          pk.y = cvtpk(acc[mt][nt][2], acc[mt][nt][3]);
          *(uint2*)((ushort_t*)o2 + ((size_t)(b * 8 + h) * 32 + d) * SS + s0) = pk;
        } else {
          #pragma unroll
          for (int r = 0; r < 4; ++r)
            ((float*)o3)[(size_t)(grow0 + r) * DD + c] = acc[mt][nt][r];
        }
      }
  } else {
    #pragma unroll
    for (int mt = 0; mt < MT; ++mt)
      #pragma unroll
      for (int nt = 0; nt < NT; ++nt) {
        const int gcol = bn + wc * WNH + nt * 16 + ln;
        #pragma unroll
        for (int r = 0; r < 4; ++r) {
          const int grow = bm + wr * WMH + mt * 16 + lg * 4 + r;
          float v = acc[mt][nt][r];
          if constexpr (EPI == E_BGELU) {
            v += bias[gcol];
            v = 0.5f * v * (1.0f + erff(v * 0.70710678118654752f));
            ((bf16*)o0)[(size_t)grow * N + gcol] = __float2bfloat16(v);
          } else if constexpr (EPI == E_RES) {
            v += res[(size_t)grow * N + gcol];
            ((float*)o0)[(size_t)grow * N + gcol] = v;
          } else { // E_BRES
            v += bias[gcol] + res[(size_t)grow * N + gcol];
            ((float*)o0)[(size_t)grow * N + gcol] = v;
          }
        }
      }
  }
}

// ---------------- Retention + fused GroupNorm/SiLU-gate ----------------
// q,k row-major bf16; vT [b][h][32d][S] bf16. Output ub bf16 (gated, normed).
// grid (B*H, S/64), block 256 = 4 waves; wave w rows [n0+16w, +16). n0 reversed for tail.
__global__ __launch_bounds__(256) void attn_k(const bf16* __restrict__ qg, const bf16* __restrict__ kg,
    const bf16* __restrict__ vtg, const float* __restrict__ gbuf,
    const float* __restrict__ gnw, const float* __restrict__ gnb, bf16* __restrict__ ub)
{
  __shared__ __align__(16) ushort_t Kl[2][64 * 32];      // [m][k], blk ^= m&3
  __shared__ __align__(16) ushort_t Vl[2][32 * 64];      // [d][m], blk ^= d&7
  __shared__ __align__(16) unsigned int Pl[4][512];      // per wave: P^T[n=ln][64 m] bf16

  const int bh = blockIdx.x;
  const int b = bh >> 3, h = bh & (HH - 1);
  const int n0 = ((int)gridDim.y - 1 - (int)blockIdx.y) * 64;
  const int tid = threadIdx.x;
  const int w = tid >> 6, lane = tid & 63;
  const int lg = lane >> 4, ln = lane & 15;

  const size_t base = (size_t)b * SS * DD + h * HDD;
  const ushort_t* qp = (const ushort_t*)qg + base;
  const ushort_t* kp = (const ushort_t*)kg + base;
  const ushort_t* vtp = (const ushort_t*)vtg + (size_t)(b * 8 + h) * 32 * SS;

  const int n = n0 + w * 16 + ln;
  const short8v qf = *(const short8v*)(qp + (size_t)n * DD + lg * 8);

  const float onemg = expf(-3.4657359028f - 0.3960841187f * (float)h);
  const float l2g = log2f(1.0f - onemg);           // negative
  float emr[4];
  #pragma unroll
  for (int r = 0; r < 4; ++r) emr[r] = exp2f(-l2g * (float)(lg * 4 + r));
  const float e16 = exp2f(-l2g * 16.0f);

  f32x4 acc0 = {0,0,0,0}, acc1 = {0,0,0,0};

  const int Wwin = (int)(20.0f / (-l2g)) + 1;
  int m_lo = 0;
  if (n0 > Wwin) m_lo = ((n0 - Wwin) >> 6) << 6;

  const int Krow = tid >> 2, Kc8 = tid & 3;
  const int Vrow = tid >> 3, Vc8 = tid & 7;

  #define STAGE(buf, m0s) { \
    gload_lds16(kp + (size_t)((m0s) + Krow) * DD + ((Kc8 ^ (Krow & 3)) * 8), &Kl[buf][tid * 8]); \
    gload_lds16(vtp + (size_t)Vrow * SS + (m0s) + ((Vc8 ^ (Vrow & 7)) * 8), &Vl[buf][tid * 8]); }

  STAGE(0, m_lo)
  asm volatile("s_waitcnt vmcnt(0)" ::: "memory");
  __builtin_amdgcn_s_barrier();

  int cur = 0;
  for (int m0 = m_lo; m0 <= n0; m0 += 64) {
    if (m0 < n0) STAGE(cur ^ 1, m0 + 64)
    const bool diag = (m0 == n0);
    // fnt = exp2(l2g*(n-m0)) chained with e16 per mt
    float fnt = exp2f(l2g * (float)(n - m0));
    #pragma unroll
    for (int mt = 0; mt < 4; ++mt) {
      const int krow = mt * 16 + ln;
      short8v kf = *(const short8v*)&Kl[cur][krow * 32 + ((lg ^ (krow & 3)) << 3)];
      f32x4 z = {0,0,0,0};
      f32x4 pa = __builtin_amdgcn_mfma_f32_16x16x32_bf16(kf, qf, z, 0, 0, 0);
      float v0 = pa[0] * (fnt * emr[0]);
      float v1 = pa[1] * (fnt * emr[1]);
      float v2 = pa[2] * (fnt * emr[2]);
      float v3 = pa[3] * (fnt * emr[3]);
      if (diag) {
        const int m = n0 + mt * 16 + lg * 4;
        v0 = (n < m)     ? 0.f : v0;
        v1 = (n < m + 1) ? 0.f : v1;
        v2 = (n < m + 2) ? 0.f : v2;
        v3 = (n < m + 3) ? 0.f : v3;
      }
      uint2 pk;
      pk.x = cvtpk(v0, v1);
      pk.y = cvtpk(v2, v3);
      const int blk = (mt * 2 + (lg >> 1)) ^ (ln & 7);
      *(uint2*)&Pl[w][ln * 32 + blk * 4 + (lg & 1) * 2] = pk;
      fnt *= e16;
    }
    #pragma unroll
    for (int hh = 0; hh < 2; ++hh) {
      const int pblk = (hh * 4 + lg) ^ (ln & 7);
      uint4v pw = *(const uint4v*)&Pl[w][ln * 32 + pblk * 4];
      short8v pf = __builtin_bit_cast(short8v, pw);
      #pragma unroll
      for (int dt = 0; dt < 2; ++dt) {
        const int d = dt * 16 + ln;
        short8v vf = *(const short8v*)&Vl[cur][d * 64 + (((hh * 4 + lg) ^ (d & 7)) << 3)];
        if (dt == 0) acc0 = __builtin_amdgcn_mfma_f32_16x16x32_bf16(vf, pf, acc0, 0, 0, 0);
        else         acc1 = __builtin_amdgcn_mfma_f32_16x16x32_bf16(vf, pf, acc1, 0, 0, 0);
      }
    }
    asm volatile("s_waitcnt vmcnt(0)" ::: "memory");
    __builtin_amdgcn_s_barrier();
    cur ^= 1;
  }
  #undef STAGE

  // ---- fused GroupNorm (per head, 32 d across 4 lane-groups) + SiLU gate ----
  float gwv[8], gbv[8];
  #pragma unroll
  for (int dt = 0; dt < 2; ++dt) {
    f32x4 a = *(const f32x4*)&gnw[h * 32 + dt * 16 + lg * 4];
    f32x4 c = *(const f32x4*)&gnb[h * 32 + dt * 16 + lg * 4];
    #pragma unroll
    for (int r = 0; r < 4; ++r) { gwv[dt * 4 + r] = a[r]; gbv[dt * 4 + r] = c[r]; }
  }
  float s = 0.f;
  #pragma unroll
  for (int r = 0; r < 4; ++r) s += acc0[r] + acc1[r];
  s += __shfl_xor(s, 16); s += __shfl_xor(s, 32);
  const float mu = s * (1.0f / 32.0f);
  float s2 = 0.f;
  #pragma unroll
  for (int r = 0; r < 4; ++r) { float d0 = acc0[r] - mu, d1 = acc1[r] - mu; s2 += d0 * d0 + d1 * d1; }
  s2 += __shfl_xor(s2, 16); s2 += __shfl_xor(s2, 32);
  const float rs = rsqrtf(s2 * (1.0f / 32.0f) + 1e-5f);
  const size_t rowoff = ((size_t)b * SS + n) * DD + h * 32;
  #pragma unroll
  for (int dt = 0; dt < 2; ++dt) {
    f32x4 yv = dt ? acc1 : acc0;
    f32x4 gv = *(const f32x4*)&gbuf[rowoff + dt * 16 + lg * 4];
    float o0, o1, o2, o3;
    {
      float yn0 = (yv[0] - mu) * rs * gwv[dt * 4 + 0] + gbv[dt * 4 + 0];
      float yn1 = (yv[1] - mu) * rs * gwv[dt * 4 + 1] + gbv[dt * 4 + 1];
      float yn2 = (yv[2] - mu) * rs * gwv[dt * 4 + 2] + gbv[dt * 4 + 2];
      float yn3 = (yv[3] - mu) * rs * gwv[dt * 4 + 3] + gbv[dt * 4 + 3];
      o0 = gv[0] / (1.0f + expf(-gv[0])) * yn0;
      o1 = gv[1] / (1.0f + expf(-gv[1])) * yn1;
      o2 = gv[2] / (1.0f + expf(-gv[2])) * yn2;
      o3 = gv[3] / (1.0f + expf(-gv[3])) * yn3;
    }
    uint2 pk;
    pk.x = cvtpk(o0, o1);
    pk.y = cvtpk(o2, o3);
    *(uint2*)((ushort_t*)ub + rowoff + dt * 16 + lg * 4) = pk;
  }
}

extern "C" void kernel_launch(void* const* d_in, const int* in_sizes, int n_in,
                              void* d_out, int out_size, void* d_ws, size_t ws_size,
                              hipStream_t stream)
{
  const float* X    = (const float*)d_in[0];
  const float* Wq   = (const float*)d_in[1];
  const float* Wk   = (const float*)d_in[2];
  const float* Wv   = (const float*)d_in[3];
  const float* Wg   = (const float*)d_in[4];
  const float* Wo   = (const float*)d_in[5];
  const float* gnw  = (const float*)d_in[6];
  const float* gnb  = (const float*)d_in[7];
  const float* ln1w = (const float*)d_in[8];
  const float* ln1b = (const float*)d_in[9];
  const float* ln2w = (const float*)d_in[10];
  const float* ln2b = (const float*)d_in[11];
  const float* w1   = (const float*)d_in[12];
  const float* b1   = (const float*)d_in[13];
  const float* w2   = (const float*)d_in[14];
  const float* b2   = (const float*)d_in[15];
  const float* lnfw = (const float*)d_in[16];
  const float* lnfb = (const float*)d_in[17];

  // Workspace (~40 MiB)
  char* p = (char*)d_ws;
  const size_t AF  = (size_t)MM * DD * sizeof(float);  // 8 MiB
  const size_t ABF = (size_t)MM * DD * sizeof(bf16);   // 4 MiB
  bf16*  xn   = (bf16*)p;  p += ABF;
  bf16*  qb   = (bf16*)p;  p += ABF;   // h1 (16 MiB bf16) aliases qb..ub
  bf16*  kb   = (bf16*)p;  p += ABF;
  bf16*  vT   = (bf16*)p;  p += ABF;   // [B][H][32][S]
  bf16*  ub   = (bf16*)p;  p += ABF;
  float* gbuf = (float*)p; p += AF;
  float* yres = (float*)p; p += AF;
  bf16*  wqkvgt = (bf16*)p; p += (size_t)2 * 1024 * 256 * sizeof(bf16);
  bf16*  wot    = (bf16*)p; p += (size_t)2 * 256 * 256 * sizeof(bf16);
  bf16*  w1t    = (bf16*)p; p += (size_t)2 * 1024 * 256 * sizeof(bf16);
  bf16*  w2t    = (bf16*)p; p += (size_t)2 * 256 * 1024 * sizeof(bf16);
  float* tsn  = (float*)p; p += SS * 16 * sizeof(float);
  float* tcs  = (float*)p; p += SS * 16 * sizeof(float);
  float* tsc  = (float*)p; p += SS * 16 * sizeof(float);
  bf16*  h1   = qb;                    // MM*FFD bf16 = 16 MiB

  tables_k<<<dim3((SS * 16 + 255) / 256), dim3(256), 0, stream>>>(tsn, tcs, tsc);

  {
    WDescA da;
    for (int l = 0; l < 2; ++l) {
      da.d[l * 7 + 0] = { Wq + (size_t)l * 65536, wqkvgt + (size_t)l * 262144 + 0 * 65536, 256, 256 };
      da.d[l * 7 + 1] = { Wk + (size_t)l * 65536, wqkvgt + (size_t)l * 262144 + 1 * 65536, 256, 256 };
      da.d[l * 7 + 2] = { Wv + (size_t)l * 65536, wqkvgt + (size_t)l * 262144 + 2 * 65536, 256, 256 };
      da.d[l * 7 + 3] = { Wg + (size_t)l * 65536, wqkvgt + (size_t)l * 262144 + 3 * 65536, 256, 256 };
      da.d[l * 7 + 4] = { Wo + (size_t)l * 65536, wot + (size_t)l * 65536, 256, 256 };
      da.d[l * 7 + 5] = { w1 + (size_t)l * 262144, w1t + (size_t)l * 262144, 256, 1024 };
      da.d[l * 7 + 6] = { w2 + (size_t)l * 262144, w2t + (size_t)l * 262144, 1024, 256 };
    }
    wconv_k<<<dim3(32, 32, 14), dim3(32, 8), 0, stream>>>(da);
  }

  const float* xin = X;
  for (int l = 0; l < LYR; ++l) {
    ln_k<bf16><<<dim3(MM), 256, 0, stream>>>(xin, ln1w + l * DD, ln1b + l * DD, xn);
    mgemm_k<128, 128, DD, E_QKVG><<<dim3(MM / 128, 1024 / 128), 256, 0, stream>>>(
        xn, wqkvgt + (size_t)l * 262144, nullptr, nullptr, qb, kb, vT, gbuf, 1024, tsn, tcs, tsc);
    attn_k<<<dim3(BB * HH, SS / 64), 256, 0, stream>>>(qb, kb, vT, gbuf, gnw + l * DD, gnb + l * DD, ub);
    mgemm_k<64, 64, DD, E_RES><<<dim3(MM / 64, 256 / 64), 256, 0, stream>>>(
        ub, wot + (size_t)l * 65536, nullptr, xin, yres, nullptr, nullptr, nullptr, 256, tsn, tcs, tsc);
    ln_k<bf16><<<dim3(MM), 256, 0, stream>>>(yres, ln2w + l * DD, ln2b + l * DD, xn);
    mgemm_k<128, 128, DD, E_BGELU><<<dim3(MM / 128, FFD / 128), 256, 0, stream>>>(
        xn, w1t + (size_t)l * 262144, b1 + l * FFD, nullptr, h1, nullptr, nullptr, nullptr, FFD, tsn, tcs, tsc);
    mgemm_k<64, 64, FFD, E_BRES><<<dim3(MM / 64, 256 / 64), 256, 0, stream>>>(
        h1, w2t + (size_t)l * 262144, b2 + l * DD, yres, yres, nullptr, nullptr, nullptr, 256, tsn, tcs, tsc);
    if (l == LYR - 1) {
      ln_k<float><<<dim3(MM), 256, 0, stream>>>(yres, lnfw, lnfb, (float*)d_out);
    } else {
      ln_k<float><<<dim3(MM), 256, 0, stream>>>(yres, lnfw, lnfb, yres);
      xin = yres;
    }
  }
}

// Round 10
// 229.796 us; speedup vs baseline: 7.1004x; 1.0977x over previous
//
#include <hip/hip_runtime.h>
#include <hip/hip_bf16.h>

typedef __hip_bfloat16 bf16;
typedef unsigned short ushort_t;
typedef __attribute__((ext_vector_type(8))) short short8v;
typedef __attribute__((ext_vector_type(4))) float f32x4;
typedef __attribute__((ext_vector_type(4))) unsigned int uint4v;

// RetNet block: L=2, B=4, S=2048, D=256, H=8, HD=32, FFN*D=1024
#define LYR 2
#define BB 4
#define SS 2048
#define DD 256
#define HH 8
#define HDD 32
#define FFD 1024
#define MM (BB*SS)   // 8192 tokens

__device__ __forceinline__ unsigned int cvtpk(float lo, float hi) {
  unsigned int r;
  asm("v_cvt_pk_bf16_f32 %0, %1, %2" : "=v"(r) : "v"(lo), "v"(hi));
  return r;
}

__device__ __forceinline__ void gload_lds16(const void* g, void* l) {
  __builtin_amdgcn_global_load_lds((const __attribute__((address_space(1))) void*)g,
                                   (__attribute__((address_space(3))) void*)l, 16, 0, 0);
}

// ---------------- xPos tables (sin/cos/scale, S x 16) ----------------
__global__ void tables_k(float* __restrict__ sn, float* __restrict__ cs, float* __restrict__ sc) {
  int i = blockIdx.x * 256 + threadIdx.x;
  if (i >= SS * 16) return;
  int s = i >> 4, j = i & 15;
  float sv = (2.0f * (float)j + 0.4f * (float)HDD) / (1.4f * (float)HDD);
  sc[i] = powf(sv, (float)s * (1.0f / 512.0f));
  float inv_freq = powf(10000.0f, -(float)j * (1.0f / 16.0f));
  float ang = (float)s * inv_freq;
  sn[i] = sinf(ang);
  cs[i] = cosf(ang);
}

// ---------------- weight transpose+convert: Wt[n][k] = bf16(W[k][n]) ----------------
struct WDesc { const float* src; bf16* dst; int K; int N; };
struct WDescA { WDesc d[14]; };
__global__ __launch_bounds__(256) void wconv_k(WDescA da) {
  WDesc dd = da.d[blockIdx.z];
  int n0 = blockIdx.x * 32, k0 = blockIdx.y * 32;
  if (n0 >= dd.N || k0 >= dd.K) return;
  __shared__ float t[32][33];
  int tx = threadIdx.x, ty = threadIdx.y;   // 32 x 8
  #pragma unroll
  for (int i = 0; i < 32; i += 8) t[ty + i][tx] = dd.src[(size_t)(k0 + ty + i) * dd.N + n0 + tx];
  __syncthreads();
  #pragma unroll
  for (int i = 0; i < 32; i += 8) dd.dst[(size_t)(n0 + ty + i) * dd.K + k0 + tx] = __float2bfloat16(t[tx][ty + i]);
}

// ---------------- LayerNorm over D=256 (one block per row), f32 in, OT out ----------------
template<typename OT>
__global__ __launch_bounds__(256) void ln_k(const float* __restrict__ in, const float* __restrict__ w,
    const float* __restrict__ b, OT* __restrict__ out)
{
  int row = blockIdx.x, t = threadIdx.x;
  float v = in[(size_t)row * DD + t];
  __shared__ float red[4];
  float s = v;
  #pragma unroll
  for (int m = 32; m >= 1; m >>= 1) s += __shfl_xor(s, m);
  if ((t & 63) == 0) red[t >> 6] = s;
  __syncthreads();
  float mu = (red[0] + red[1] + red[2] + red[3]) * (1.0f / 256.0f);
  float d = v - mu;
  float s2 = d * d;
  #pragma unroll
  for (int m = 32; m >= 1; m >>= 1) s2 += __shfl_xor(s2, m);
  __syncthreads();
  if ((t & 63) == 0) red[t >> 6] = s2;
  __syncthreads();
  float var = (red[0] + red[1] + red[2] + red[3]) * (1.0f / 256.0f);
  float o = d * rsqrtf(var + 1e-5f) * w[t] + b[t];
  if constexpr (sizeof(OT) == 2) out[(size_t)row * DD + t] = __float2bfloat16(o);
  else                           out[(size_t)row * DD + t] = o;
}

#define STAGEG(buf, k0s) { \
    _Pragma("unroll") \
    for (int i = 0; i < BM / 32; ++i) { \
      int slot = i * 256 + tid; int row = slot >> 3, blk = slot & 7; \
      gload_lds16(Au + (size_t)(bm + row) * K + (k0s) + ((blk ^ (row & 7))) * 8, &Al[buf][slot * 8]); \
    } \
    _Pragma("unroll") \
    for (int i = 0; i < BN / 32; ++i) { \
      int slot = i * 256 + tid; int row = slot >> 3, blk = slot & 7; \
      gload_lds16(Bu + (size_t)(bn + row) * K + (k0s) + ((blk ^ (row & 7))) * 8, &Bl[buf][slot * 8]); \
    } }

// ---------------- bf16 MFMA GEMM, double-buffered pipeline ----------------
enum { E_QKVG = 0, E_BGELU = 2 };

template<int BM, int BN, int K, int EPI>
__global__ __launch_bounds__(256) void mgemm_k(const bf16* __restrict__ Ag, const bf16* __restrict__ Wt,
    const float* __restrict__ bias,
    void* o0, void* o1, void* o2, void* o3, int N,
    const float* __restrict__ tsn, const float* __restrict__ tcs, const float* __restrict__ tsc)
{
  constexpr int MT = BM / 32, NT = BN / 32;
  constexpr int WMH = BM / 2, WNH = BN / 2;
  __shared__ __align__(16) ushort_t Al[2][BM * 64];
  __shared__ __align__(16) ushort_t Bl[2][BN * 64];
  const int bm = blockIdx.x * BM;
  const int bn = blockIdx.y * BN;
  const int tid = threadIdx.x;
  const int lane = tid & 63, w = tid >> 6;
  const int lg = lane >> 4, ln = lane & 15;
  const int wr = w >> 1, wc = w & 1;
  const ushort_t* Au = (const ushort_t*)Ag;
  const ushort_t* Bu = (const ushort_t*)Wt;
  f32x4 acc[MT][NT] = {};

  STAGEG(0, 0)
  asm volatile("s_waitcnt vmcnt(0)" ::: "memory");
  __builtin_amdgcn_s_barrier();

  int cur = 0;
  for (int k0 = 0; k0 < K; k0 += 64) {
    if (k0 + 64 < K) STAGEG(cur ^ 1, k0 + 64)
    #pragma unroll
    for (int kh = 0; kh < 2; ++kh) {
      short8v af[MT], bfr[NT];
      #pragma unroll
      for (int mt = 0; mt < MT; ++mt) {
        int row = wr * WMH + mt * 16 + ln;
        af[mt] = *(const short8v*)&Al[cur][row * 64 + (((kh * 4 + lg) ^ (row & 7))) * 8];
      }
      #pragma unroll
      for (int nt = 0; nt < NT; ++nt) {
        int row = wc * WNH + nt * 16 + ln;
        bfr[nt] = *(const short8v*)&Bl[cur][row * 64 + (((kh * 4 + lg) ^ (row & 7))) * 8];
      }
      #pragma unroll
      for (int mt = 0; mt < MT; ++mt)
        #pragma unroll
        for (int nt = 0; nt < NT; ++nt)
          acc[mt][nt] = __builtin_amdgcn_mfma_f32_16x16x32_bf16(af[mt], bfr[nt], acc[mt][nt], 0, 0, 0);
    }
    asm volatile("s_waitcnt vmcnt(0)" ::: "memory");
    __builtin_amdgcn_s_barrier();
    cur ^= 1;
  }

  if constexpr (EPI == E_QKVG) {
    #pragma unroll
    for (int mt = 0; mt < MT; ++mt)
      #pragma unroll
      for (int nt = 0; nt < NT; ++nt) {
        const int colbase = bn + wc * WNH + nt * 16;
        const int sec = colbase >> 8;          // 0=Q 1=K 2=V 3=G
        const int c = (colbase & 255) + ln;
        const int grow0 = bm + wr * WMH + mt * 16 + lg * 4;
        if (sec <= 1) {
          const int jj = (c & 31) >> 1;
          #pragma unroll
          for (int r = 0; r < 4; ++r) {
            const int grow = grow0 + r;
            const int s = grow & (SS - 1);
            float v = acc[mt][nt][r];
            float pv = __shfl_xor(v, 1);
            float scv = tsc[s * 16 + jj];
            if (sec == 1) scv = 1.0f / scv;
            float ce = tcs[s * 16 + jj] * scv, se = tsn[s * 16 + jj] * scv;
            float o = (ln & 1) ? (v * ce + pv * se) : (v * ce - pv * se);
            bf16* dst = (sec == 0) ? (bf16*)o0 : (bf16*)o1;
            dst[(size_t)grow * DD + c] = __float2bfloat16(o);
          }
        } else if (sec == 2) {
          const int b = grow0 >> 11, s0 = grow0 & (SS - 1);
          const int h = c >> 5, d = c & 31;
          uint2 pk;
          pk.x = cvtpk(acc[mt][nt][0], acc[mt][nt][1]);
          pk.y = cvtpk(acc[mt][nt][2], acc[mt][nt][3]);
          *(uint2*)((ushort_t*)o2 + ((size_t)(b * 8 + h) * 32 + d) * SS + s0) = pk;
        } else {
          #pragma unroll
          for (int r = 0; r < 4; ++r)
            ((float*)o3)[(size_t)(grow0 + r) * DD + c] = acc[mt][nt][r];
        }
      }
  } else {  // E_BGELU
    #pragma unroll
    for (int mt = 0; mt < MT; ++mt)
      #pragma unroll
      for (int nt = 0; nt < NT; ++nt) {
        const int gcol = bn + wc * WNH + nt * 16 + ln;
        #pragma unroll
        for (int r = 0; r < 4; ++r) {
          const int grow = bm + wr * WMH + mt * 16 + lg * 4 + r;
          float v = acc[mt][nt][r] + bias[gcol];
          v = 0.5f * v * (1.0f + erff(v * 0.70710678118654752f));
          ((bf16*)o0)[(size_t)grow * N + gcol] = __float2bfloat16(v);
        }
      }
  }
}

// ---------------- GEMM (N=256) + residual + fused LayerNorm(s) ----------------
// BM=32, BN=256 (full row), 4 waves 2Mx2N; wave = 16 rows x 128 cols, NT=8.
// MODE 0 (Wo):  v = acc + res;        yres=v;  xn = LN(v; law,lab)
// MODE 1 (FFN2): v = acc + bias + res; u = LN(v; law,lab);
//                LAST: dout = u (f32). else: yres = u; xn = LN(u; lbw,lbb)
template<int K, int MODE, bool LAST>
__global__ __launch_bounds__(256) void mgemm_ln(const bf16* __restrict__ Ag, const bf16* __restrict__ Wt,
    const float* __restrict__ bias, const float* __restrict__ res,
    float* __restrict__ yres, bf16* __restrict__ xn, float* __restrict__ dout,
    const float* __restrict__ law, const float* __restrict__ lab,
    const float* __restrict__ lbw, const float* __restrict__ lbb)
{
  constexpr int BM = 32, BN = 256;
  __shared__ __align__(16) ushort_t Al[2][BM * 64];
  __shared__ __align__(16) ushort_t Bl[2][BN * 64];
  __shared__ float red[2][32][2];
  const int bm = blockIdx.x * BM;
  const int bn = 0;
  const int tid = threadIdx.x;
  const int lane = tid & 63, w = tid >> 6;
  const int lg = lane >> 4, ln = lane & 15;
  const int wr = w >> 1, wc = w & 1;
  const ushort_t* Au = (const ushort_t*)Ag;
  const ushort_t* Bu = (const ushort_t*)Wt;
  f32x4 acc[8] = {};

  STAGEG(0, 0)
  asm volatile("s_waitcnt vmcnt(0)" ::: "memory");
  __builtin_amdgcn_s_barrier();

  int cur = 0;
  for (int k0 = 0; k0 < K; k0 += 64) {
    if (k0 + 64 < K) STAGEG(cur ^ 1, k0 + 64)
    #pragma unroll
    for (int kh = 0; kh < 2; ++kh) {
      short8v af, bfr[8];
      {
        int row = wr * 16 + ln;
        af = *(const short8v*)&Al[cur][row * 64 + (((kh * 4 + lg) ^ (row & 7))) * 8];
      }
      #pragma unroll
      for (int nt = 0; nt < 8; ++nt) {
        int row = wc * 128 + nt * 16 + ln;
        bfr[nt] = *(const short8v*)&Bl[cur][row * 64 + (((kh * 4 + lg) ^ (row & 7))) * 8];
      }
      #pragma unroll
      for (int nt = 0; nt < 8; ++nt)
        acc[nt] = __builtin_amdgcn_mfma_f32_16x16x32_bf16(af, bfr[nt], acc[nt], 0, 0, 0);
    }
    asm volatile("s_waitcnt vmcnt(0)" ::: "memory");
    __builtin_amdgcn_s_barrier();
    cur ^= 1;
  }

  // ---- epilogue: v = acc (+bias) + res ----
  const int row0 = wr * 16 + lg * 4;               // block-local row base (4 rows)
  float v[8][4];
  #pragma unroll
  for (int nt = 0; nt < 8; ++nt) {
    const int gcol = wc * 128 + nt * 16 + ln;
    #pragma unroll
    for (int r = 0; r < 4; ++r) {
      float t = acc[nt][r];
      if constexpr (MODE == 1) t += bias[gcol];
      t += res[(size_t)(bm + row0 + r) * DD + gcol];
      v[nt][r] = t;
    }
  }
  // ---- LN reduction #1 ----
  float mu[4], rs[4];
  {
    #pragma unroll
    for (int r = 0; r < 4; ++r) {
      float s = 0.f, s2 = 0.f;
      #pragma unroll
      for (int nt = 0; nt < 8; ++nt) { s += v[nt][r]; s2 += v[nt][r] * v[nt][r]; }
      #pragma unroll
      for (int m = 8; m >= 1; m >>= 1) { s += __shfl_xor(s, m); s2 += __shfl_xor(s2, m); }
      if (ln == 0) { red[wc][row0 + r][0] = s; red[wc][row0 + r][1] = s2; }
    }
    __syncthreads();
    #pragma unroll
    for (int r = 0; r < 4; ++r) {
      float S  = red[0][row0 + r][0] + red[1][row0 + r][0];
      float S2 = red[0][row0 + r][1] + red[1][row0 + r][1];
      float m_ = S * (1.0f / 256.0f);
      float var = S2 * (1.0f / 256.0f) - m_ * m_;
      mu[r] = m_; rs[r] = rsqrtf(var + 1e-5f);
    }
  }

  if constexpr (MODE == 0) {
    #pragma unroll
    for (int nt = 0; nt < 8; ++nt) {
      const int gcol = wc * 128 + nt * 16 + ln;
      const float lw = law[gcol], lb = lab[gcol];
      #pragma unroll
      for (int r = 0; r < 4; ++r) {
        const size_t idx = (size_t)(bm + row0 + r) * DD + gcol;
        yres[idx] = v[nt][r];
        xn[idx] = __float2bfloat16((v[nt][r] - mu[r]) * rs[r] * lw + lb);
      }
    }
  } else {
    float u[8][4];
    #pragma unroll
    for (int nt = 0; nt < 8; ++nt) {
      const int gcol = wc * 128 + nt * 16 + ln;
      const float lw = law[gcol], lb = lab[gcol];
      #pragma unroll
      for (int r = 0; r < 4; ++r)
        u[nt][r] = (v[nt][r] - mu[r]) * rs[r] * lw + lb;
    }
    if constexpr (LAST) {
      #pragma unroll
      for (int nt = 0; nt < 8; ++nt) {
        const int gcol = wc * 128 + nt * 16 + ln;
        #pragma unroll
        for (int r = 0; r < 4; ++r)
          dout[(size_t)(bm + row0 + r) * DD + gcol] = u[nt][r];
      }
    } else {
      // ---- LN reduction #2 (next layer's LN1) ----
      __syncthreads();
      #pragma unroll
      for (int r = 0; r < 4; ++r) {
        float s = 0.f, s2 = 0.f;
        #pragma unroll
        for (int nt = 0; nt < 8; ++nt) { s += u[nt][r]; s2 += u[nt][r] * u[nt][r]; }
        #pragma unroll
        for (int m = 8; m >= 1; m >>= 1) { s += __shfl_xor(s, m); s2 += __shfl_xor(s2, m); }
        if (ln == 0) { red[wc][row0 + r][0] = s; red[wc][row0 + r][1] = s2; }
      }
      __syncthreads();
      float mu2[4], rs2[4];
      #pragma unroll
      for (int r = 0; r < 4; ++r) {
        float S  = red[0][row0 + r][0] + red[1][row0 + r][0];
        float S2 = red[0][row0 + r][1] + red[1][row0 + r][1];
        float m_ = S * (1.0f / 256.0f);
        float var = S2 * (1.0f / 256.0f) - m_ * m_;
        mu2[r] = m_; rs2[r] = rsqrtf(var + 1e-5f);
      }
      #pragma unroll
      for (int nt = 0; nt < 8; ++nt) {
        const int gcol = wc * 128 + nt * 16 + ln;
        const float lw = lbw[gcol], lb = lbb[gcol];
        #pragma unroll
        for (int r = 0; r < 4; ++r) {
          const size_t idx = (size_t)(bm + row0 + r) * DD + gcol;
          yres[idx] = u[nt][r];
          xn[idx] = __float2bfloat16((u[nt][r] - mu2[r]) * rs2[r] * lw + lb);
        }
      }
    }
  }
}

// ---------------- Retention + fused GroupNorm/SiLU-gate ----------------
__global__ __launch_bounds__(256) void attn_k(const bf16* __restrict__ qg, const bf16* __restrict__ kg,
    const bf16* __restrict__ vtg, const float* __restrict__ gbuf,
    const float* __restrict__ gnw, const float* __restrict__ gnb, bf16* __restrict__ ub)
{
  __shared__ __align__(16) ushort_t Kl[2][64 * 32];      // [m][k], blk ^= m&3
  __shared__ __align__(16) ushort_t Vl[2][32 * 64];      // [d][m], blk ^= d&7
  __shared__ __align__(16) unsigned int Pl[4][512];      // per wave: P^T[n=ln][64 m] bf16

  const int bh = blockIdx.x;
  const int b = bh >> 3, h = bh & (HH - 1);
  const int n0 = ((int)gridDim.y - 1 - (int)blockIdx.y) * 64;
  const int tid = threadIdx.x;
  const int w = tid >> 6, lane = tid & 63;
  const int lg = lane >> 4, ln = lane & 15;

  const size_t base = (size_t)b * SS * DD + h * HDD;
  const ushort_t* qp = (const ushort_t*)qg + base;
  const ushort_t* kp = (const ushort_t*)kg + base;
  const ushort_t* vtp = (const ushort_t*)vtg + (size_t)(b * 8 + h) * 32 * SS;

  const int n = n0 + w * 16 + ln;
  const short8v qf = *(const short8v*)(qp + (size_t)n * DD + lg * 8);

  const float onemg = expf(-3.4657359028f - 0.3960841187f * (float)h);
  const float l2g = log2f(1.0f - onemg);           // negative
  float emr[4];
  #pragma unroll
  for (int r = 0; r < 4; ++r) emr[r] = exp2f(-l2g * (float)(lg * 4 + r));
  const float e16 = exp2f(-l2g * 16.0f);

  f32x4 acc0 = {0,0,0,0}, acc1 = {0,0,0,0};

  const int Wwin = (int)(20.0f / (-l2g)) + 1;
  int m_lo = 0;
  if (n0 > Wwin) m_lo = ((n0 - Wwin) >> 6) << 6;

  const int Krow = tid >> 2, Kc8 = tid & 3;
  const int Vrow = tid >> 3, Vc8 = tid & 7;

  #define STAGE(buf, m0s) { \
    gload_lds16(kp + (size_t)((m0s) + Krow) * DD + ((Kc8 ^ (Krow & 3)) * 8), &Kl[buf][tid * 8]); \
    gload_lds16(vtp + (size_t)Vrow * SS + (m0s) + ((Vc8 ^ (Vrow & 7)) * 8), &Vl[buf][tid * 8]); }

  STAGE(0, m_lo)
  asm volatile("s_waitcnt vmcnt(0)" ::: "memory");
  __builtin_amdgcn_s_barrier();

  int cur = 0;
  for (int m0 = m_lo; m0 <= n0; m0 += 64) {
    if (m0 < n0) STAGE(cur ^ 1, m0 + 64)
    const bool diag = (m0 == n0);
    float fnt = exp2f(l2g * (float)(n - m0));
    __builtin_amdgcn_s_setprio(1);
    #pragma unroll
    for (int mt = 0; mt < 4; ++mt) {
      const int krow = mt * 16 + ln;
      short8v kf = *(const short8v*)&Kl[cur][krow * 32 + ((lg ^ (krow & 3)) << 3)];
      f32x4 z = {0,0,0,0};
      f32x4 pa = __builtin_amdgcn_mfma_f32_16x16x32_bf16(kf, qf, z, 0, 0, 0);
      float v0 = pa[0] * (fnt * emr[0]);
      float v1 = pa[1] * (fnt * emr[1]);
      float v2 = pa[2] * (fnt * emr[2]);
      float v3 = pa[3] * (fnt * emr[3]);
      if (diag) {
        const int m = n0 + mt * 16 + lg * 4;
        v0 = (n < m)     ? 0.f : v0;
        v1 = (n < m + 1) ? 0.f : v1;
        v2 = (n < m + 2) ? 0.f : v2;
        v3 = (n < m + 3) ? 0.f : v3;
      }
      uint2 pk;
      pk.x = cvtpk(v0, v1);
      pk.y = cvtpk(v2, v3);
      const int blk = (mt * 2 + (lg >> 1)) ^ (ln & 7);
      *(uint2*)&Pl[w][ln * 32 + blk * 4 + (lg & 1) * 2] = pk;
      fnt *= e16;
    }
    #pragma unroll
    for (int hh = 0; hh < 2; ++hh) {
      const int pblk = (hh * 4 + lg) ^ (ln & 7);
      uint4v pw = *(const uint4v*)&Pl[w][ln * 32 + pblk * 4];
      short8v pf = __builtin_bit_cast(short8v, pw);
      #pragma unroll
      for (int dt = 0; dt < 2; ++dt) {
        const int d = dt * 16 + ln;
        short8v vf = *(const short8v*)&Vl[cur][d * 64 + (((hh * 4 + lg) ^ (d & 7)) << 3)];
        if (dt == 0) acc0 = __builtin_amdgcn_mfma_f32_16x16x32_bf16(vf, pf, acc0, 0, 0, 0);
        else         acc1 = __builtin_amdgcn_mfma_f32_16x16x32_bf16(vf, pf, acc1, 0, 0, 0);
      }
    }
    __builtin_amdgcn_s_setprio(0);
    asm volatile("s_waitcnt vmcnt(0)" ::: "memory");
    __builtin_amdgcn_s_barrier();
    cur ^= 1;
  }
  #undef STAGE

  // ---- fused GroupNorm (per head) + SiLU gate ----
  float gwv[8], gbv[8];
  #pragma unroll
  for (int dt = 0; dt < 2; ++dt) {
    f32x4 a = *(const f32x4*)&gnw[h * 32 + dt * 16 + lg * 4];
    f32x4 c = *(const f32x4*)&gnb[h * 32 + dt * 16 + lg * 4];
    #pragma unroll
    for (int r = 0; r < 4; ++r) { gwv[dt * 4 + r] = a[r]; gbv[dt * 4 + r] = c[r]; }
  }
  float s = 0.f;
  #pragma unroll
  for (int r = 0; r < 4; ++r) s += acc0[r] + acc1[r];
  s += __shfl_xor(s, 16); s += __shfl_xor(s, 32);
  const float mu = s * (1.0f / 32.0f);
  float s2 = 0.f;
  #pragma unroll
  for (int r = 0; r < 4; ++r) { float d0 = acc0[r] - mu, d1 = acc1[r] - mu; s2 += d0 * d0 + d1 * d1; }
  s2 += __shfl_xor(s2, 16); s2 += __shfl_xor(s2, 32);
  const float rs = rsqrtf(s2 * (1.0f / 32.0f) + 1e-5f);
  const size_t rowoff = ((size_t)b * SS + n) * DD + h * 32;
  #pragma unroll
  for (int dt = 0; dt < 2; ++dt) {
    f32x4 yv = dt ? acc1 : acc0;
    f32x4 gv = *(const f32x4*)&gbuf[rowoff + dt * 16 + lg * 4];
    float o0, o1, o2, o3;
    {
      float yn0 = (yv[0] - mu) * rs * gwv[dt * 4 + 0] + gbv[dt * 4 + 0];
      float yn1 = (yv[1] - mu) * rs * gwv[dt * 4 + 1] + gbv[dt * 4 + 1];
      float yn2 = (yv[2] - mu) * rs * gwv[dt * 4 + 2] + gbv[dt * 4 + 2];
      float yn3 = (yv[3] - mu) * rs * gwv[dt * 4 + 3] + gbv[dt * 4 + 3];
      o0 = gv[0] / (1.0f + expf(-gv[0])) * yn0;
      o1 = gv[1] / (1.0f + expf(-gv[1])) * yn1;
      o2 = gv[2] / (1.0f + expf(-gv[2])) * yn2;
      o3 = gv[3] / (1.0f + expf(-gv[3])) * yn3;
    }
    uint2 pk;
    pk.x = cvtpk(o0, o1);
    pk.y = cvtpk(o2, o3);
    *(uint2*)((ushort_t*)ub + rowoff + dt * 16 + lg * 4) = pk;
  }
}

extern "C" void kernel_launch(void* const* d_in, const int* in_sizes, int n_in,
                              void* d_out, int out_size, void* d_ws, size_t ws_size,
                              hipStream_t stream)
{
  const float* X    = (const float*)d_in[0];
  const float* Wq   = (const float*)d_in[1];
  const float* Wk   = (const float*)d_in[2];
  const float* Wv   = (const float*)d_in[3];
  const float* Wg   = (const float*)d_in[4];
  const float* Wo   = (const float*)d_in[5];
  const float* gnw  = (const float*)d_in[6];
  const float* gnb  = (const float*)d_in[7];
  const float* ln1w = (const float*)d_in[8];
  const float* ln1b = (const float*)d_in[9];
  const float* ln2w = (const float*)d_in[10];
  const float* ln2b = (const float*)d_in[11];
  const float* w1   = (const float*)d_in[12];
  const float* b1   = (const float*)d_in[13];
  const float* w2   = (const float*)d_in[14];
  const float* b2   = (const float*)d_in[15];
  const float* lnfw = (const float*)d_in[16];
  const float* lnfb = (const float*)d_in[17];

  // Workspace (~40 MiB)
  char* p = (char*)d_ws;
  const size_t AF  = (size_t)MM * DD * sizeof(float);  // 8 MiB
  const size_t ABF = (size_t)MM * DD * sizeof(bf16);   // 4 MiB
  bf16*  xn   = (bf16*)p;  p += ABF;
  bf16*  qb   = (bf16*)p;  p += ABF;   // h1 (16 MiB bf16) aliases qb..ub
  bf16*  kb   = (bf16*)p;  p += ABF;
  bf16*  vT   = (bf16*)p;  p += ABF;   // [B][H][32][S]
  bf16*  ub   = (bf16*)p;  p += ABF;
  float* gbuf = (float*)p; p += AF;
  float* yres = (float*)p; p += AF;
  bf16*  wqkvgt = (bf16*)p; p += (size_t)2 * 1024 * 256 * sizeof(bf16);
  bf16*  wot    = (bf16*)p; p += (size_t)2 * 256 * 256 * sizeof(bf16);
  bf16*  w1t    = (bf16*)p; p += (size_t)2 * 1024 * 256 * sizeof(bf16);
  bf16*  w2t    = (bf16*)p; p += (size_t)2 * 256 * 1024 * sizeof(bf16);
  float* tsn  = (float*)p; p += SS * 16 * sizeof(float);
  float* tcs  = (float*)p; p += SS * 16 * sizeof(float);
  float* tsc  = (float*)p; p += SS * 16 * sizeof(float);
  bf16*  h1   = qb;                    // MM*FFD bf16 = 16 MiB

  tables_k<<<dim3((SS * 16 + 255) / 256), dim3(256), 0, stream>>>(tsn, tcs, tsc);

  {
    WDescA da;
    for (int l = 0; l < 2; ++l) {
      da.d[l * 7 + 0] = { Wq + (size_t)l * 65536, wqkvgt + (size_t)l * 262144 + 0 * 65536, 256, 256 };
      da.d[l * 7 + 1] = { Wk + (size_t)l * 65536, wqkvgt + (size_t)l * 262144 + 1 * 65536, 256, 256 };
      da.d[l * 7 + 2] = { Wv + (size_t)l * 65536, wqkvgt + (size_t)l * 262144 + 2 * 65536, 256, 256 };
      da.d[l * 7 + 3] = { Wg + (size_t)l * 65536, wqkvgt + (size_t)l * 262144 + 3 * 65536, 256, 256 };
      da.d[l * 7 + 4] = { Wo + (size_t)l * 65536, wot + (size_t)l * 65536, 256, 256 };
      da.d[l * 7 + 5] = { w1 + (size_t)l * 262144, w1t + (size_t)l * 262144, 256, 1024 };
      da.d[l * 7 + 6] = { w2 + (size_t)l * 262144, w2t + (size_t)l * 262144, 1024, 256 };
    }
    wconv_k<<<dim3(32, 32, 14), dim3(32, 8), 0, stream>>>(da);
  }

  // layer 0 LN1 (layer 1's LN1 is fused into layer 0's FFN2 epilogue)
  ln_k<bf16><<<dim3(MM), 256, 0, stream>>>(X, ln1w, ln1b, xn);

  for (int l = 0; l < LYR; ++l) {
    mgemm_k<128, 128, DD, E_QKVG><<<dim3(MM / 128, 1024 / 128), 256, 0, stream>>>(
        xn, wqkvgt + (size_t)l * 262144, nullptr, qb, kb, vT, gbuf, 1024, tsn, tcs, tsc);
    attn_k<<<dim3(BB * HH, SS / 64), 256, 0, stream>>>(qb, kb, vT, gbuf, gnw + l * DD, gnb + l * DD, ub);
    // Wo + residual + LN2 -> yres (pre-LN) + xn (LN2 out)
    mgemm_ln<DD, 0, false><<<dim3(MM / 32), 256, 0, stream>>>(
        ub, wot + (size_t)l * 65536, nullptr, (l == 0) ? X : yres, yres, xn, nullptr,
        ln2w + l * DD, ln2b + l * DD, nullptr, nullptr);
    mgemm_k<128, 128, DD, E_BGELU><<<dim3(MM / 128, FFD / 128), 256, 0, stream>>>(
        xn, w1t + (size_t)l * 262144, b1 + l * FFD, h1, nullptr, nullptr, nullptr, FFD, tsn, tcs, tsc);
    if (l == LYR - 1) {
      mgemm_ln<FFD, 1, true><<<dim3(MM / 32), 256, 0, stream>>>(
          h1, w2t + (size_t)l * 262144, b2 + l * DD, yres, nullptr, nullptr, (float*)d_out,
          lnfw, lnfb, nullptr, nullptr);
    } else {
      // FFN2 + bias + residual + final-LN (-> yres) + next-layer LN1 (-> xn)
      mgemm_ln<FFD, 1, false><<<dim3(MM / 32), 256, 0, stream>>>(
          h1, w2t + (size_t)l * 262144, b2 + l * DD, yres, yres, xn, nullptr,
          lnfw, lnfb, ln1w + (l + 1) * DD, ln1b + (l + 1) * DD);
    }
  }
}

// Round 11
// 223.263 us; speedup vs baseline: 7.3082x; 1.0293x over previous
//
#include <hip/hip_runtime.h>
#include <hip/hip_bf16.h>

typedef __hip_bfloat16 bf16;
typedef unsigned short ushort_t;
typedef __attribute__((ext_vector_type(8))) short short8v;
typedef __attribute__((ext_vector_type(4))) float f32x4;
typedef __attribute__((ext_vector_type(4))) unsigned int uint4v;

// RetNet block: L=2, B=4, S=2048, D=256, H=8, HD=32, FFN*D=1024
#define LYR 2
#define BB 4
#define SS 2048
#define DD 256
#define HH 8
#define HDD 32
#define FFD 1024
#define MM (BB*SS)   // 8192 tokens

__device__ __forceinline__ unsigned int cvtpk(float lo, float hi) {
  unsigned int r;
  asm("v_cvt_pk_bf16_f32 %0, %1, %2" : "=v"(r) : "v"(lo), "v"(hi));
  return r;
}

__device__ __forceinline__ void gload_lds16(const void* g, void* l) {
  __builtin_amdgcn_global_load_lds((const __attribute__((address_space(1))) void*)g,
                                   (__attribute__((address_space(3))) void*)l, 16, 0, 0);
}

// decay exponent: l2g(h) = log2(1 - exp(log(1/32) + h*(log(1/512)-log(1/32))/7))  (negative)
__device__ __forceinline__ float l2g_of(int h) {
  return log2f(1.0f - expf(-3.4657359028f - 0.3960841187f * (float)h));
}

// ---------------- weight transpose+convert + xPos tables (z==14) ----------------
struct WDesc { const float* src; bf16* dst; int K; int N; };
struct WDescA { WDesc d[14]; float* tsn; float* tcs; float* tsc; };
__global__ __launch_bounds__(256) void wconv_k(WDescA da) {
  if (blockIdx.z == 14) {
    int i = (blockIdx.y * 32 + blockIdx.x) * 256 + threadIdx.y * 32 + threadIdx.x;
    if (i >= SS * 16) return;
    int s = i >> 4, j = i & 15;
    float sv = (2.0f * (float)j + 0.4f * (float)HDD) / (1.4f * (float)HDD);
    da.tsc[i] = powf(sv, (float)s * (1.0f / 512.0f));
    float inv_freq = powf(10000.0f, -(float)j * (1.0f / 16.0f));
    float ang = (float)s * inv_freq;
    da.tsn[i] = sinf(ang);
    da.tcs[i] = cosf(ang);
    return;
  }
  WDesc dd = da.d[blockIdx.z];
  int n0 = blockIdx.x * 32, k0 = blockIdx.y * 32;
  if (n0 >= dd.N || k0 >= dd.K) return;
  __shared__ float t[32][33];
  int tx = threadIdx.x, ty = threadIdx.y;   // 32 x 8
  #pragma unroll
  for (int i = 0; i < 32; i += 8) t[ty + i][tx] = dd.src[(size_t)(k0 + ty + i) * dd.N + n0 + tx];
  __syncthreads();
  #pragma unroll
  for (int i = 0; i < 32; i += 8) dd.dst[(size_t)(n0 + ty + i) * dd.K + k0 + tx] = __float2bfloat16(t[tx][ty + i]);
}

// ---------------- LayerNorm over D=256 (one block per row), f32 in, OT out ----------------
template<typename OT>
__global__ __launch_bounds__(256) void ln_k(const float* __restrict__ in, const float* __restrict__ w,
    const float* __restrict__ b, OT* __restrict__ out)
{
  int row = blockIdx.x, t = threadIdx.x;
  float v = in[(size_t)row * DD + t];
  __shared__ float red[4];
  float s = v;
  #pragma unroll
  for (int m = 32; m >= 1; m >>= 1) s += __shfl_xor(s, m);
  if ((t & 63) == 0) red[t >> 6] = s;
  __syncthreads();
  float mu = (red[0] + red[1] + red[2] + red[3]) * (1.0f / 256.0f);
  float d = v - mu;
  float s2 = d * d;
  #pragma unroll
  for (int m = 32; m >= 1; m >>= 1) s2 += __shfl_xor(s2, m);
  __syncthreads();
  if ((t & 63) == 0) red[t >> 6] = s2;
  __syncthreads();
  float var = (red[0] + red[1] + red[2] + red[3]) * (1.0f / 256.0f);
  float o = d * rsqrtf(var + 1e-5f) * w[t] + b[t];
  if constexpr (sizeof(OT) == 2) out[(size_t)row * DD + t] = __float2bfloat16(o);
  else                           out[(size_t)row * DD + t] = o;
}

#define STAGEG(buf, k0s) { \
    _Pragma("unroll") \
    for (int i = 0; i < BM / 32; ++i) { \
      int slot = i * 256 + tid; int row = slot >> 3, blk = slot & 7; \
      gload_lds16(Au + (size_t)(bm + row) * K + (k0s) + ((blk ^ (row & 7))) * 8, &Al[buf][slot * 8]); \
    } \
    _Pragma("unroll") \
    for (int i = 0; i < BN / 32; ++i) { \
      int slot = i * 256 + tid; int row = slot >> 3, blk = slot & 7; \
      gload_lds16(Bu + (size_t)(bn + row) * K + (k0s) + ((blk ^ (row & 7))) * 8, &Bl[buf][slot * 8]); \
    } }

// ---------------- bf16 MFMA GEMM, double-buffered pipeline ----------------
enum { E_QKVG = 0, E_BGELU = 2 };

template<int BM, int BN, int K, int EPI>
__global__ __launch_bounds__(256) void mgemm_k(const bf16* __restrict__ Ag, const bf16* __restrict__ Wt,
    const float* __restrict__ bias,
    void* o0, void* o1, void* o2, void* o3, int N,
    const float* __restrict__ tsn, const float* __restrict__ tcs, const float* __restrict__ tsc)
{
  constexpr int MT = BM / 32, NT = BN / 32;
  constexpr int WMH = BM / 2, WNH = BN / 2;
  __shared__ __align__(16) ushort_t Al[2][BM * 64];
  __shared__ __align__(16) ushort_t Bl[2][BN * 64];
  const int bm = blockIdx.x * BM;
  const int bn = blockIdx.y * BN;
  const int tid = threadIdx.x;
  const int lane = tid & 63, w = tid >> 6;
  const int lg = lane >> 4, ln = lane & 15;
  const int wr = w >> 1, wc = w & 1;
  const ushort_t* Au = (const ushort_t*)Ag;
  const ushort_t* Bu = (const ushort_t*)Wt;
  f32x4 acc[MT][NT] = {};

  STAGEG(0, 0)
  asm volatile("s_waitcnt vmcnt(0)" ::: "memory");
  __builtin_amdgcn_s_barrier();

  int cur = 0;
  for (int k0 = 0; k0 < K; k0 += 64) {
    if (k0 + 64 < K) STAGEG(cur ^ 1, k0 + 64)
    #pragma unroll
    for (int kh = 0; kh < 2; ++kh) {
      short8v af[MT], bfr[NT];
      #pragma unroll
      for (int mt = 0; mt < MT; ++mt) {
        int row = wr * WMH + mt * 16 + ln;
        af[mt] = *(const short8v*)&Al[cur][row * 64 + (((kh * 4 + lg) ^ (row & 7))) * 8];
      }
      #pragma unroll
      for (int nt = 0; nt < NT; ++nt) {
        int row = wc * WNH + nt * 16 + ln;
        bfr[nt] = *(const short8v*)&Bl[cur][row * 64 + (((kh * 4 + lg) ^ (row & 7))) * 8];
      }
      #pragma unroll
      for (int mt = 0; mt < MT; ++mt)
        #pragma unroll
        for (int nt = 0; nt < NT; ++nt)
          acc[mt][nt] = __builtin_amdgcn_mfma_f32_16x16x32_bf16(af[mt], bfr[nt], acc[mt][nt], 0, 0, 0);
    }
    asm volatile("s_waitcnt vmcnt(0)" ::: "memory");
    __builtin_amdgcn_s_barrier();
    cur ^= 1;
  }

  if constexpr (EPI == E_QKVG) {
    #pragma unroll
    for (int mt = 0; mt < MT; ++mt)
      #pragma unroll
      for (int nt = 0; nt < NT; ++nt) {
        const int colbase = bn + wc * WNH + nt * 16;
        const int sec = colbase >> 8;          // 0=Q 1=K 2=V 3=G (uniform per block)
        const int c = (colbase & 255) + ln;
        const int grow0 = bm + wr * WMH + mt * 16 + lg * 4;
        if (sec <= 1) {
          const int jj = (c & 31) >> 1;
          const float l2g = l2g_of(c >> 5);
          #pragma unroll
          for (int r = 0; r < 4; ++r) {
            const int grow = grow0 + r;
            const int s = grow & (SS - 1);
            float v = acc[mt][nt][r];
            float pv = __shfl_xor(v, 1);
            float scv = tsc[s * 16 + jj];
            if (sec == 1) scv = 1.0f / scv;
            float ce = tcs[s * 16 + jj] * scv, se = tsn[s * 16 + jj] * scv;
            float o = (ln & 1) ? (v * ce + pv * se) : (v * ce - pv * se);
            if (sec == 0) o *= exp2f(l2g * (float)s);   // fold decay g^n into Q
            bf16* dst = (sec == 0) ? (bf16*)o0 : (bf16*)o1;
            dst[(size_t)grow * DD + c] = __float2bfloat16(o);
          }
        } else if (sec == 2) {
          // V transposed + fold g^(-m): vT[(b*8+h)*32 + d][s] = v(m=s,d) * g^(-s)
          const int b = grow0 >> 11, s0 = grow0 & (SS - 1);
          const int h = c >> 5, d = c & 31;
          const float nl2g = -l2g_of(h);                // positive
          float v0 = acc[mt][nt][0] * exp2f(nl2g * (float)(s0 + 0));
          float v1 = acc[mt][nt][1] * exp2f(nl2g * (float)(s0 + 1));
          float v2 = acc[mt][nt][2] * exp2f(nl2g * (float)(s0 + 2));
          float v3 = acc[mt][nt][3] * exp2f(nl2g * (float)(s0 + 3));
          uint2 pk;
          pk.x = cvtpk(v0, v1);
          pk.y = cvtpk(v2, v3);
          *(uint2*)((ushort_t*)o2 + ((size_t)(b * 8 + h) * 32 + d) * SS + s0) = pk;
        } else {
          #pragma unroll
          for (int r = 0; r < 4; ++r)
            ((float*)o3)[(size_t)(grow0 + r) * DD + c] = acc[mt][nt][r];
        }
      }
  } else {  // E_BGELU
    #pragma unroll
    for (int mt = 0; mt < MT; ++mt)
      #pragma unroll
      for (int nt = 0; nt < NT; ++nt) {
        const int gcol = bn + wc * WNH + nt * 16 + ln;
        #pragma unroll
        for (int r = 0; r < 4; ++r) {
          const int grow = bm + wr * WMH + mt * 16 + lg * 4 + r;
          float v = acc[mt][nt][r] + bias[gcol];
          v = 0.5f * v * (1.0f + erff(v * 0.70710678118654752f));
          ((bf16*)o0)[(size_t)grow * N + gcol] = __float2bfloat16(v);
        }
      }
  }
}

// ---------------- GEMM (N=256) + residual + fused LayerNorm(s) ----------------
template<int K, int MODE, bool LAST>
__global__ __launch_bounds__(256) void mgemm_ln(const bf16* __restrict__ Ag, const bf16* __restrict__ Wt,
    const float* __restrict__ bias, const float* __restrict__ res,
    float* __restrict__ yres, bf16* __restrict__ xn, float* __restrict__ dout,
    const float* __restrict__ law, const float* __restrict__ lab,
    const float* __restrict__ lbw, const float* __restrict__ lbb)
{
  constexpr int BM = 32, BN = 256;
  __shared__ __align__(16) ushort_t Al[2][BM * 64];
  __shared__ __align__(16) ushort_t Bl[2][BN * 64];
  __shared__ float red[2][32][2];
  const int bm = blockIdx.x * BM;
  const int bn = 0;
  const int tid = threadIdx.x;
  const int lane = tid & 63, w = tid >> 6;
  const int lg = lane >> 4, ln = lane & 15;
  const int wr = w >> 1, wc = w & 1;
  const ushort_t* Au = (const ushort_t*)Ag;
  const ushort_t* Bu = (const ushort_t*)Wt;
  f32x4 acc[8] = {};

  STAGEG(0, 0)
  asm volatile("s_waitcnt vmcnt(0)" ::: "memory");
  __builtin_amdgcn_s_barrier();

  int cur = 0;
  for (int k0 = 0; k0 < K; k0 += 64) {
    if (k0 + 64 < K) STAGEG(cur ^ 1, k0 + 64)
    #pragma unroll
    for (int kh = 0; kh < 2; ++kh) {
      short8v af, bfr[8];
      {
        int row = wr * 16 + ln;
        af = *(const short8v*)&Al[cur][row * 64 + (((kh * 4 + lg) ^ (row & 7))) * 8];
      }
      #pragma unroll
      for (int nt = 0; nt < 8; ++nt) {
        int row = wc * 128 + nt * 16 + ln;
        bfr[nt] = *(const short8v*)&Bl[cur][row * 64 + (((kh * 4 + lg) ^ (row & 7))) * 8];
      }
      #pragma unroll
      for (int nt = 0; nt < 8; ++nt)
        acc[nt] = __builtin_amdgcn_mfma_f32_16x16x32_bf16(af, bfr[nt], acc[nt], 0, 0, 0);
    }
    asm volatile("s_waitcnt vmcnt(0)" ::: "memory");
    __builtin_amdgcn_s_barrier();
    cur ^= 1;
  }

  const int row0 = wr * 16 + lg * 4;
  float v[8][4];
  #pragma unroll
  for (int nt = 0; nt < 8; ++nt) {
    const int gcol = wc * 128 + nt * 16 + ln;
    #pragma unroll
    for (int r = 0; r < 4; ++r) {
      float t = acc[nt][r];
      if constexpr (MODE == 1) t += bias[gcol];
      t += res[(size_t)(bm + row0 + r) * DD + gcol];
      v[nt][r] = t;
    }
  }
  float mu[4], rs[4];
  {
    #pragma unroll
    for (int r = 0; r < 4; ++r) {
      float s = 0.f, s2 = 0.f;
      #pragma unroll
      for (int nt = 0; nt < 8; ++nt) { s += v[nt][r]; s2 += v[nt][r] * v[nt][r]; }
      #pragma unroll
      for (int m = 8; m >= 1; m >>= 1) { s += __shfl_xor(s, m); s2 += __shfl_xor(s2, m); }
      if (ln == 0) { red[wc][row0 + r][0] = s; red[wc][row0 + r][1] = s2; }
    }
    __syncthreads();
    #pragma unroll
    for (int r = 0; r < 4; ++r) {
      float S  = red[0][row0 + r][0] + red[1][row0 + r][0];
      float S2 = red[0][row0 + r][1] + red[1][row0 + r][1];
      float m_ = S * (1.0f / 256.0f);
      float var = S2 * (1.0f / 256.0f) - m_ * m_;
      mu[r] = m_; rs[r] = rsqrtf(var + 1e-5f);
    }
  }

  if constexpr (MODE == 0) {
    #pragma unroll
    for (int nt = 0; nt < 8; ++nt) {
      const int gcol = wc * 128 + nt * 16 + ln;
      const float lw = law[gcol], lb = lab[gcol];
      #pragma unroll
      for (int r = 0; r < 4; ++r) {
        const size_t idx = (size_t)(bm + row0 + r) * DD + gcol;
        yres[idx] = v[nt][r];
        xn[idx] = __float2bfloat16((v[nt][r] - mu[r]) * rs[r] * lw + lb);
      }
    }
  } else {
    float u[8][4];
    #pragma unroll
    for (int nt = 0; nt < 8; ++nt) {
      const int gcol = wc * 128 + nt * 16 + ln;
      const float lw = law[gcol], lb = lab[gcol];
      #pragma unroll
      for (int r = 0; r < 4; ++r)
        u[nt][r] = (v[nt][r] - mu[r]) * rs[r] * lw + lb;
    }
    if constexpr (LAST) {
      #pragma unroll
      for (int nt = 0; nt < 8; ++nt) {
        const int gcol = wc * 128 + nt * 16 + ln;
        #pragma unroll
        for (int r = 0; r < 4; ++r)
          dout[(size_t)(bm + row0 + r) * DD + gcol] = u[nt][r];
      }
    } else {
      __syncthreads();
      #pragma unroll
      for (int r = 0; r < 4; ++r) {
        float s = 0.f, s2 = 0.f;
        #pragma unroll
        for (int nt = 0; nt < 8; ++nt) { s += u[nt][r]; s2 += u[nt][r] * u[nt][r]; }
        #pragma unroll
        for (int m = 8; m >= 1; m >>= 1) { s += __shfl_xor(s, m); s2 += __shfl_xor(s2, m); }
        if (ln == 0) { red[wc][row0 + r][0] = s; red[wc][row0 + r][1] = s2; }
      }
      __syncthreads();
      float mu2[4], rs2[4];
      #pragma unroll
      for (int r = 0; r < 4; ++r) {
        float S  = red[0][row0 + r][0] + red[1][row0 + r][0];
        float S2 = red[0][row0 + r][1] + red[1][row0 + r][1];
        float m_ = S * (1.0f / 256.0f);
        float var = S2 * (1.0f / 256.0f) - m_ * m_;
        mu2[r] = m_; rs2[r] = rsqrtf(var + 1e-5f);
      }
      #pragma unroll
      for (int nt = 0; nt < 8; ++nt) {
        const int gcol = wc * 128 + nt * 16 + ln;
        const float lw = lbw[gcol], lb = lbb[gcol];
        #pragma unroll
        for (int r = 0; r < 4; ++r) {
          const size_t idx = (size_t)(bm + row0 + r) * DD + gcol;
          yres[idx] = u[nt][r];
          xn[idx] = __float2bfloat16((u[nt][r] - mu2[r]) * rs2[r] * lw + lb);
        }
      }
    }
  }
}

// ---------------- Retention + fused GroupNorm/SiLU-gate ----------------
// Decay is pre-folded: q *= g^n, vT *= g^(-m). Inner loop: raw QK -> pack -> PV.
__global__ __launch_bounds__(256) void attn_k(const bf16* __restrict__ qg, const bf16* __restrict__ kg,
    const bf16* __restrict__ vtg, const float* __restrict__ gbuf,
    const float* __restrict__ gnw, const float* __restrict__ gnb, bf16* __restrict__ ub)
{
  __shared__ __align__(16) ushort_t Kl[2][64 * 32];      // [m][k], blk ^= m&3
  __shared__ __align__(16) ushort_t Vl[2][32 * 64];      // [d][m], blk ^= d&7
  __shared__ __align__(16) unsigned int Pl[4][512];      // per wave: P^T[n=ln][64 m] bf16

  const int bh = blockIdx.x;
  const int b = bh >> 3, h = bh & (HH - 1);
  const int n0 = ((int)gridDim.y - 1 - (int)blockIdx.y) * 64;
  const int tid = threadIdx.x;
  const int w = tid >> 6, lane = tid & 63;
  const int lg = lane >> 4, ln = lane & 15;

  const size_t base = (size_t)b * SS * DD + h * HDD;
  const ushort_t* qp = (const ushort_t*)qg + base;
  const ushort_t* kp = (const ushort_t*)kg + base;
  const ushort_t* vtp = (const ushort_t*)vtg + (size_t)(b * 8 + h) * 32 * SS;

  const int n = n0 + w * 16 + ln;
  const short8v qf = *(const short8v*)(qp + (size_t)n * DD + lg * 8);

  const float l2g = l2g_of(h);                     // negative; only for window calc
  f32x4 acc0 = {0,0,0,0}, acc1 = {0,0,0,0};

  const int Wwin = (int)(20.0f / (-l2g)) + 1;
  int m_lo = 0;
  if (n0 > Wwin) m_lo = ((n0 - Wwin) >> 6) << 6;

  const int Krow = tid >> 2, Kc8 = tid & 3;
  const int Vrow = tid >> 3, Vc8 = tid & 7;

  #define STAGE(buf, m0s) { \
    gload_lds16(kp + (size_t)((m0s) + Krow) * DD + ((Kc8 ^ (Krow & 3)) * 8), &Kl[buf][tid * 8]); \
    gload_lds16(vtp + (size_t)Vrow * SS + (m0s) + ((Vc8 ^ (Vrow & 7)) * 8), &Vl[buf][tid * 8]); }

  STAGE(0, m_lo)
  asm volatile("s_waitcnt vmcnt(0)" ::: "memory");
  __builtin_amdgcn_s_barrier();

  int cur = 0;
  for (int m0 = m_lo; m0 <= n0; m0 += 64) {
    if (m0 < n0) STAGE(cur ^ 1, m0 + 64)
    const bool diag = (m0 == n0);
    __builtin_amdgcn_s_setprio(1);
    #pragma unroll
    for (int mt = 0; mt < 4; ++mt) {
      const int krow = mt * 16 + ln;
      short8v kf = *(const short8v*)&Kl[cur][krow * 32 + ((lg ^ (krow & 3)) << 3)];
      f32x4 z = {0,0,0,0};
      f32x4 pa = __builtin_amdgcn_mfma_f32_16x16x32_bf16(kf, qf, z, 0, 0, 0);
      float v0 = pa[0], v1 = pa[1], v2 = pa[2], v3 = pa[3];
      if (diag) {
        const int m = n0 + mt * 16 + lg * 4;
        v0 = (n < m)     ? 0.f : v0;
        v1 = (n < m + 1) ? 0.f : v1;
        v2 = (n < m + 2) ? 0.f : v2;
        v3 = (n < m + 3) ? 0.f : v3;
      }
      uint2 pk;
      pk.x = cvtpk(v0, v1);
      pk.y = cvtpk(v2, v3);
      const int blk = (mt * 2 + (lg >> 1)) ^ (ln & 7);
      *(uint2*)&Pl[w][ln * 32 + blk * 4 + (lg & 1) * 2] = pk;
    }
    #pragma unroll
    for (int hh = 0; hh < 2; ++hh) {
      const int pblk = (hh * 4 + lg) ^ (ln & 7);
      uint4v pw = *(const uint4v*)&Pl[w][ln * 32 + pblk * 4];
      short8v pf = __builtin_bit_cast(short8v, pw);
      #pragma unroll
      for (int dt = 0; dt < 2; ++dt) {
        const int d = dt * 16 + ln;
        short8v vf = *(const short8v*)&Vl[cur][d * 64 + (((hh * 4 + lg) ^ (d & 7)) << 3)];
        if (dt == 0) acc0 = __builtin_amdgcn_mfma_f32_16x16x32_bf16(vf, pf, acc0, 0, 0, 0);
        else         acc1 = __builtin_amdgcn_mfma_f32_16x16x32_bf16(vf, pf, acc1, 0, 0, 0);
      }
    }
    __builtin_amdgcn_s_setprio(0);
    asm volatile("s_waitcnt vmcnt(0)" ::: "memory");
    __builtin_amdgcn_s_barrier();
    cur ^= 1;
  }
  #undef STAGE

  // ---- fused GroupNorm (per head) + SiLU gate ----
  float gwv[8], gbv[8];
  #pragma unroll
  for (int dt = 0; dt < 2; ++dt) {
    f32x4 a = *(const f32x4*)&gnw[h * 32 + dt * 16 + lg * 4];
    f32x4 c = *(const f32x4*)&gnb[h * 32 + dt * 16 + lg * 4];
    #pragma unroll
    for (int r = 0; r < 4; ++r) { gwv[dt * 4 + r] = a[r]; gbv[dt * 4 + r] = c[r]; }
  }
  float s = 0.f;
  #pragma unroll
  for (int r = 0; r < 4; ++r) s += acc0[r] + acc1[r];
  s += __shfl_xor(s, 16); s += __shfl_xor(s, 32);
  const float mu = s * (1.0f / 32.0f);
  float s2 = 0.f;
  #pragma unroll
  for (int r = 0; r < 4; ++r) { float d0 = acc0[r] - mu, d1 = acc1[r] - mu; s2 += d0 * d0 + d1 * d1; }
  s2 += __shfl_xor(s2, 16); s2 += __shfl_xor(s2, 32);
  const float rs = rsqrtf(s2 * (1.0f / 32.0f) + 1e-5f);
  const size_t rowoff = ((size_t)b * SS + n) * DD + h * 32;
  #pragma unroll
  for (int dt = 0; dt < 2; ++dt) {
    f32x4 yv = dt ? acc1 : acc0;
    f32x4 gv = *(const f32x4*)&gbuf[rowoff + dt * 16 + lg * 4];
    float o0, o1, o2, o3;
    {
      float yn0 = (yv[0] - mu) * rs * gwv[dt * 4 + 0] + gbv[dt * 4 + 0];
      float yn1 = (yv[1] - mu) * rs * gwv[dt * 4 + 1] + gbv[dt * 4 + 1];
      float yn2 = (yv[2] - mu) * rs * gwv[dt * 4 + 2] + gbv[dt * 4 + 2];
      float yn3 = (yv[3] - mu) * rs * gwv[dt * 4 + 3] + gbv[dt * 4 + 3];
      o0 = gv[0] / (1.0f + expf(-gv[0])) * yn0;
      o1 = gv[1] / (1.0f + expf(-gv[1])) * yn1;
      o2 = gv[2] / (1.0f + expf(-gv[2])) * yn2;
      o3 = gv[3] / (1.0f + expf(-gv[3])) * yn3;
    }
    uint2 pk;
    pk.x = cvtpk(o0, o1);
    pk.y = cvtpk(o2, o3);
    *(uint2*)((ushort_t*)ub + rowoff + dt * 16 + lg * 4) = pk;
  }
}

extern "C" void kernel_launch(void* const* d_in, const int* in_sizes, int n_in,
                              void* d_out, int out_size, void* d_ws, size_t ws_size,
                              hipStream_t stream)
{
  const float* X    = (const float*)d_in[0];
  const float* Wq   = (const float*)d_in[1];
  const float* Wk   = (const float*)d_in[2];
  const float* Wv   = (const float*)d_in[3];
  const float* Wg   = (const float*)d_in[4];
  const float* Wo   = (const float*)d_in[5];
  const float* gnw  = (const float*)d_in[6];
  const float* gnb  = (const float*)d_in[7];
  const float* ln1w = (const float*)d_in[8];
  const float* ln1b = (const float*)d_in[9];
  const float* ln2w = (const float*)d_in[10];
  const float* ln2b = (const float*)d_in[11];
  const float* w1   = (const float*)d_in[12];
  const float* b1   = (const float*)d_in[13];
  const float* w2   = (const float*)d_in[14];
  const float* b2   = (const float*)d_in[15];
  const float* lnfw = (const float*)d_in[16];
  const float* lnfb = (const float*)d_in[17];

  // Workspace (~40 MiB)
  char* p = (char*)d_ws;
  const size_t AF  = (size_t)MM * DD * sizeof(float);  // 8 MiB
  const size_t ABF = (size_t)MM * DD * sizeof(bf16);   // 4 MiB
  bf16*  xn   = (bf16*)p;  p += ABF;
  bf16*  qb   = (bf16*)p;  p += ABF;   // h1 (16 MiB bf16) aliases qb..ub
  bf16*  kb   = (bf16*)p;  p += ABF;
  bf16*  vT   = (bf16*)p;  p += ABF;   // [B][H][32][S], pre-scaled by g^(-m)
  bf16*  ub   = (bf16*)p;  p += ABF;
  float* gbuf = (float*)p; p += AF;
  float* yres = (float*)p; p += AF;
  bf16*  wqkvgt = (bf16*)p; p += (size_t)2 * 1024 * 256 * sizeof(bf16);
  bf16*  wot    = (bf16*)p; p += (size_t)2 * 256 * 256 * sizeof(bf16);
  bf16*  w1t    = (bf16*)p; p += (size_t)2 * 1024 * 256 * sizeof(bf16);
  bf16*  w2t    = (bf16*)p; p += (size_t)2 * 256 * 1024 * sizeof(bf16);
  float* tsn  = (float*)p; p += SS * 16 * sizeof(float);
  float* tcs  = (float*)p; p += SS * 16 * sizeof(float);
  float* tsc  = (float*)p; p += SS * 16 * sizeof(float);
  bf16*  h1   = qb;                    // MM*FFD bf16 = 16 MiB

  {
    WDescA da;
    for (int l = 0; l < 2; ++l) {
      da.d[l * 7 + 0] = { Wq + (size_t)l * 65536, wqkvgt + (size_t)l * 262144 + 0 * 65536, 256, 256 };
      da.d[l * 7 + 1] = { Wk + (size_t)l * 65536, wqkvgt + (size_t)l * 262144 + 1 * 65536, 256, 256 };
      da.d[l * 7 + 2] = { Wv + (size_t)l * 65536, wqkvgt + (size_t)l * 262144 + 2 * 65536, 256, 256 };
      da.d[l * 7 + 3] = { Wg + (size_t)l * 65536, wqkvgt + (size_t)l * 262144 + 3 * 65536, 256, 256 };
      da.d[l * 7 + 4] = { Wo + (size_t)l * 65536, wot + (size_t)l * 65536, 256, 256 };
      da.d[l * 7 + 5] = { w1 + (size_t)l * 262144, w1t + (size_t)l * 262144, 256, 1024 };
      da.d[l * 7 + 6] = { w2 + (size_t)l * 262144, w2t + (size_t)l * 262144, 1024, 256 };
    }
    da.tsn = tsn; da.tcs = tcs; da.tsc = tsc;
    wconv_k<<<dim3(32, 32, 15), dim3(32, 8), 0, stream>>>(da);
  }

  // layer 0 LN1 (layer 1's LN1 is fused into layer 0's FFN2 epilogue)
  ln_k<bf16><<<dim3(MM), 256, 0, stream>>>(X, ln1w, ln1b, xn);

  for (int l = 0; l < LYR; ++l) {
    mgemm_k<128, 128, DD, E_QKVG><<<dim3(MM / 128, 1024 / 128), 256, 0, stream>>>(
        xn, wqkvgt + (size_t)l * 262144, nullptr, qb, kb, vT, gbuf, 1024, tsn, tcs, tsc);
    attn_k<<<dim3(BB * HH, SS / 64), 256, 0, stream>>>(qb, kb, vT, gbuf, gnw + l * DD, gnb + l * DD, ub);
    mgemm_ln<DD, 0, false><<<dim3(MM / 32), 256, 0, stream>>>(
        ub, wot + (size_t)l * 65536, nullptr, (l == 0) ? X : yres, yres, xn, nullptr,
        ln2w + l * DD, ln2b + l * DD, nullptr, nullptr);
    mgemm_k<128, 128, DD, E_BGELU><<<dim3(MM / 128, FFD / 128), 256, 0, stream>>>(
        xn, w1t + (size_t)l * 262144, b1 + l * FFD, h1, nullptr, nullptr, nullptr, FFD, tsn, tcs, tsc);
    if (l == LYR - 1) {
      mgemm_ln<FFD, 1, true><<<dim3(MM / 32), 256, 0, stream>>>(
          h1, w2t + (size_t)l * 262144, b2 + l * DD, yres, nullptr, nullptr, (float*)d_out,
          lnfw, lnfb, nullptr, nullptr);
    } else {
      mgemm_ln<FFD, 1, false><<<dim3(MM / 32), 256, 0, stream>>>(
          h1, w2t + (size_t)l * 262144, b2 + l * DD, yres, yres, xn, nullptr,
          lnfw, lnfb, ln1w + (l + 1) * DD, ln1b + (l + 1) * DD);
    }
  }
}

// Round 12
// 200.546 us; speedup vs baseline: 8.1361x; 1.1133x over previous
//
#include <hip/hip_runtime.h>
#include <hip/hip_bf16.h>

typedef __hip_bfloat16 bf16;
typedef unsigned short ushort_t;
typedef __attribute__((ext_vector_type(8))) short short8v;
typedef __attribute__((ext_vector_type(4))) float f32x4;
typedef __attribute__((ext_vector_type(4))) unsigned int uint4v;

// RetNet block: L=2, B=4, S=2048, D=256, H=8, HD=32, FFN*D=1024
#define LYR 2
#define BB 4
#define SS 2048
#define DD 256
#define HH 8
#define HDD 32
#define FFD 1024
#define MM (BB*SS)   // 8192 tokens

__device__ __forceinline__ unsigned int cvtpk(float lo, float hi) {
  unsigned int r;
  asm("v_cvt_pk_bf16_f32 %0, %1, %2" : "=v"(r) : "v"(lo), "v"(hi));
  return r;
}

__device__ __forceinline__ void gload_lds16(const void* g, void* l) {
  __builtin_amdgcn_global_load_lds((const __attribute__((address_space(1))) void*)g,
                                   (__attribute__((address_space(3))) void*)l, 16, 0, 0);
}

// decay exponent: l2g(h) = log2(1 - exp(log(1/32) + h*(log(1/512)-log(1/32))/7))  (negative)
__device__ __forceinline__ float l2g_of(int h) {
  return log2f(1.0f - expf(-3.4657359028f - 0.3960841187f * (float)h));
}

// ---------------- weight transpose+convert + xPos tables (z==14) ----------------
struct WDesc { const float* src; bf16* dst; int K; int N; };
struct WDescA { WDesc d[14]; float* tsn; float* tcs; float* tsc; };
__global__ __launch_bounds__(256) void wconv_k(WDescA da) {
  if (blockIdx.z == 14) {
    int i = (blockIdx.y * 32 + blockIdx.x) * 256 + threadIdx.y * 32 + threadIdx.x;
    if (i >= SS * 16) return;
    int s = i >> 4, j = i & 15;
    float sv = (2.0f * (float)j + 0.4f * (float)HDD) / (1.4f * (float)HDD);
    da.tsc[i] = powf(sv, (float)s * (1.0f / 512.0f));
    float inv_freq = powf(10000.0f, -(float)j * (1.0f / 16.0f));
    float ang = (float)s * inv_freq;
    da.tsn[i] = sinf(ang);
    da.tcs[i] = cosf(ang);
    return;
  }
  WDesc dd = da.d[blockIdx.z];
  int n0 = blockIdx.x * 32, k0 = blockIdx.y * 32;
  if (n0 >= dd.N || k0 >= dd.K) return;
  __shared__ float t[32][33];
  int tx = threadIdx.x, ty = threadIdx.y;   // 32 x 8
  #pragma unroll
  for (int i = 0; i < 32; i += 8) t[ty + i][tx] = dd.src[(size_t)(k0 + ty + i) * dd.N + n0 + tx];
  __syncthreads();
  #pragma unroll
  for (int i = 0; i < 32; i += 8) dd.dst[(size_t)(n0 + ty + i) * dd.K + k0 + tx] = __float2bfloat16(t[tx][ty + i]);
}

// ---------------- LayerNorm over D=256 (one block per row), f32 in, OT out ----------------
template<typename OT>
__global__ __launch_bounds__(256) void ln_k(const float* __restrict__ in, const float* __restrict__ w,
    const float* __restrict__ b, OT* __restrict__ out)
{
  int row = blockIdx.x, t = threadIdx.x;
  float v = in[(size_t)row * DD + t];
  __shared__ float red[4];
  float s = v;
  #pragma unroll
  for (int m = 32; m >= 1; m >>= 1) s += __shfl_xor(s, m);
  if ((t & 63) == 0) red[t >> 6] = s;
  __syncthreads();
  float mu = (red[0] + red[1] + red[2] + red[3]) * (1.0f / 256.0f);
  float d = v - mu;
  float s2 = d * d;
  #pragma unroll
  for (int m = 32; m >= 1; m >>= 1) s2 += __shfl_xor(s2, m);
  __syncthreads();
  if ((t & 63) == 0) red[t >> 6] = s2;
  __syncthreads();
  float var = (red[0] + red[1] + red[2] + red[3]) * (1.0f / 256.0f);
  float o = d * rsqrtf(var + 1e-5f) * w[t] + b[t];
  if constexpr (sizeof(OT) == 2) out[(size_t)row * DD + t] = __float2bfloat16(o);
  else                           out[(size_t)row * DD + t] = o;
}

#define STAGEG(buf, k0s) { \
    _Pragma("unroll") \
    for (int i = 0; i < BM / 32; ++i) { \
      int slot = i * 256 + tid; int row = slot >> 3, blk = slot & 7; \
      gload_lds16(Au + (size_t)(bm + row) * K + (k0s) + ((blk ^ (row & 7))) * 8, &Al[buf][slot * 8]); \
    } \
    _Pragma("unroll") \
    for (int i = 0; i < BN / 32; ++i) { \
      int slot = i * 256 + tid; int row = slot >> 3, blk = slot & 7; \
      gload_lds16(Bu + (size_t)(bn + row) * K + (k0s) + ((blk ^ (row & 7))) * 8, &Bl[buf][slot * 8]); \
    } }

// ---------------- bf16 MFMA GEMM, double-buffered pipeline ----------------
enum { E_QKVG = 0, E_BGELU = 2 };

template<int BM, int BN, int K, int EPI>
__global__ __launch_bounds__(256) void mgemm_k(const bf16* __restrict__ Ag, const bf16* __restrict__ Wt,
    const float* __restrict__ bias,
    void* o0, void* o1, void* o2, void* o3, int N,
    const float* __restrict__ tsn, const float* __restrict__ tcs, const float* __restrict__ tsc)
{
  constexpr int MT = BM / 32, NT = BN / 32;
  constexpr int WMH = BM / 2, WNH = BN / 2;
  __shared__ __align__(16) ushort_t Al[2][BM * 64];
  __shared__ __align__(16) ushort_t Bl[2][BN * 64];
  const int bm = blockIdx.x * BM;
  const int bn = blockIdx.y * BN;
  const int tid = threadIdx.x;
  const int lane = tid & 63, w = tid >> 6;
  const int lg = lane >> 4, ln = lane & 15;
  const int wr = w >> 1, wc = w & 1;
  const ushort_t* Au = (const ushort_t*)Ag;
  const ushort_t* Bu = (const ushort_t*)Wt;
  f32x4 acc[MT][NT] = {};

  STAGEG(0, 0)
  asm volatile("s_waitcnt vmcnt(0)" ::: "memory");
  __builtin_amdgcn_s_barrier();

  int cur = 0;
  for (int k0 = 0; k0 < K; k0 += 64) {
    if (k0 + 64 < K) STAGEG(cur ^ 1, k0 + 64)
    #pragma unroll
    for (int kh = 0; kh < 2; ++kh) {
      short8v af[MT], bfr[NT];
      #pragma unroll
      for (int mt = 0; mt < MT; ++mt) {
        int row = wr * WMH + mt * 16 + ln;
        af[mt] = *(const short8v*)&Al[cur][row * 64 + (((kh * 4 + lg) ^ (row & 7))) * 8];
      }
      #pragma unroll
      for (int nt = 0; nt < NT; ++nt) {
        int row = wc * WNH + nt * 16 + ln;
        bfr[nt] = *(const short8v*)&Bl[cur][row * 64 + (((kh * 4 + lg) ^ (row & 7))) * 8];
      }
      #pragma unroll
      for (int mt = 0; mt < MT; ++mt)
        #pragma unroll
        for (int nt = 0; nt < NT; ++nt)
          acc[mt][nt] = __builtin_amdgcn_mfma_f32_16x16x32_bf16(af[mt], bfr[nt], acc[mt][nt], 0, 0, 0);
    }
    asm volatile("s_waitcnt vmcnt(0)" ::: "memory");
    __builtin_amdgcn_s_barrier();
    cur ^= 1;
  }

  if constexpr (EPI == E_QKVG) {
    #pragma unroll
    for (int mt = 0; mt < MT; ++mt)
      #pragma unroll
      for (int nt = 0; nt < NT; ++nt) {
        const int colbase = bn + wc * WNH + nt * 16;
        const int sec = colbase >> 8;          // 0=Q 1=K 2=V 3=G (uniform per block)
        const int c = (colbase & 255) + ln;
        const int grow0 = bm + wr * WMH + mt * 16 + lg * 4;
        if (sec <= 1) {
          const int jj = (c & 31) >> 1;
          const float l2g = l2g_of(c >> 5);
          #pragma unroll
          for (int r = 0; r < 4; ++r) {
            const int grow = grow0 + r;
            const int s = grow & (SS - 1);
            float v = acc[mt][nt][r];
            float pv = __shfl_xor(v, 1);
            float scv = tsc[s * 16 + jj];
            if (sec == 1) scv = 1.0f / scv;
            float ce = tcs[s * 16 + jj] * scv, se = tsn[s * 16 + jj] * scv;
            float o = (ln & 1) ? (v * ce + pv * se) : (v * ce - pv * se);
            if (sec == 0) o *= exp2f(l2g * (float)s);   // fold decay g^n into Q
            bf16* dst = (sec == 0) ? (bf16*)o0 : (bf16*)o1;
            dst[(size_t)grow * DD + c] = __float2bfloat16(o);
          }
        } else if (sec == 2) {
          // V transposed + fold g^(-m): vT[(b*8+h)*32 + d][s] = v(m=s,d) * g^(-s)
          const int b = grow0 >> 11, s0 = grow0 & (SS - 1);
          const int h = c >> 5, d = c & 31;
          const float nl2g = -l2g_of(h);                // positive
          float v0 = acc[mt][nt][0] * exp2f(nl2g * (float)(s0 + 0));
          float v1 = acc[mt][nt][1] * exp2f(nl2g * (float)(s0 + 1));
          float v2 = acc[mt][nt][2] * exp2f(nl2g * (float)(s0 + 2));
          float v3 = acc[mt][nt][3] * exp2f(nl2g * (float)(s0 + 3));
          uint2 pk;
          pk.x = cvtpk(v0, v1);
          pk.y = cvtpk(v2, v3);
          *(uint2*)((ushort_t*)o2 + ((size_t)(b * 8 + h) * 32 + d) * SS + s0) = pk;
        } else {
          #pragma unroll
          for (int r = 0; r < 4; ++r)
            ((float*)o3)[(size_t)(grow0 + r) * DD + c] = acc[mt][nt][r];
        }
      }
  } else {  // E_BGELU
    #pragma unroll
    for (int mt = 0; mt < MT; ++mt)
      #pragma unroll
      for (int nt = 0; nt < NT; ++nt) {
        const int gcol = bn + wc * WNH + nt * 16 + ln;
        #pragma unroll
        for (int r = 0; r < 4; ++r) {
          const int grow = bm + wr * WMH + mt * 16 + lg * 4 + r;
          float v = acc[mt][nt][r] + bias[gcol];
          v = 0.5f * v * (1.0f + erff(v * 0.70710678118654752f));
          ((bf16*)o0)[(size_t)grow * N + gcol] = __float2bfloat16(v);
        }
      }
  }
}

// ---------------- GEMM (N=256) + residual + fused LayerNorm(s) ----------------
// BM=16, BN=256 (full row), grid MM/16=512 blocks (2/CU). 4 waves all in N:
// wave w = 16 rows x cols [w*64, w*64+64), NT=4.
template<int K, int MODE, bool LAST>
__global__ __launch_bounds__(256) void mgemm_ln(const bf16* __restrict__ Ag, const bf16* __restrict__ Wt,
    const float* __restrict__ bias, const float* __restrict__ res,
    float* __restrict__ yres, bf16* __restrict__ xn, float* __restrict__ dout,
    const float* __restrict__ law, const float* __restrict__ lab,
    const float* __restrict__ lbw, const float* __restrict__ lbb)
{
  constexpr int BM = 16;
  __shared__ __align__(16) ushort_t Al[2][BM * 64];
  __shared__ __align__(16) ushort_t Bl[2][256 * 64];
  __shared__ float red[4][16][2];
  const int bm = blockIdx.x * BM;
  const int tid = threadIdx.x;
  const int lane = tid & 63, w = tid >> 6;
  const int lg = lane >> 4, ln = lane & 15;
  const ushort_t* Au = (const ushort_t*)Ag;
  const ushort_t* Bu = (const ushort_t*)Wt;
  f32x4 acc[4] = {};

  #define STAGEL(buf, k0s) { \
    if (tid < 128) { int row = tid >> 3, blk = tid & 7; \
      gload_lds16(Au + (size_t)(bm + row) * K + (k0s) + ((blk ^ (row & 7))) * 8, &Al[buf][tid * 8]); } \
    _Pragma("unroll") \
    for (int i = 0; i < 8; ++i) { \
      int slot = i * 256 + tid; int row = slot >> 3, blk = slot & 7; \
      gload_lds16(Bu + (size_t)row * K + (k0s) + ((blk ^ (row & 7))) * 8, &Bl[buf][slot * 8]); } }

  STAGEL(0, 0)
  asm volatile("s_waitcnt vmcnt(0)" ::: "memory");
  __builtin_amdgcn_s_barrier();

  int cur = 0;
  for (int k0 = 0; k0 < K; k0 += 64) {
    if (k0 + 64 < K) STAGEL(cur ^ 1, k0 + 64)
    #pragma unroll
    for (int kh = 0; kh < 2; ++kh) {
      short8v af, bfr[4];
      af = *(const short8v*)&Al[cur][ln * 64 + (((kh * 4 + lg) ^ (ln & 7))) * 8];
      #pragma unroll
      for (int nt = 0; nt < 4; ++nt) {
        int row = w * 64 + nt * 16 + ln;
        bfr[nt] = *(const short8v*)&Bl[cur][row * 64 + (((kh * 4 + lg) ^ (row & 7))) * 8];
      }
      #pragma unroll
      for (int nt = 0; nt < 4; ++nt)
        acc[nt] = __builtin_amdgcn_mfma_f32_16x16x32_bf16(af, bfr[nt], acc[nt], 0, 0, 0);
    }
    asm volatile("s_waitcnt vmcnt(0)" ::: "memory");
    __builtin_amdgcn_s_barrier();
    cur ^= 1;
  }
  #undef STAGEL

  const int row0 = lg * 4;                        // block-local rows [row0, row0+4)
  float v[4][4];
  #pragma unroll
  for (int nt = 0; nt < 4; ++nt) {
    const int gcol = w * 64 + nt * 16 + ln;
    #pragma unroll
    for (int r = 0; r < 4; ++r) {
      float t = acc[nt][r];
      if constexpr (MODE == 1) t += bias[gcol];
      t += res[(size_t)(bm + row0 + r) * DD + gcol];
      v[nt][r] = t;
    }
  }
  float mu[4], rs[4];
  {
    #pragma unroll
    for (int r = 0; r < 4; ++r) {
      float s = 0.f, s2 = 0.f;
      #pragma unroll
      for (int nt = 0; nt < 4; ++nt) { s += v[nt][r]; s2 += v[nt][r] * v[nt][r]; }
      #pragma unroll
      for (int m = 8; m >= 1; m >>= 1) { s += __shfl_xor(s, m); s2 += __shfl_xor(s2, m); }
      if (ln == 0) { red[w][row0 + r][0] = s; red[w][row0 + r][1] = s2; }
    }
    __syncthreads();
    #pragma unroll
    for (int r = 0; r < 4; ++r) {
      float S  = red[0][row0 + r][0] + red[1][row0 + r][0] + red[2][row0 + r][0] + red[3][row0 + r][0];
      float S2 = red[0][row0 + r][1] + red[1][row0 + r][1] + red[2][row0 + r][1] + red[3][row0 + r][1];
      float m_ = S * (1.0f / 256.0f);
      float var = S2 * (1.0f / 256.0f) - m_ * m_;
      mu[r] = m_; rs[r] = rsqrtf(var + 1e-5f);
    }
  }

  if constexpr (MODE == 0) {
    #pragma unroll
    for (int nt = 0; nt < 4; ++nt) {
      const int gcol = w * 64 + nt * 16 + ln;
      const float lw = law[gcol], lb = lab[gcol];
      #pragma unroll
      for (int r = 0; r < 4; ++r) {
        const size_t idx = (size_t)(bm + row0 + r) * DD + gcol;
        yres[idx] = v[nt][r];
        xn[idx] = __float2bfloat16((v[nt][r] - mu[r]) * rs[r] * lw + lb);
      }
    }
  } else {
    float u[4][4];
    #pragma unroll
    for (int nt = 0; nt < 4; ++nt) {
      const int gcol = w * 64 + nt * 16 + ln;
      const float lw = law[gcol], lb = lab[gcol];
      #pragma unroll
      for (int r = 0; r < 4; ++r)
        u[nt][r] = (v[nt][r] - mu[r]) * rs[r] * lw + lb;
    }
    if constexpr (LAST) {
      #pragma unroll
      for (int nt = 0; nt < 4; ++nt) {
        const int gcol = w * 64 + nt * 16 + ln;
        #pragma unroll
        for (int r = 0; r < 4; ++r)
          dout[(size_t)(bm + row0 + r) * DD + gcol] = u[nt][r];
      }
    } else {
      __syncthreads();
      #pragma unroll
      for (int r = 0; r < 4; ++r) {
        float s = 0.f, s2 = 0.f;
        #pragma unroll
        for (int nt = 0; nt < 4; ++nt) { s += u[nt][r]; s2 += u[nt][r] * u[nt][r]; }
        #pragma unroll
        for (int m = 8; m >= 1; m >>= 1) { s += __shfl_xor(s, m); s2 += __shfl_xor(s2, m); }
        if (ln == 0) { red[w][row0 + r][0] = s; red[w][row0 + r][1] = s2; }
      }
      __syncthreads();
      float mu2[4], rs2[4];
      #pragma unroll
      for (int r = 0; r < 4; ++r) {
        float S  = red[0][row0 + r][0] + red[1][row0 + r][0] + red[2][row0 + r][0] + red[3][row0 + r][0];
        float S2 = red[0][row0 + r][1] + red[1][row0 + r][1] + red[2][row0 + r][1] + red[3][row0 + r][1];
        float m_ = S * (1.0f / 256.0f);
        float var = S2 * (1.0f / 256.0f) - m_ * m_;
        mu2[r] = m_; rs2[r] = rsqrtf(var + 1e-5f);
      }
      #pragma unroll
      for (int nt = 0; nt < 4; ++nt) {
        const int gcol = w * 64 + nt * 16 + ln;
        const float lw = lbw[gcol], lb = lbb[gcol];
        #pragma unroll
        for (int r = 0; r < 4; ++r) {
          const size_t idx = (size_t)(bm + row0 + r) * DD + gcol;
          yres[idx] = u[nt][r];
          xn[idx] = __float2bfloat16((u[nt][r] - mu2[r]) * rs2[r] * lw + lb);
        }
      }
    }
  }
}

// ---------------- Retention + fused GroupNorm/SiLU-gate ----------------
// Decay is pre-folded: q *= g^n, vT *= g^(-m). Inner loop: raw QK -> pack -> PV.
__global__ __launch_bounds__(256) void attn_k(const bf16* __restrict__ qg, const bf16* __restrict__ kg,
    const bf16* __restrict__ vtg, const float* __restrict__ gbuf,
    const float* __restrict__ gnw, const float* __restrict__ gnb, bf16* __restrict__ ub)
{
  __shared__ __align__(16) ushort_t Kl[2][64 * 32];      // [m][k], blk ^= m&3
  __shared__ __align__(16) ushort_t Vl[2][32 * 64];      // [d][m], blk ^= d&7
  __shared__ __align__(16) unsigned int Pl[4][512];      // per wave: P^T[n=ln][64 m] bf16

  const int bh = blockIdx.x;
  const int b = bh >> 3, h = bh & (HH - 1);
  const int n0 = ((int)gridDim.y - 1 - (int)blockIdx.y) * 64;
  const int tid = threadIdx.x;
  const int w = tid >> 6, lane = tid & 63;
  const int lg = lane >> 4, ln = lane & 15;

  const size_t base = (size_t)b * SS * DD + h * HDD;
  const ushort_t* qp = (const ushort_t*)qg + base;
  const ushort_t* kp = (const ushort_t*)kg + base;
  const ushort_t* vtp = (const ushort_t*)vtg + (size_t)(b * 8 + h) * 32 * SS;

  const int n = n0 + w * 16 + ln;
  const short8v qf = *(const short8v*)(qp + (size_t)n * DD + lg * 8);

  const float l2g = l2g_of(h);                     // negative; only for window calc
  f32x4 acc0 = {0,0,0,0}, acc1 = {0,0,0,0};

  const int Wwin = (int)(20.0f / (-l2g)) + 1;
  int m_lo = 0;
  if (n0 > Wwin) m_lo = ((n0 - Wwin) >> 6) << 6;

  const int Krow = tid >> 2, Kc8 = tid & 3;
  const int Vrow = tid >> 3, Vc8 = tid & 7;

  #define STAGE(buf, m0s) { \
    gload_lds16(kp + (size_t)((m0s) + Krow) * DD + ((Kc8 ^ (Krow & 3)) * 8), &Kl[buf][tid * 8]); \
    gload_lds16(vtp + (size_t)Vrow * SS + (m0s) + ((Vc8 ^ (Vrow & 7)) * 8), &Vl[buf][tid * 8]); }

  STAGE(0, m_lo)
  asm volatile("s_waitcnt vmcnt(0)" ::: "memory");
  __builtin_amdgcn_s_barrier();

  int cur = 0;
  for (int m0 = m_lo; m0 <= n0; m0 += 64) {
    if (m0 < n0) STAGE(cur ^ 1, m0 + 64)
    const bool diag = (m0 == n0);
    __builtin_amdgcn_s_setprio(1);
    #pragma unroll
    for (int mt = 0; mt < 4; ++mt) {
      const int krow = mt * 16 + ln;
      short8v kf = *(const short8v*)&Kl[cur][krow * 32 + ((lg ^ (krow & 3)) << 3)];
      f32x4 z = {0,0,0,0};
      f32x4 pa = __builtin_amdgcn_mfma_f32_16x16x32_bf16(kf, qf, z, 0, 0, 0);
      float v0 = pa[0], v1 = pa[1], v2 = pa[2], v3 = pa[3];
      if (diag) {
        const int m = n0 + mt * 16 + lg * 4;
        v0 = (n < m)     ? 0.f : v0;
        v1 = (n < m + 1) ? 0.f : v1;
        v2 = (n < m + 2) ? 0.f : v2;
        v3 = (n < m + 3) ? 0.f : v3;
      }
      uint2 pk;
      pk.x = cvtpk(v0, v1);
      pk.y = cvtpk(v2, v3);
      const int blk = (mt * 2 + (lg >> 1)) ^ (ln & 7);
      *(uint2*)&Pl[w][ln * 32 + blk * 4 + (lg & 1) * 2] = pk;
    }
    #pragma unroll
    for (int hh = 0; hh < 2; ++hh) {
      const int pblk = (hh * 4 + lg) ^ (ln & 7);
      uint4v pw = *(const uint4v*)&Pl[w][ln * 32 + pblk * 4];
      short8v pf = __builtin_bit_cast(short8v, pw);
      #pragma unroll
      for (int dt = 0; dt < 2; ++dt) {
        const int d = dt * 16 + ln;
        short8v vf = *(const short8v*)&Vl[cur][d * 64 + (((hh * 4 + lg) ^ (d & 7)) << 3)];
        if (dt == 0) acc0 = __builtin_amdgcn_mfma_f32_16x16x32_bf16(vf, pf, acc0, 0, 0, 0);
        else         acc1 = __builtin_amdgcn_mfma_f32_16x16x32_bf16(vf, pf, acc1, 0, 0, 0);
      }
    }
    __builtin_amdgcn_s_setprio(0);
    asm volatile("s_waitcnt vmcnt(0)" ::: "memory");
    __builtin_amdgcn_s_barrier();
    cur ^= 1;
  }
  #undef STAGE

  // ---- fused GroupNorm (per head) + SiLU gate ----
  float gwv[8], gbv[8];
  #pragma unroll
  for (int dt = 0; dt < 2; ++dt) {
    f32x4 a = *(const f32x4*)&gnw[h * 32 + dt * 16 + lg * 4];
    f32x4 c = *(const f32x4*)&gnb[h * 32 + dt * 16 + lg * 4];
    #pragma unroll
    for (int r = 0; r < 4; ++r) { gwv[dt * 4 + r] = a[r]; gbv[dt * 4 + r] = c[r]; }
  }
  float s = 0.f;
  #pragma unroll
  for (int r = 0; r < 4; ++r) s += acc0[r] + acc1[r];
  s += __shfl_xor(s, 16); s += __shfl_xor(s, 32);
  const float mu = s * (1.0f / 32.0f);
  float s2 = 0.f;
  #pragma unroll
  for (int r = 0; r < 4; ++r) { float d0 = acc0[r] - mu, d1 = acc1[r] - mu; s2 += d0 * d0 + d1 * d1; }
  s2 += __shfl_xor(s2, 16); s2 += __shfl_xor(s2, 32);
  const float rs = rsqrtf(s2 * (1.0f / 32.0f) + 1e-5f);
  const size_t rowoff = ((size_t)b * SS + n) * DD + h * 32;
  #pragma unroll
  for (int dt = 0; dt < 2; ++dt) {
    f32x4 yv = dt ? acc1 : acc0;
    f32x4 gv = *(const f32x4*)&gbuf[rowoff + dt * 16 + lg * 4];
    float o0, o1, o2, o3;
    {
      float yn0 = (yv[0] - mu) * rs * gwv[dt * 4 + 0] + gbv[dt * 4 + 0];
      float yn1 = (yv[1] - mu) * rs * gwv[dt * 4 + 1] + gbv[dt * 4 + 1];
      float yn2 = (yv[2] - mu) * rs * gwv[dt * 4 + 2] + gbv[dt * 4 + 2];
      float yn3 = (yv[3] - mu) * rs * gwv[dt * 4 + 3] + gbv[dt * 4 + 3];
      o0 = gv[0] / (1.0f + expf(-gv[0])) * yn0;
      o1 = gv[1] / (1.0f + expf(-gv[1])) * yn1;
      o2 = gv[2] / (1.0f + expf(-gv[2])) * yn2;
      o3 = gv[3] / (1.0f + expf(-gv[3])) * yn3;
    }
    uint2 pk;
    pk.x = cvtpk(o0, o1);
    pk.y = cvtpk(o2, o3);
    *(uint2*)((ushort_t*)ub + rowoff + dt * 16 + lg * 4) = pk;
  }
}

extern "C" void kernel_launch(void* const* d_in, const int* in_sizes, int n_in,
                              void* d_out, int out_size, void* d_ws, size_t ws_size,
                              hipStream_t stream)
{
  const float* X    = (const float*)d_in[0];
  const float* Wq   = (const float*)d_in[1];
  const float* Wk   = (const float*)d_in[2];
  const float* Wv   = (const float*)d_in[3];
  const float* Wg   = (const float*)d_in[4];
  const float* Wo   = (const float*)d_in[5];
  const float* gnw  = (const float*)d_in[6];
  const float* gnb  = (const float*)d_in[7];
  const float* ln1w = (const float*)d_in[8];
  const float* ln1b = (const float*)d_in[9];
  const float* ln2w = (const float*)d_in[10];
  const float* ln2b = (const float*)d_in[11];
  const float* w1   = (const float*)d_in[12];
  const float* b1   = (const float*)d_in[13];
  const float* w2   = (const float*)d_in[14];
  const float* b2   = (const float*)d_in[15];
  const float* lnfw = (const float*)d_in[16];
  const float* lnfb = (const float*)d_in[17];

  // Workspace (~40 MiB)
  char* p = (char*)d_ws;
  const size_t AF  = (size_t)MM * DD * sizeof(float);  // 8 MiB
  const size_t ABF = (size_t)MM * DD * sizeof(bf16);   // 4 MiB
  bf16*  xn   = (bf16*)p;  p += ABF;
  bf16*  qb   = (bf16*)p;  p += ABF;   // h1 (16 MiB bf16) aliases qb..ub
  bf16*  kb   = (bf16*)p;  p += ABF;
  bf16*  vT   = (bf16*)p;  p += ABF;   // [B][H][32][S], pre-scaled by g^(-m)
  bf16*  ub   = (bf16*)p;  p += ABF;
  float* gbuf = (float*)p; p += AF;
  float* yres = (float*)p; p += AF;
  bf16*  wqkvgt = (bf16*)p; p += (size_t)2 * 1024 * 256 * sizeof(bf16);
  bf16*  wot    = (bf16*)p; p += (size_t)2 * 256 * 256 * sizeof(bf16);
  bf16*  w1t    = (bf16*)p; p += (size_t)2 * 1024 * 256 * sizeof(bf16);
  bf16*  w2t    = (bf16*)p; p += (size_t)2 * 256 * 1024 * sizeof(bf16);
  float* tsn  = (float*)p; p += SS * 16 * sizeof(float);
  float* tcs  = (float*)p; p += SS * 16 * sizeof(float);
  float* tsc  = (float*)p; p += SS * 16 * sizeof(float);
  bf16*  h1   = qb;                    // MM*FFD bf16 = 16 MiB

  {
    WDescA da;
    for (int l = 0; l < 2; ++l) {
      da.d[l * 7 + 0] = { Wq + (size_t)l * 65536, wqkvgt + (size_t)l * 262144 + 0 * 65536, 256, 256 };
      da.d[l * 7 + 1] = { Wk + (size_t)l * 65536, wqkvgt + (size_t)l * 262144 + 1 * 65536, 256, 256 };
      da.d[l * 7 + 2] = { Wv + (size_t)l * 65536, wqkvgt + (size_t)l * 262144 + 2 * 65536, 256, 256 };
      da.d[l * 7 + 3] = { Wg + (size_t)l * 65536, wqkvgt + (size_t)l * 262144 + 3 * 65536, 256, 256 };
      da.d[l * 7 + 4] = { Wo + (size_t)l * 65536, wot + (size_t)l * 65536, 256, 256 };
      da.d[l * 7 + 5] = { w1 + (size_t)l * 262144, w1t + (size_t)l * 262144, 256, 1024 };
      da.d[l * 7 + 6] = { w2 + (size_t)l * 262144, w2t + (size_t)l * 262144, 1024, 256 };
    }
    da.tsn = tsn; da.tcs = tcs; da.tsc = tsc;
    wconv_k<<<dim3(32, 32, 15), dim3(32, 8), 0, stream>>>(da);
  }

  // layer 0 LN1 (layer 1's LN1 is fused into layer 0's FFN2 epilogue)
  ln_k<bf16><<<dim3(MM), 256, 0, stream>>>(X, ln1w, ln1b, xn);

  for (int l = 0; l < LYR; ++l) {
    mgemm_k<64, 128, DD, E_QKVG><<<dim3(MM / 64, 1024 / 128), 256, 0, stream>>>(
        xn, wqkvgt + (size_t)l * 262144, nullptr, qb, kb, vT, gbuf, 1024, tsn, tcs, tsc);
    attn_k<<<dim3(BB * HH, SS / 64), 256, 0, stream>>>(qb, kb, vT, gbuf, gnw + l * DD, gnb + l * DD, ub);
    mgemm_ln<DD, 0, false><<<dim3(MM / 16), 256, 0, stream>>>(
        ub, wot + (size_t)l * 65536, nullptr, (l == 0) ? X : yres, yres, xn, nullptr,
        ln2w + l * DD, ln2b + l * DD, nullptr, nullptr);
    mgemm_k<64, 128, DD, E_BGELU><<<dim3(MM / 64, FFD / 128), 256, 0, stream>>>(
        xn, w1t + (size_t)l * 262144, b1 + l * FFD, h1, nullptr, nullptr, nullptr, FFD, tsn, tcs, tsc);
    if (l == LYR - 1) {
      mgemm_ln<FFD, 1, true><<<dim3(MM / 16), 256, 0, stream>>>(
          h1, w2t + (size_t)l * 262144, b2 + l * DD, yres, nullptr, nullptr, (float*)d_out,
          lnfw, lnfb, nullptr, nullptr);
    } else {
      mgemm_ln<FFD, 1, false><<<dim3(MM / 16), 256, 0, stream>>>(
          h1, w2t + (size_t)l * 262144, b2 + l * DD, yres, yres, xn, nullptr,
          lnfw, lnfb, ln1w + (l + 1) * DD, ln1b + (l + 1) * DD);
    }
  }
}